// Round 10
// baseline (2760.572 us; speedup 1.0000x reference)
//
#include <hip/hip_runtime.h>
#include <math.h>

#define NN   20000
#define EE   320000
#define ELG  600000
#define FE   64
#define HD   256
#define FOUT 40
#define LOG2E 1.44269504f
#define NTOTC (NN + EE + NN)            // concatenated count-buffer size
// CSR-build privatization: one block owns one key-class; all build atomics in LDS.
#define DCLS 8
#define DRNG 2500                        // NN / DCLS
#define LGCLS 32
#define LGRNG 10000                      // EE / LGCLS (LG keys are edge ids)
#define HCLS 8
#define HRNG 2500

typedef __attribute__((ext_vector_type(8))) short bf16x8;
typedef __attribute__((ext_vector_type(4))) float f32x4;

__device__ __forceinline__ float leaky02(float x) { return x > 0.f ? x : 0.2f * x; }

__device__ __forceinline__ unsigned short bf16rne(float f) {
    unsigned int u = __float_as_uint(f);
    u = (u + 0x7FFFu + ((u >> 16) & 1u)) >> 16;
    return (unsigned short)u;
}
__device__ __forceinline__ float bflo(unsigned int u) { return __uint_as_float(u << 16); }
__device__ __forceinline__ float bfhi(unsigned int u) { return __uint_as_float(u & 0xffff0000u); }
__device__ __forceinline__ unsigned int bfpack(float a, float b) {
    return (unsigned int)bf16rne(a) | ((unsigned int)bf16rne(b) << 16);
}

// ---------------- small utility kernels ----------------
__global__ void conv_bf16(const float* __restrict__ in, unsigned int* __restrict__ out, int n2) {
    int i = blockIdx.x * 256 + threadIdx.x;
    if (i < n2) { float2 v = ((const float2*)in)[i]; out[i] = bfpack(v.x, v.y); }
}

// ---------------- privatized CSR count: one block per key-class, zero global atomics ----------------
// cntAll sections: [0,NN) = raw-by-dst, [NN,NN+EE) = lg-by-lgd, [NN+EE,NN+EE+NN) = incidence H
__global__ __launch_bounds__(256)
void count_priv(const int* __restrict__ dstN, const int* __restrict__ lgd,
                const int* __restrict__ Hm, int* __restrict__ cntAll) {
    __shared__ int hist[LGRNG];              // 40 KB (largest class range)
    int cb = blockIdx.x;
    int t = threadIdx.x;
    if (cb < DCLS) {
        int base = cb * DRNG;
        for (int i = t; i < DRNG; i += 256) hist[i] = 0;
        __syncthreads();
        for (int i = t; i < EE; i += 256) {
            unsigned key = (unsigned)(dstN[i] - base);
            if (key < DRNG) atomicAdd(&hist[key], 1);
        }
        __syncthreads();
        for (int i = t; i < DRNG; i += 256) cntAll[base + i] = hist[i];
    } else if (cb < DCLS + LGCLS) {
        int base = (cb - DCLS) * LGRNG;
        for (int i = t; i < LGRNG; i += 256) hist[i] = 0;
        __syncthreads();
        for (int i = t; i < ELG; i += 256) {
            unsigned key = (unsigned)(lgd[i] - base);
            if (key < LGRNG) atomicAdd(&hist[key], 1);
        }
        __syncthreads();
        for (int i = t; i < LGRNG; i += 256) cntAll[NN + base + i] = hist[i];
    } else {
        int base = (cb - DCLS - LGCLS) * HRNG;
        for (int i = t; i < HRNG; i += 256) hist[i] = 0;
        __syncthreads();
        for (int i = t; i < 2 * EE; i += 256) {
            unsigned key = (unsigned)(Hm[i] - base);
            if (key < HRNG) atomicAdd(&hist[key], 1);
        }
        __syncthreads();
        for (int i = t; i < HRNG; i += 256) cntAll[NN + EE + base + i] = hist[i];
    }
}

__global__ void scan_pass1(const int* __restrict__ in, int* __restrict__ bsum, int n) {
    __shared__ int sm[256];
    int base = blockIdx.x * 1024, t = threadIdx.x;
    int s = 0;
#pragma unroll
    for (int j = 0; j < 4; ++j) { int i = base + t * 4 + j; s += (i < n) ? in[i] : 0; }
    sm[t] = s; __syncthreads();
    for (int o = 128; o > 0; o >>= 1) { if (t < o) sm[t] += sm[t + o]; __syncthreads(); }
    if (t == 0) bsum[blockIdx.x] = sm[0];
}
__global__ void scan_pass2(int* __restrict__ bsum, int nb) {
    __shared__ int sm[1024];
    int t = threadIdx.x;
    for (int i = t; i < nb; i += 256) sm[i] = bsum[i];
    __syncthreads();
    if (t == 0) { int run = 0; for (int i = 0; i < nb; ++i) { int v = sm[i]; sm[i] = run; run += v; } }
    __syncthreads();
    for (int i = t; i < nb; i += 256) bsum[i] = sm[i];
}
__global__ void scan_pass3(const int* __restrict__ in, const int* __restrict__ boff,
                           int* __restrict__ out, int n) {
    __shared__ int tsum[256];
    int base = blockIdx.x * 1024, t = threadIdx.x;
    int v[4];
#pragma unroll
    for (int j = 0; j < 4; ++j) { int i = base + t * 4 + j; v[j] = (i < n) ? in[i] : 0; }
    int loc = v[0] + v[1] + v[2] + v[3];
    tsum[t] = loc; __syncthreads();
    for (int o = 1; o < 256; o <<= 1) {
        int x = (t >= o) ? tsum[t - o] : 0;
        __syncthreads();
        tsum[t] += x;
        __syncthreads();
    }
    int off = boff[blockIdx.x] + (tsum[t] - loc);
    int run = 0;
#pragma unroll
    for (int j = 0; j < 4; ++j) { int i = base + t * 4 + j; if (i < n) out[i] = off + run; run += v[j]; }
}

// section-rebased rowptr (one pass; cursors now live in place_priv's LDS)
__global__ void rebase_all(const int* __restrict__ scanAll,
                           int* __restrict__ rowptrD, int* __restrict__ rowptrLG,
                           int* __restrict__ rowptrH) {
    int i = blockIdx.x * 256 + threadIdx.x;
    if (i == 0) { rowptrD[NN] = EE; rowptrLG[EE] = ELG; rowptrH[NN] = 2 * EE; }
    if (i >= NTOTC) return;
    if (i < NN) rowptrD[i] = scanAll[i];
    else if (i < NN + EE) rowptrLG[i - NN] = scanAll[i] - EE;
    else rowptrH[i - NN - EE] = scanAll[i] - (EE + ELG);
}

// ---------------- privatized CSR place: LDS cursors, single writer per adj region ----------------
__global__ __launch_bounds__(256)
void place_priv(const int* __restrict__ srcN, const int* __restrict__ dstN,
                const int* __restrict__ lgs, const int* __restrict__ lgd,
                const int* __restrict__ Hm,
                const int* __restrict__ rowptrD, const int* __restrict__ rowptrLG,
                const int* __restrict__ rowptrH,
                int* __restrict__ adjS, int* __restrict__ adjLG, int* __restrict__ adjH) {
    __shared__ int cur[LGRNG];               // 40 KB
    int cb = blockIdx.x;
    int t = threadIdx.x;
    if (cb < DCLS) {
        int base = cb * DRNG;
        for (int i = t; i < DRNG; i += 256) cur[i] = rowptrD[base + i];
        __syncthreads();
        for (int i = t; i < EE; i += 256) {
            unsigned key = (unsigned)(dstN[i] - base);
            if (key < DRNG) {
                int pos = atomicAdd(&cur[key], 1);
                adjS[pos] = srcN[i];
            }
        }
    } else if (cb < DCLS + LGCLS) {
        int base = (cb - DCLS) * LGRNG;
        for (int i = t; i < LGRNG; i += 256) cur[i] = rowptrLG[base + i];
        __syncthreads();
        for (int i = t; i < ELG; i += 256) {
            unsigned key = (unsigned)(lgd[i] - base);
            if (key < LGRNG) {
                int pos = atomicAdd(&cur[key], 1);
                adjLG[pos] = lgs[i];
            }
        }
    } else {
        int base = (cb - DCLS - LGCLS) * HRNG;
        for (int i = t; i < HRNG; i += 256) cur[i] = rowptrH[base + i];
        __syncthreads();
        for (int i = t; i < 2 * EE; i += 256) {
            unsigned key = (unsigned)(Hm[i] - base);
            if (key < HRNG) {
                int pos = atomicAdd(&cur[key], 1);
                adjH[pos] = (i < EE) ? i : i - EE;
            }
        }
    }
}

// ---------------- weight transpose+convert ----------------
struct Ptr14 { const float* p[14]; };
__global__ void wtrans14(Ptr14 srcs, unsigned short* __restrict__ dst) {
    int m = blockIdx.x >> 6;
    int tile = blockIdx.x & 63;
    const float* src = srcs.p[m];
    unsigned short* out = dst + (size_t)m * 65536;
    int kb = (tile >> 3) * 32, nb = (tile & 7) * 32;
    __shared__ float sm[32][33];
    int t = threadIdx.x;
#pragma unroll
    for (int i = 0; i < 4; ++i) {
        int e = t + i * 256; int r = e >> 5, c = e & 31;
        sm[r][c] = src[(kb + r) * 256 + nb + c];
    }
    __syncthreads();
#pragma unroll
    for (int i = 0; i < 4; ++i) {
        int e = t + i * 256; int nr = e >> 5, kc = e & 31;
        out[(size_t)(nb + nr) * 256 + kb + kc] = bf16rne(sm[kc][nr]);
    }
}
__global__ void wtrans_one(const float* __restrict__ src, unsigned short* __restrict__ dst,
                           int K, int N) {
    int tilesN = N >> 5;
    int kb = (blockIdx.x / tilesN) * 32, nb = (blockIdx.x % tilesN) * 32;
    __shared__ float sm[32][33];
    int t = threadIdx.x;
#pragma unroll
    for (int i = 0; i < 4; ++i) {
        int e = t + i * 256; int r = e >> 5, c = e & 31;
        sm[r][c] = src[(kb + r) * N + nb + c];
    }
    __syncthreads();
#pragma unroll
    for (int i = 0; i < 4; ++i) {
        int e = t + i * 256; int nr = e >> 5, kc = e & 31;
        dst[(size_t)(nb + nr) * K + kb + kc] = bf16rne(sm[kc][nr]);
    }
}

// ---------------- bf16 MFMA GEMM ----------------
// flags: 1=relu, 4=degE-mask + leaky
__global__ __launch_bounds__(256)
void gemm_bf16(const unsigned short* __restrict__ A1, const unsigned short* __restrict__ A2,
               const unsigned short* __restrict__ W1, const unsigned short* __restrict__ W2,
               const float* __restrict__ bias, const float* __restrict__ degmask,
               unsigned short* __restrict__ C, int M, int K1, int flags) {
    __shared__ unsigned short As[128][40];
    __shared__ unsigned short Bs[64][40];
    int tid = threadIdx.x;
    int w = tid >> 6, l = tid & 63;
    int wr = w >> 1, wc = w & 1;
    int brow = blockIdx.y * 128, bcol = blockIdx.x * 64;
    int Ktot = K1 + (A2 ? 256 : 0);
    f32x4 acc[4][2] = {};
    for (int k0 = 0; k0 < Ktot; k0 += 32) {
        const unsigned short* Ap; const unsigned short* Wp; int kk, Klen;
        if (k0 < K1) { Ap = A1; Wp = W1; kk = k0; Klen = K1; }
        else         { Ap = A2; Wp = W2; kk = k0 - K1; Klen = 256; }
#pragma unroll
        for (int i = 0; i < 4; ++i) {
            int q = tid + i * 256;
            int r = q >> 3, kb = (q & 7) * 4;
            int gr = brow + r;
            ushort4 u;
            if (gr < M) u = *(const ushort4*)(Ap + (size_t)gr * Klen + kk + kb);
            else { u.x = 0; u.y = 0; u.z = 0; u.w = 0; }
            *(ushort4*)(&As[r][kb]) = u;
        }
#pragma unroll
        for (int i = 0; i < 2; ++i) {
            int q = tid + i * 256;
            int n = q >> 3, kb = (q & 7) * 4;
            *(ushort4*)(&Bs[n][kb]) = *(const ushort4*)(Wp + (size_t)(bcol + n) * Klen + kk + kb);
        }
        __syncthreads();
        bf16x8 af[4], bfr[2];
#pragma unroll
        for (int fr = 0; fr < 4; ++fr)
            af[fr] = *(const bf16x8*)(&As[wr * 64 + fr * 16 + (l & 15)][(l >> 4) * 8]);
#pragma unroll
        for (int fc = 0; fc < 2; ++fc)
            bfr[fc] = *(const bf16x8*)(&Bs[wc * 32 + fc * 16 + (l & 15)][(l >> 4) * 8]);
#pragma unroll
        for (int fr = 0; fr < 4; ++fr)
#pragma unroll
            for (int fc = 0; fc < 2; ++fc)
                acc[fr][fc] = __builtin_amdgcn_mfma_f32_16x16x32_bf16(af[fr], bfr[fc], acc[fr][fc], 0, 0, 0);
        __syncthreads();
    }
#pragma unroll
    for (int fr = 0; fr < 4; ++fr) {
#pragma unroll
        for (int fc = 0; fc < 2; ++fc) {
            int col = bcol + wc * 32 + fc * 16 + (l & 15);
#pragma unroll
            for (int i = 0; i < 4; ++i) {
                int row = brow + wr * 64 + fr * 16 + (l >> 4) * 4 + i;
                if (row >= M) continue;
                float v = acc[fr][fc][i];
                if (bias) v += bias[col];
                if (flags & 1) v = fmaxf(v, 0.f);
                if (flags & 4) { v = (degmask[row] > 0.f) ? v : 0.f; v = leaky02(v); }
                C[(size_t)row * 256 + col] = bf16rne(v);
            }
        }
    }
}

// three single-K GEMMs in one launch
__global__ __launch_bounds__(256)
void gemm_bf16_tri(const unsigned short* __restrict__ A0, const unsigned short* __restrict__ W0,
                   unsigned short* __restrict__ C0,
                   const unsigned short* __restrict__ A1, const unsigned short* __restrict__ W1,
                   unsigned short* __restrict__ C1,
                   const unsigned short* __restrict__ A2, const unsigned short* __restrict__ W2,
                   unsigned short* __restrict__ C2, int M) {
    __shared__ unsigned short As[128][40];
    __shared__ unsigned short Bs[64][40];
    int sel = blockIdx.x >> 2;
    const unsigned short* A = (sel == 0) ? A0 : (sel == 1) ? A1 : A2;
    const unsigned short* W = (sel == 0) ? W0 : (sel == 1) ? W1 : W2;
    unsigned short* C = (sel == 0) ? C0 : (sel == 1) ? C1 : C2;
    int tid = threadIdx.x;
    int w = tid >> 6, l = tid & 63;
    int wr = w >> 1, wc = w & 1;
    int brow = blockIdx.y * 128, bcol = (blockIdx.x & 3) * 64;
    f32x4 acc[4][2] = {};
    for (int k0 = 0; k0 < 256; k0 += 32) {
#pragma unroll
        for (int i = 0; i < 4; ++i) {
            int q = tid + i * 256;
            int r = q >> 3, kb = (q & 7) * 4;
            int gr = brow + r;
            ushort4 u;
            if (gr < M) u = *(const ushort4*)(A + (size_t)gr * 256 + k0 + kb);
            else { u.x = 0; u.y = 0; u.z = 0; u.w = 0; }
            *(ushort4*)(&As[r][kb]) = u;
        }
#pragma unroll
        for (int i = 0; i < 2; ++i) {
            int q = tid + i * 256;
            int n = q >> 3, kb = (q & 7) * 4;
            *(ushort4*)(&Bs[n][kb]) = *(const ushort4*)(W + (size_t)(bcol + n) * 256 + k0 + kb);
        }
        __syncthreads();
        bf16x8 af[4], bfr[2];
#pragma unroll
        for (int fr = 0; fr < 4; ++fr)
            af[fr] = *(const bf16x8*)(&As[wr * 64 + fr * 16 + (l & 15)][(l >> 4) * 8]);
#pragma unroll
        for (int fc = 0; fc < 2; ++fc)
            bfr[fc] = *(const bf16x8*)(&Bs[wc * 32 + fc * 16 + (l & 15)][(l >> 4) * 8]);
#pragma unroll
        for (int fr = 0; fr < 4; ++fr)
#pragma unroll
            for (int fc = 0; fc < 2; ++fc)
                acc[fr][fc] = __builtin_amdgcn_mfma_f32_16x16x32_bf16(af[fr], bfr[fc], acc[fr][fc], 0, 0, 0);
        __syncthreads();
    }
#pragma unroll
    for (int fr = 0; fr < 4; ++fr) {
#pragma unroll
        for (int fc = 0; fc < 2; ++fc) {
            int col = bcol + wc * 32 + fc * 16 + (l & 15);
#pragma unroll
            for (int i = 0; i < 4; ++i) {
                int row = brow + wr * 64 + fr * 16 + (l >> 4) * 4 + i;
                if (row >= M) continue;
                C[(size_t)row * 256 + col] = bf16rne(acc[fr][fc][i]);
            }
        }
    }
}

// ---------------- fp32 GEMM (Wcomb build only) ----------------
__global__ __launch_bounds__(256)
void gemm_f32(const float* __restrict__ A, const float* __restrict__ B,
              float* __restrict__ C, int M, int N, int K) {
    const int BM = 64, BN = 64, BK = 16;
    __shared__ float As[BK][BM + 1];
    __shared__ float Bs[BK][BN + 1];
    int tid = threadIdx.x;
    int tr = tid >> 4, tc = tid & 15;
    int brow = blockIdx.y * BM, bcol = blockIdx.x * BN;
    float acc[4][4] = {{0.f}};
    for (int k0 = 0; k0 < K; k0 += BK) {
#pragma unroll
        for (int i = 0; i < 4; ++i) {
            int e = tid + i * 256;
            int r = e >> 4, c = e & 15;
            int gr = brow + r, gc = k0 + c;
            As[c][r] = (gr < M && gc < K) ? A[(long)gr * K + gc] : 0.f;
        }
#pragma unroll
        for (int i = 0; i < 4; ++i) {
            int e = tid + i * 256;
            int r = e >> 6, c = e & 63;
            int gr = k0 + r, gc = bcol + c;
            Bs[r][c] = (gr < K && gc < N) ? B[(long)gr * N + gc] : 0.f;
        }
        __syncthreads();
#pragma unroll
        for (int k = 0; k < BK; ++k) {
            float ra[4], rb[4];
#pragma unroll
            for (int i = 0; i < 4; ++i) ra[i] = As[k][tr * 4 + i];
#pragma unroll
            for (int j = 0; j < 4; ++j) rb[j] = Bs[k][tc * 4 + j];
#pragma unroll
            for (int i = 0; i < 4; ++i)
#pragma unroll
                for (int j = 0; j < 4; ++j) acc[i][j] += ra[i] * rb[j];
        }
        __syncthreads();
    }
#pragma unroll
    for (int i = 0; i < 4; ++i) {
        int gr = brow + tr * 4 + i;
        if (gr >= M) continue;
#pragma unroll
        for (int j = 0; j < 4; ++j) {
            int gc = bcol + tc * 4 + j;
            if (gc < N) C[(long)gr * N + gc] = acc[i][j];
        }
    }
}

// ---------------- final linear + log_softmax fused ----------------
__global__ __launch_bounds__(256)
void gemm_out_lsm(const float* __restrict__ A, const float* __restrict__ B,
                  float* __restrict__ out, int M) {
    const int BK = 16;
    __shared__ float As[BK][65];
    __shared__ float Bs[BK][65];
    __shared__ float tile[64][41];
    __shared__ float lsb[64];
    int tid = threadIdx.x;
    int tr = tid >> 4, tc = tid & 15;
    int brow = blockIdx.y * 64;
    float acc[4][4] = {{0.f}};
    for (int k0 = 0; k0 < 256; k0 += BK) {
#pragma unroll
        for (int i = 0; i < 4; ++i) {
            int e = tid + i * 256;
            int r = e >> 4, c = e & 15;
            int gr = brow + r;
            As[c][r] = (gr < M) ? A[(long)gr * 256 + k0 + c] : 0.f;
        }
#pragma unroll
        for (int i = 0; i < 4; ++i) {
            int e = tid + i * 256;
            int r = e >> 6, c = e & 63;
            Bs[r][c] = (c < FOUT) ? B[(long)(k0 + r) * FOUT + c] : 0.f;
        }
        __syncthreads();
#pragma unroll
        for (int k = 0; k < BK; ++k) {
            float ra[4], rb[4];
#pragma unroll
            for (int i = 0; i < 4; ++i) ra[i] = As[k][tr * 4 + i];
#pragma unroll
            for (int j = 0; j < 4; ++j) rb[j] = Bs[k][tc * 4 + j];
#pragma unroll
            for (int i = 0; i < 4; ++i)
#pragma unroll
                for (int j = 0; j < 4; ++j) acc[i][j] += ra[i] * rb[j];
        }
        __syncthreads();
    }
#pragma unroll
    for (int i = 0; i < 4; ++i)
#pragma unroll
        for (int j = 0; j < 4; ++j) {
            int gc = tc * 4 + j;
            if (gc < FOUT) tile[tr * 4 + i][gc] = acc[i][j];
        }
    __syncthreads();
    if (tid < 64) {
        int gr = brow + tid;
        float mx = -INFINITY;
        if (gr < M) {
            for (int c = 0; c < FOUT; ++c) mx = fmaxf(mx, tile[tid][c]);
            float s = 0.f;
            for (int c = 0; c < FOUT; ++c) s += __expf(tile[tid][c] - mx);
            lsb[tid] = mx + logf(s);
        }
    }
    __syncthreads();
#pragma unroll
    for (int i = 0; i < 4; ++i) {
        int r = tr * 4 + i;
        int gr = brow + r;
        if (gr >= M) continue;
#pragma unroll
        for (int j = 0; j < 4; ++j) {
            int gc = tc * 4 + j;
            if (gc < FOUT) out[(long)gr * FOUT + gc] = tile[r][gc] - lsb[r];
        }
    }
}

// ---------------- GAT pre-computation (wg_av + bias_proj fused) ----------------
__global__ void gat_prep(const float* __restrict__ W, const float* __restrict__ as_,
                         const float* __restrict__ ad_, const float* __restrict__ b_gat,
                         const float* __restrict__ W_etn,
                         float* __restrict__ asv, float* __restrict__ adv, float* __restrict__ b2) {
    int t = threadIdx.x;
    if (blockIdx.x == FE) {
        float s = 0.f;
        for (int i = 0; i < HD; ++i) s += b_gat[i] * W_etn[i * HD + t];
        b2[t] = s;
        return;
    }
    __shared__ float sm[256];
    int i = blockIdx.x;
    float w = W[i * HD + t];
    sm[t] = w * as_[t];
    __syncthreads();
    for (int o = 128; o > 0; o >>= 1) { if (t < o) sm[t] += sm[t + o]; __syncthreads(); }
    if (t == 0) asv[i] = sm[0];
    __syncthreads();
    sm[t] = w * ad_[t];
    __syncthreads();
    for (int o = 128; o > 0; o >>= 1) { if (t < o) sm[t] += sm[t + o]; __syncthreads(); }
    if (t == 0) adv[i] = sm[0];
}

__global__ void edge_scores_conv(const float* __restrict__ et, const float* __restrict__ asv,
                                 const float* __restrict__ adv, float* __restrict__ es,
                                 float* __restrict__ ed, unsigned short* __restrict__ et_bf) {
    int e = blockIdx.x * 4 + (threadIdx.x >> 6);
    int l = threadIdx.x & 63;
    float x = et[(long)e * FE + l];
    et_bf[(long)e * FE + l] = bf16rne(x);
    float vs = x * asv[l];
    float vd = x * adv[l];
    for (int o = 32; o > 0; o >>= 1) { vs += __shfl_down(vs, o); vd += __shfl_down(vd, o); }
    if (l == 0) { es[e] = vs; ed[e] = vd; }
}

// ---------------- GAT: scalar alpha (thread per segment) ----------------
__global__ void seg_alpha(const int* __restrict__ rowptr, const int* __restrict__ adj,
                          const float* __restrict__ es, const float* __restrict__ ed,
                          float* __restrict__ alphaS, float* __restrict__ alphaL) {
    int d = blockIdx.x * 256 + threadIdx.x;
    if (d >= EE) return;
    int b = rowptr[d], e_ = rowptr[d + 1];
    float edd = ed[d];
    float selfsc = leaky02(es[d] + edd);
    float m = selfsc;
    for (int i = b; i < e_; ++i) m = fmaxf(m, leaky02(es[adj[i]] + edd));
    float s = __expf(selfsc - m);
    for (int i = b; i < e_; ++i) s += __expf(leaky02(es[adj[i]] + edd) - m);
    float inv = 1.f / (s + 1e-16f);
    alphaS[d] = __expf(selfsc - m) * inv;
    for (int i = b; i < e_; ++i) alphaL[i] = __expf(leaky02(es[adj[i]] + edd) - m) * inv;
}

// ---------------- GAT: weighted gather (8-lane group, prefetched) ----------------
__global__ void gat_gather3(const int* __restrict__ rowptr, const int* __restrict__ adj,
                            const float* __restrict__ alphaS, const float* __restrict__ alphaL,
                            const unsigned short* __restrict__ et_bf,
                            unsigned short* __restrict__ agg_et) {
    int d = blockIdx.x * 32 + (threadIdx.x >> 3);
    int hl = threadIdx.x & 7;                  // row = 8 x uint4 (64 bf16)
    if (d >= EE) return;
    int b = rowptr[d], e_ = rowptr[d + 1];
    const uint4* etu = (const uint4*)et_bf;
    int i = b;
    float aln = 0.f; uint4 un;
    if (i < e_) { aln = alphaL[i]; un = etu[(size_t)adj[i] * 8 + hl]; }
    float al = alphaS[d];
    uint4 u = etu[(size_t)d * 8 + hl];
    float a0 = al * bflo(u.x), a1 = al * bfhi(u.x), a2 = al * bflo(u.y), a3 = al * bfhi(u.y);
    float a4 = al * bflo(u.z), a5 = al * bfhi(u.z), a6 = al * bflo(u.w), a7 = al * bfhi(u.w);
    while (i < e_) {
        float alc = aln; uint4 uc = un;
        int in = i + 1;
        if (in < e_) { aln = alphaL[in]; un = etu[(size_t)adj[in] * 8 + hl]; }
        a0 += alc * bflo(uc.x); a1 += alc * bfhi(uc.x); a2 += alc * bflo(uc.y); a3 += alc * bfhi(uc.y);
        a4 += alc * bflo(uc.z); a5 += alc * bfhi(uc.z); a6 += alc * bflo(uc.w); a7 += alc * bfhi(uc.w);
        i = in;
    }
    uint4 o;
    o.x = bfpack(a0, a1); o.y = bfpack(a2, a3); o.z = bfpack(a4, a5); o.w = bfpack(a6, a7);
    ((uint4*)agg_et)[(size_t)d * 8 + hl] = o;
}

// ---------------- incidence mean (8-lane group, uint4, prefetched) ----------------
__global__ void etn_gather3(const int* __restrict__ rowptr, const int* __restrict__ adj,
                            const unsigned short* __restrict__ agg_et,
                            unsigned short* __restrict__ agg2, float* __restrict__ degE) {
    int n = blockIdx.x * 32 + (threadIdx.x >> 3);
    int hl = threadIdx.x & 7;
    if (n >= NN) return;
    int b = rowptr[n], e_ = rowptr[n + 1];
    const uint4* au = (const uint4*)agg_et;
    int i = b;
    uint4 un;
    if (i < e_) un = au[(size_t)adj[i] * 8 + hl];
    float a0 = 0.f, a1 = 0.f, a2 = 0.f, a3 = 0.f, a4 = 0.f, a5 = 0.f, a6 = 0.f, a7 = 0.f;
    while (i < e_) {
        uint4 uc = un;
        int in = i + 1;
        if (in < e_) un = au[(size_t)adj[in] * 8 + hl];
        a0 += bflo(uc.x); a1 += bfhi(uc.x); a2 += bflo(uc.y); a3 += bfhi(uc.y);
        a4 += bflo(uc.z); a5 += bfhi(uc.z); a6 += bflo(uc.w); a7 += bfhi(uc.w);
        i = in;
    }
    float deg = (float)(e_ - b);
    float inv = 1.f / fmaxf(deg, 1.f);
    uint4 o;
    o.x = bfpack(a0 * inv, a1 * inv); o.y = bfpack(a2 * inv, a3 * inv);
    o.z = bfpack(a4 * inv, a5 * inv); o.w = bfpack(a6 * inv, a7 * inv);
    ((uint4*)agg2)[(size_t)n * 8 + hl] = o;
    if (hl == 0) degE[n] = deg;
}

// ---------------- SAGE mean (2 nodes/wave, 32-lane halves, prefetched) ----------------
__global__ void sage_gather2(const unsigned short* __restrict__ X, const int* __restrict__ rowptr,
                             const int* __restrict__ adjS, unsigned short* __restrict__ mean) {
    int base = (blockIdx.x * 4 + (threadIdx.x >> 6)) * 2;
    int lane = threadIdx.x & 63;
    int half = lane >> 5, hl = lane & 31;
    int n = base + half;
    if (n >= NN) return;
    int b = rowptr[n], e_ = rowptr[n + 1];
    const uint4* Xu = (const uint4*)X;
    int i = b;
    uint4 un;
    if (i < e_) un = Xu[(size_t)adjS[i] * 32 + hl];
    float a0 = 0.f, a1 = 0.f, a2 = 0.f, a3 = 0.f, a4 = 0.f, a5 = 0.f, a6 = 0.f, a7 = 0.f;
    while (i < e_) {
        uint4 uc = un;
        int in = i + 1;
        if (in < e_) un = Xu[(size_t)adjS[in] * 32 + hl];
        a0 += bflo(uc.x); a1 += bfhi(uc.x); a2 += bflo(uc.y); a3 += bfhi(uc.y);
        a4 += bflo(uc.z); a5 += bfhi(uc.z); a6 += bflo(uc.w); a7 += bfhi(uc.w);
        i = in;
    }
    float inv = 1.f / fmaxf((float)(e_ - b), 1.f);
    uint4 o;
    o.x = bfpack(a0 * inv, a1 * inv); o.y = bfpack(a2 * inv, a3 * inv);
    o.z = bfpack(a4 * inv, a5 * inv); o.w = bfpack(a6 * inv, a7 * inv);
    ((uint4*)mean)[(size_t)n * 32 + hl] = o;
}

// ---------------- MixAttention: online softmax, k/v prefetched 2 ahead ----------------
__global__ void attn_online(const unsigned short* __restrict__ q, const unsigned short* __restrict__ k,
                            const unsigned short* __restrict__ v, const unsigned short* __restrict__ nrep,
                            const int* __restrict__ rowptr, const int* __restrict__ adjS,
                            float* __restrict__ mixed) {
    int n = blockIdx.x * 4 + (threadIdx.x >> 6);
    int lane = threadIdx.x & 63;
    if (n >= NN) return;
    int half = lane >> 5, hl = lane & 31;
    int b = rowptr[n], e_ = rowptr[n + 1];
    const uint4* qu4 = (const uint4*)q;
    const uint4* ku4 = (const uint4*)k;
    const uint4* vu4 = (const uint4*)v;
    const uint4* nu4 = (const uint4*)nrep;
    uint4 nu = nu4[(size_t)n * 32 + hl];
    float nr0 = bflo(nu.x), nr1 = bfhi(nu.x), nr2 = bflo(nu.y), nr3 = bfhi(nu.y);
    float nr4 = bflo(nu.z), nr5 = bfhi(nu.z), nr6 = bflo(nu.w), nr7 = bfhi(nu.w);
    float* mrow = mixed + (size_t)n * HD;
    if (b == e_) {
        if (half == 0) {
            ((float4*)mrow)[2 * hl]     = make_float4(nr0, nr1, nr2, nr3);
            ((float4*)mrow)[2 * hl + 1] = make_float4(nr4, nr5, nr6, nr7);
        }
        return;
    }
    uint4 qv = qu4[(size_t)n * 32 + hl];
    float q0 = bflo(qv.x), q1 = bfhi(qv.x), q2 = bflo(qv.y), q3 = bfhi(qv.y);
    float q4 = bflo(qv.z), q5 = bfhi(qv.z), q6 = bflo(qv.w), q7 = bfhi(qv.w);
    float m = -INFINITY, srun = 0.f;
    float a0 = 0.f, a1 = 0.f, a2 = 0.f, a3 = 0.f, a4 = 0.f, a5 = 0.f, a6 = 0.f, a7 = 0.f;
    int i = b + half;
    uint4 ku, vu;
    if (i < e_) {
        int s0 = adjS[i];
        ku = ku4[(size_t)s0 * 32 + hl];
        vu = vu4[(size_t)s0 * 32 + hl];
    }
    while (i < e_) {
        int in = i + 2;
        uint4 kn, vn;
        if (in < e_) {
            int s1 = adjS[in];
            kn = ku4[(size_t)s1 * 32 + hl];
            vn = vu4[(size_t)s1 * 32 + hl];
        }
        float p = q0 * bflo(ku.x) + q1 * bfhi(ku.x) + q2 * bflo(ku.y) + q3 * bfhi(ku.y)
                + q4 * bflo(ku.z) + q5 * bfhi(ku.z) + q6 * bflo(ku.w) + q7 * bfhi(ku.w);
        p += __shfl_xor(p, 1); p += __shfl_xor(p, 2); p += __shfl_xor(p, 4);
        p += __shfl_xor(p, 8); p += __shfl_xor(p, 16);
        p *= 0.0625f;
        float mn = fmaxf(m, p);
        float scale = exp2f((m - mn) * LOG2E);
        float w = exp2f((p - mn) * LOG2E);
        m = mn;
        srun = srun * scale + w;
        a0 = a0 * scale + w * bflo(vu.x); a1 = a1 * scale + w * bfhi(vu.x);
        a2 = a2 * scale + w * bflo(vu.y); a3 = a3 * scale + w * bfhi(vu.y);
        a4 = a4 * scale + w * bflo(vu.z); a5 = a5 * scale + w * bfhi(vu.z);
        a6 = a6 * scale + w * bflo(vu.w); a7 = a7 * scale + w * bfhi(vu.w);
        i = in; ku = kn; vu = vn;
    }
    float mo = __shfl_xor(m, 32);
    float so = __shfl_xor(srun, 32);
    float mn = fmaxf(m, mo);
    float cs = exp2f((m - mn) * LOG2E);
    float co = exp2f((mo - mn) * LOG2E);
    float st = srun * cs + so * co;
    float inv = 1.f / (st + 1e-16f);
    float o0 = (a0 * cs + __shfl_xor(a0, 32) * co) * inv + nr0;
    float o1 = (a1 * cs + __shfl_xor(a1, 32) * co) * inv + nr1;
    float o2 = (a2 * cs + __shfl_xor(a2, 32) * co) * inv + nr2;
    float o3 = (a3 * cs + __shfl_xor(a3, 32) * co) * inv + nr3;
    float o4 = (a4 * cs + __shfl_xor(a4, 32) * co) * inv + nr4;
    float o5 = (a5 * cs + __shfl_xor(a5, 32) * co) * inv + nr5;
    float o6 = (a6 * cs + __shfl_xor(a6, 32) * co) * inv + nr6;
    float o7 = (a7 * cs + __shfl_xor(a7, 32) * co) * inv + nr7;
    if (half == 0) {
        ((float4*)mrow)[2 * hl]     = make_float4(o0, o1, o2, o3);
        ((float4*)mrow)[2 * hl + 1] = make_float4(o4, o5, o6, o7);
    }
}

extern "C" void kernel_launch(void* const* d_in, const int* in_sizes, int n_in,
                              void* d_out, int out_size, void* d_ws, size_t ws_size,
                              hipStream_t stream) {
    (void)in_sizes; (void)n_in; (void)out_size; (void)ws_size;
    const float* x     = (const float*)d_in[0];
    const float* et    = (const float*)d_in[1];
    const int*   Hm    = (const int*)d_in[2];
    const int*   raw   = (const int*)d_in[3];
    const int*   lg    = (const int*)d_in[4];
    const float* W_gat = (const float*)d_in[5];
    const float* a_src = (const float*)d_in[6];
    const float* a_dst = (const float*)d_in[7];
    const float* b_gat = (const float*)d_in[8];
    const float* W_etn = (const float*)d_in[9];
    const float* W_eg  = (const float*)d_in[10];
    const float* Wr_e1 = (const float*)d_in[11];
    const float* Wn_e1 = (const float*)d_in[12];
    const float* b_e1  = (const float*)d_in[13];
    const float* Wr_e2 = (const float*)d_in[14];
    const float* Wn_e2 = (const float*)d_in[15];
    const float* b_e2  = (const float*)d_in[16];
    const float* Wr_n1 = (const float*)d_in[17];
    const float* Wn_n1 = (const float*)d_in[18];
    const float* b_n1  = (const float*)d_in[19];
    const float* Wr_n2 = (const float*)d_in[20];
    const float* Wn_n2 = (const float*)d_in[21];
    const float* b_n2  = (const float*)d_in[22];
    const float* Wr_n3 = (const float*)d_in[23];
    const float* Wn_n3 = (const float*)d_in[24];
    const float* b_n3  = (const float*)d_in[25];
    const float* Wq    = (const float*)d_in[26];
    const float* Wk    = (const float*)d_in[27];
    const float* Wv    = (const float*)d_in[28];
    const float* W_out = (const float*)d_in[29];

    const int* srcN = raw;
    const int* dstN = raw + EE;
    const int* lgs  = lg;
    const int* lgd  = lg + ELG;

    float* ws = (float*)d_ws;
    size_t off = 0;
    auto alloc = [&](size_t n) { float* p = ws + off; off += (n + 63) & ~(size_t)63; return p; };
    auto allocU = [&](size_t nus) { return (unsigned short*)alloc(nus / 2 + 64); };

    unsigned short* et_bf   = allocU((size_t)EE * FE);
    unsigned short* agg_et  = allocU((size_t)EE * FE);   // reused later as q/k/v
    float* es     = alloc(EE);
    float* ed     = alloc(EE);
    float* alphaS = alloc(EE);
    float* alphaL = alloc(ELG);
    float* Wcomb  = alloc((size_t)FE * HD);
    float* b2     = alloc(HD);
    float* asv    = alloc(FE);
    float* adv    = alloc(FE);
    unsigned short* agg2_bf = allocU((size_t)NN * FE);
    float* degE   = alloc(NN);
    unsigned short* etnL  = allocU((size_t)NN * HD);
    unsigned short* erep  = allocU((size_t)NN * HD);
    unsigned short* meanb = allocU((size_t)NN * HD);
    unsigned short* t1    = allocU((size_t)NN * HD);
    unsigned short* aggr  = allocU((size_t)NN * HD);
    unsigned short* nrep  = allocU((size_t)NN * HD);
    unsigned short* x_bf  = allocU((size_t)NN * HD);
    float* mixed  = alloc((size_t)NN * HD);
    unsigned short* wtb    = allocU((size_t)14 * 65536);
    unsigned short* wcombt = allocU((size_t)HD * FE);
    int* rowptrD  = (int*)alloc(NN + 64);
    int* adjS     = (int*)alloc(EE);
    int* rowptrLG = (int*)alloc(EE + 64);
    int* adjLG    = (int*)alloc(ELG);
    int* rowptrH  = (int*)alloc(NN + 64);
    int* adjH     = (int*)alloc(2 * EE);
    int* cntAll   = (int*)alloc(NTOTC + 64);
    int* scanAll  = (int*)alloc(NTOTC + 64);
    int* bsum     = (int*)alloc(1024);
    // aliases (lifetime-checked)
    unsigned short* ta = etnL;                 // etnL dead after erep GEMM
    unsigned short* tb = erep;                 // erep dead after edge layer 1
    unsigned short* qb = agg_et;               // agg_et dead after etn_gather
    unsigned short* kb = agg_et + (size_t)NN * HD;
    unsigned short* vb = agg_et + (size_t)2 * NN * HD;
    float* outp = (float*)d_out;

    unsigned short* W_eg_t  = wtb + 0 * 65536;
    unsigned short* Wr_e1_t = wtb + 1 * 65536;
    unsigned short* Wn_e1_t = wtb + 2 * 65536;
    unsigned short* Wr_e2_t = wtb + 3 * 65536;
    unsigned short* Wn_e2_t = wtb + 4 * 65536;
    unsigned short* Wr_n1_t = wtb + 5 * 65536;
    unsigned short* Wn_n1_t = wtb + 6 * 65536;
    unsigned short* Wr_n2_t = wtb + 7 * 65536;
    unsigned short* Wn_n2_t = wtb + 8 * 65536;
    unsigned short* Wr_n3_t = wtb + 9 * 65536;
    unsigned short* Wn_n3_t = wtb + 10 * 65536;
    unsigned short* Wq_t    = wtb + 11 * 65536;
    unsigned short* Wk_t    = wtb + 12 * 65536;
    unsigned short* Wv_t    = wtb + 13 * 65536;

    dim3 gB(4, (NN + 127) / 128);

    // ======== weight conversion + x conversion ========
    Ptr14 p14;
    p14.p[0] = W_eg;  p14.p[1] = Wr_e1; p14.p[2] = Wn_e1; p14.p[3] = Wr_e2;
    p14.p[4] = Wn_e2; p14.p[5] = Wr_n1; p14.p[6] = Wn_n1; p14.p[7] = Wr_n2;
    p14.p[8] = Wn_n2; p14.p[9] = Wr_n3; p14.p[10] = Wn_n3; p14.p[11] = Wq;
    p14.p[12] = Wk;   p14.p[13] = Wv;
    wtrans14<<<14 * 64, 256, 0, stream>>>(p14, wtb);
    conv_bf16<<<(NN * HD / 2 + 255) / 256, 256, 0, stream>>>(x, (unsigned int*)x_bf, NN * HD / 2);

    // ======== privatized CSR build (LDS histograms / LDS cursors; no global atomics) ========
    count_priv<<<DCLS + LGCLS + HCLS, 256, 0, stream>>>(dstN, lgd, Hm, cntAll);
    {
        int nb = (NTOTC + 1023) / 1024;
        scan_pass1<<<nb, 256, 0, stream>>>(cntAll, bsum, NTOTC);
        scan_pass2<<<1, 256, 0, stream>>>(bsum, nb);
        scan_pass3<<<nb, 256, 0, stream>>>(cntAll, bsum, scanAll, NTOTC);
    }
    rebase_all<<<(NTOTC + 255) / 256, 256, 0, stream>>>(scanAll, rowptrD, rowptrLG, rowptrH);
    place_priv<<<DCLS + LGCLS + HCLS, 256, 0, stream>>>(srcN, dstN, lgs, lgd, Hm,
                                                        rowptrD, rowptrLG, rowptrH,
                                                        adjS, adjLG, adjH);

    // ======== GAT (folded Wcomb = W_gat@W_etn) ========
    gemm_f32<<<dim3(4, 1), 256, 0, stream>>>(W_gat, W_etn, Wcomb, FE, HD, HD);
    wtrans_one<<<(FE / 32) * (HD / 32), 256, 0, stream>>>(Wcomb, wcombt, FE, HD);
    gat_prep<<<FE + 1, 256, 0, stream>>>(W_gat, a_src, a_dst, b_gat, W_etn, asv, adv, b2);
    edge_scores_conv<<<EE / 4, 256, 0, stream>>>(et, asv, adv, es, ed, et_bf);
    seg_alpha<<<(EE + 255) / 256, 256, 0, stream>>>(rowptrLG, adjLG, es, ed, alphaS, alphaL);
    gat_gather3<<<EE / 32, 256, 0, stream>>>(rowptrLG, adjLG, alphaS, alphaL, et_bf, agg_et);

    // ======== EdgeToNode incidence mean + GEMMs ========
    etn_gather3<<<(NN + 31) / 32, 256, 0, stream>>>(rowptrH, adjH, agg_et, agg2_bf, degE);
    gemm_bf16<<<gB, 256, 0, stream>>>(agg2_bf, nullptr, wcombt, nullptr, b2, degE, etnL, NN, FE, 4);
    gemm_bf16<<<gB, 256, 0, stream>>>(etnL, nullptr, W_eg_t, nullptr, nullptr, nullptr, erep, NN, HD, 0);

    // ======== edge_aggr SAGE (2 layers, dual-K fused) ========
    sage_gather2<<<(NN + 7) / 8, 256, 0, stream>>>(erep, rowptrD, adjS, meanb);
    gemm_bf16<<<gB, 256, 0, stream>>>(erep, meanb, Wr_e1_t, Wn_e1_t, b_e1, nullptr, t1, NN, HD, 1);
    sage_gather2<<<(NN + 7) / 8, 256, 0, stream>>>(t1, rowptrD, adjS, meanb);
    gemm_bf16<<<gB, 256, 0, stream>>>(t1, meanb, Wr_e2_t, Wn_e2_t, b_e2, nullptr, aggr, NN, HD, 0);

    // ======== attr_node SAGE (3 layers, dual-K fused) ========
    sage_gather2<<<(NN + 7) / 8, 256, 0, stream>>>(x_bf, rowptrD, adjS, meanb);
    gemm_bf16<<<gB, 256, 0, stream>>>(x_bf, meanb, Wr_n1_t, Wn_n1_t, b_n1, nullptr, ta, NN, HD, 1);
    sage_gather2<<<(NN + 7) / 8, 256, 0, stream>>>(ta, rowptrD, adjS, meanb);
    gemm_bf16<<<gB, 256, 0, stream>>>(ta, meanb, Wr_n2_t, Wn_n2_t, b_n2, nullptr, tb, NN, HD, 1);
    sage_gather2<<<(NN + 7) / 8, 256, 0, stream>>>(tb, rowptrD, adjS, meanb);
    gemm_bf16<<<gB, 256, 0, stream>>>(tb, meanb, Wr_n3_t, Wn_n3_t, b_n3, nullptr, nrep, NN, HD, 0);

    // ======== MixAttention (q,k,v in ONE launch) ========
    gemm_bf16_tri<<<dim3(12, (NN + 127) / 128), 256, 0, stream>>>(
        nrep, Wq_t, qb, aggr, Wk_t, kb, aggr, Wv_t, vb, NN);
    attn_online<<<(NN + 3) / 4, 256, 0, stream>>>(qb, kb, vb, nrep, rowptrD, adjS, mixed);

    // ======== final linear + log_softmax (fused) ========
    gemm_out_lsm<<<dim3(1, (NN + 63) / 64), 256, 0, stream>>>(mixed, W_out, outp, NN);
}

// Round 11
// 847.029 us; speedup vs baseline: 3.2591x; 3.2591x over previous
//
#include <hip/hip_runtime.h>
#include <math.h>

#define NN   20000
#define EE   320000
#define ELG  600000
#define FE   64
#define HD   256
#define FOUT 40
#define LOG2E 1.44269504f
#define NTOTC (NN + EE + NN)            // concatenated count-buffer size
#define NIDX  (EE + ELG + 2 * EE)       // concatenated index-stream size
#define RD_RANGE  ((NN + 7) / 8)        // keys per XCD range (D and H sections)
#define RLG_RANGE ((EE + 7) / 8)        // keys per XCD range (LG section)
#define PBLK 256                        // persistent blocks per XCD class

typedef __attribute__((ext_vector_type(8))) short bf16x8;
typedef __attribute__((ext_vector_type(4))) float f32x4;

__device__ __forceinline__ float leaky02(float x) { return x > 0.f ? x : 0.2f * x; }

__device__ __forceinline__ unsigned short bf16rne(float f) {
    unsigned int u = __float_as_uint(f);
    u = (u + 0x7FFFu + ((u >> 16) & 1u)) >> 16;
    return (unsigned short)u;
}
__device__ __forceinline__ float bflo(unsigned int u) { return __uint_as_float(u << 16); }
__device__ __forceinline__ float bfhi(unsigned int u) { return __uint_as_float(u & 0xffff0000u); }
__device__ __forceinline__ unsigned int bfpack(float a, float b) {
    return (unsigned int)bf16rne(a) | ((unsigned int)bf16rne(b) << 16);
}

// ---------------- small utility kernels ----------------
__global__ void zero_i32(int* __restrict__ p, int n) {
    int i = blockIdx.x * 256 + threadIdx.x;
    if (i < n) p[i] = 0;
}
__global__ void conv_bf16(const float* __restrict__ in, unsigned int* __restrict__ out, int n2) {
    int i = blockIdx.x * 256 + threadIdx.x;
    if (i < n2) { float2 v = ((const float2*)in)[i]; out[i] = bfpack(v.x, v.y); }
}

// ---------------- consolidated CSR build (round-9 persistent XCD-class kernels) ----------------
// cntAll sections: [0,NN) = raw-by-dst, [NN,NN+EE) = lg-by-lgd, [NN+EE,NN+EE+NN) = incidence H
__global__ __launch_bounds__(256)
void count_ranged(const int* __restrict__ dstN, const int* __restrict__ lgd,
                  const int* __restrict__ Hm, int* __restrict__ cntAll) {
    int r = blockIdx.x & 7;
    int blk = blockIdx.x >> 3;
    const int stride = PBLK * 256;
    for (int i = blk * 256 + threadIdx.x; i < NIDX; i += stride) {
        if (i < EE) {
            int key = dstN[i];
            if (key / RD_RANGE == r) atomicAdd(&cntAll[key], 1);
        } else if (i < EE + ELG) {
            int key = lgd[i - EE];
            if (key / RLG_RANGE == r) atomicAdd(&cntAll[NN + key], 1);
        } else {
            int key = Hm[i - EE - ELG];
            if (key / RD_RANGE == r) atomicAdd(&cntAll[NN + EE + key], 1);
        }
    }
}

__global__ void scan_pass1(const int* __restrict__ in, int* __restrict__ bsum, int n) {
    __shared__ int sm[256];
    int base = blockIdx.x * 1024, t = threadIdx.x;
    int s = 0;
#pragma unroll
    for (int j = 0; j < 4; ++j) { int i = base + t * 4 + j; s += (i < n) ? in[i] : 0; }
    sm[t] = s; __syncthreads();
    for (int o = 128; o > 0; o >>= 1) { if (t < o) sm[t] += sm[t + o]; __syncthreads(); }
    if (t == 0) bsum[blockIdx.x] = sm[0];
}
__global__ void scan_pass2(int* __restrict__ bsum, int nb) {
    __shared__ int sm[1024];
    int t = threadIdx.x;
    for (int i = t; i < nb; i += 256) sm[i] = bsum[i];
    __syncthreads();
    if (t == 0) { int run = 0; for (int i = 0; i < nb; ++i) { int v = sm[i]; sm[i] = run; run += v; } }
    __syncthreads();
    for (int i = t; i < nb; i += 256) bsum[i] = sm[i];
}
__global__ void scan_pass3(const int* __restrict__ in, const int* __restrict__ boff,
                           int* __restrict__ out, int n) {
    __shared__ int tsum[256];
    int base = blockIdx.x * 1024, t = threadIdx.x;
    int v[4];
#pragma unroll
    for (int j = 0; j < 4; ++j) { int i = base + t * 4 + j; v[j] = (i < n) ? in[i] : 0; }
    int loc = v[0] + v[1] + v[2] + v[3];
    tsum[t] = loc; __syncthreads();
    for (int o = 1; o < 256; o <<= 1) {
        int x = (t >= o) ? tsum[t - o] : 0;
        __syncthreads();
        tsum[t] += x;
        __syncthreads();
    }
    int off = boff[blockIdx.x] + (tsum[t] - loc);
    int run = 0;
#pragma unroll
    for (int j = 0; j < 4; ++j) { int i = base + t * 4 + j; if (i < n) out[i] = off + run; run += v[j]; }
}

// section-rebased rowptr + cursor init (one pass)
__global__ void rebase_all(const int* __restrict__ scanAll,
                           int* __restrict__ rowptrD, int* __restrict__ cursD,
                           int* __restrict__ rowptrLG, int* __restrict__ cursLG,
                           int* __restrict__ rowptrH, int* __restrict__ cursH) {
    int i = blockIdx.x * 256 + threadIdx.x;
    if (i == 0) { rowptrD[NN] = EE; rowptrLG[EE] = ELG; rowptrH[NN] = 2 * EE; }
    if (i >= NTOTC) return;
    if (i < NN) { int v = scanAll[i]; rowptrD[i] = v; cursD[i] = v; }
    else if (i < NN + EE) { int v = scanAll[i] - EE; rowptrLG[i - NN] = v; cursLG[i - NN] = v; }
    else { int v = scanAll[i] - (EE + ELG); rowptrH[i - NN - EE] = v; cursH[i - NN - EE] = v; }
}

__global__ __launch_bounds__(256)
void place_ranged(const int* __restrict__ srcN, const int* __restrict__ dstN,
                  const int* __restrict__ lgs, const int* __restrict__ lgd,
                  const int* __restrict__ Hm,
                  int* __restrict__ cursD, int* __restrict__ cursLG, int* __restrict__ cursH,
                  int* __restrict__ adjS, int* __restrict__ adjLG, int* __restrict__ adjH) {
    int r = blockIdx.x & 7;
    int blk = blockIdx.x >> 3;
    const int stride = PBLK * 256;
    for (int i = blk * 256 + threadIdx.x; i < NIDX; i += stride) {
        if (i < EE) {
            int key = dstN[i];
            if (key / RD_RANGE == r) {
                int pos = atomicAdd(&cursD[key], 1);
                adjS[pos] = srcN[i];
            }
        } else if (i < EE + ELG) {
            int j = i - EE;
            int key = lgd[j];
            if (key / RLG_RANGE == r) {
                int pos = atomicAdd(&cursLG[key], 1);
                adjLG[pos] = lgs[j];
            }
        } else {
            int j = i - EE - ELG;
            int key = Hm[j];
            if (key / RD_RANGE == r) {
                int pos = atomicAdd(&cursH[key], 1);
                adjH[pos] = (j < EE) ? j : j - EE;
            }
        }
    }
}

// ---------------- weight transpose+convert ----------------
struct Ptr14 { const float* p[14]; };
__global__ void wtrans14(Ptr14 srcs, unsigned short* __restrict__ dst) {
    int m = blockIdx.x >> 6;
    int tile = blockIdx.x & 63;
    const float* src = srcs.p[m];
    unsigned short* out = dst + (size_t)m * 65536;
    int kb = (tile >> 3) * 32, nb = (tile & 7) * 32;
    __shared__ float sm[32][33];
    int t = threadIdx.x;
#pragma unroll
    for (int i = 0; i < 4; ++i) {
        int e = t + i * 256; int r = e >> 5, c = e & 31;
        sm[r][c] = src[(kb + r) * 256 + nb + c];
    }
    __syncthreads();
#pragma unroll
    for (int i = 0; i < 4; ++i) {
        int e = t + i * 256; int nr = e >> 5, kc = e & 31;
        out[(size_t)(nb + nr) * 256 + kb + kc] = bf16rne(sm[kc][nr]);
    }
}
__global__ void wtrans_one(const float* __restrict__ src, unsigned short* __restrict__ dst,
                           int K, int N) {
    int tilesN = N >> 5;
    int kb = (blockIdx.x / tilesN) * 32, nb = (blockIdx.x % tilesN) * 32;
    __shared__ float sm[32][33];
    int t = threadIdx.x;
#pragma unroll
    for (int i = 0; i < 4; ++i) {
        int e = t + i * 256; int r = e >> 5, c = e & 31;
        sm[r][c] = src[(kb + r) * N + nb + c];
    }
    __syncthreads();
#pragma unroll
    for (int i = 0; i < 4; ++i) {
        int e = t + i * 256; int nr = e >> 5, kc = e & 31;
        dst[(size_t)(nb + nr) * K + kb + kc] = bf16rne(sm[kc][nr]);
    }
}

// ---------------- bf16 MFMA GEMM ----------------
// flags: 1=relu, 4=degE-mask + leaky
__global__ __launch_bounds__(256)
void gemm_bf16(const unsigned short* __restrict__ A1, const unsigned short* __restrict__ A2,
               const unsigned short* __restrict__ W1, const unsigned short* __restrict__ W2,
               const float* __restrict__ bias, const float* __restrict__ degmask,
               unsigned short* __restrict__ C, int M, int K1, int flags) {
    __shared__ unsigned short As[128][40];
    __shared__ unsigned short Bs[64][40];
    int tid = threadIdx.x;
    int w = tid >> 6, l = tid & 63;
    int wr = w >> 1, wc = w & 1;
    int brow = blockIdx.y * 128, bcol = blockIdx.x * 64;
    int Ktot = K1 + (A2 ? 256 : 0);
    f32x4 acc[4][2] = {};
    for (int k0 = 0; k0 < Ktot; k0 += 32) {
        const unsigned short* Ap; const unsigned short* Wp; int kk, Klen;
        if (k0 < K1) { Ap = A1; Wp = W1; kk = k0; Klen = K1; }
        else         { Ap = A2; Wp = W2; kk = k0 - K1; Klen = 256; }
#pragma unroll
        for (int i = 0; i < 4; ++i) {
            int q = tid + i * 256;
            int r = q >> 3, kb = (q & 7) * 4;
            int gr = brow + r;
            ushort4 u;
            if (gr < M) u = *(const ushort4*)(Ap + (size_t)gr * Klen + kk + kb);
            else { u.x = 0; u.y = 0; u.z = 0; u.w = 0; }
            *(ushort4*)(&As[r][kb]) = u;
        }
#pragma unroll
        for (int i = 0; i < 2; ++i) {
            int q = tid + i * 256;
            int n = q >> 3, kb = (q & 7) * 4;
            *(ushort4*)(&Bs[n][kb]) = *(const ushort4*)(Wp + (size_t)(bcol + n) * Klen + kk + kb);
        }
        __syncthreads();
        bf16x8 af[4], bfr[2];
#pragma unroll
        for (int fr = 0; fr < 4; ++fr)
            af[fr] = *(const bf16x8*)(&As[wr * 64 + fr * 16 + (l & 15)][(l >> 4) * 8]);
#pragma unroll
        for (int fc = 0; fc < 2; ++fc)
            bfr[fc] = *(const bf16x8*)(&Bs[wc * 32 + fc * 16 + (l & 15)][(l >> 4) * 8]);
#pragma unroll
        for (int fr = 0; fr < 4; ++fr)
#pragma unroll
            for (int fc = 0; fc < 2; ++fc)
                acc[fr][fc] = __builtin_amdgcn_mfma_f32_16x16x32_bf16(af[fr], bfr[fc], acc[fr][fc], 0, 0, 0);
        __syncthreads();
    }
#pragma unroll
    for (int fr = 0; fr < 4; ++fr) {
#pragma unroll
        for (int fc = 0; fc < 2; ++fc) {
            int col = bcol + wc * 32 + fc * 16 + (l & 15);
#pragma unroll
            for (int i = 0; i < 4; ++i) {
                int row = brow + wr * 64 + fr * 16 + (l >> 4) * 4 + i;
                if (row >= M) continue;
                float v = acc[fr][fc][i];
                if (bias) v += bias[col];
                if (flags & 1) v = fmaxf(v, 0.f);
                if (flags & 4) { v = (degmask[row] > 0.f) ? v : 0.f; v = leaky02(v); }
                C[(size_t)row * 256 + col] = bf16rne(v);
            }
        }
    }
}

// three single-K GEMMs in one launch
__global__ __launch_bounds__(256)
void gemm_bf16_tri(const unsigned short* __restrict__ A0, const unsigned short* __restrict__ W0,
                   unsigned short* __restrict__ C0,
                   const unsigned short* __restrict__ A1, const unsigned short* __restrict__ W1,
                   unsigned short* __restrict__ C1,
                   const unsigned short* __restrict__ A2, const unsigned short* __restrict__ W2,
                   unsigned short* __restrict__ C2, int M) {
    __shared__ unsigned short As[128][40];
    __shared__ unsigned short Bs[64][40];
    int sel = blockIdx.x >> 2;
    const unsigned short* A = (sel == 0) ? A0 : (sel == 1) ? A1 : A2;
    const unsigned short* W = (sel == 0) ? W0 : (sel == 1) ? W1 : W2;
    unsigned short* C = (sel == 0) ? C0 : (sel == 1) ? C1 : C2;
    int tid = threadIdx.x;
    int w = tid >> 6, l = tid & 63;
    int wr = w >> 1, wc = w & 1;
    int brow = blockIdx.y * 128, bcol = (blockIdx.x & 3) * 64;
    f32x4 acc[4][2] = {};
    for (int k0 = 0; k0 < 256; k0 += 32) {
#pragma unroll
        for (int i = 0; i < 4; ++i) {
            int q = tid + i * 256;
            int r = q >> 3, kb = (q & 7) * 4;
            int gr = brow + r;
            ushort4 u;
            if (gr < M) u = *(const ushort4*)(A + (size_t)gr * 256 + k0 + kb);
            else { u.x = 0; u.y = 0; u.z = 0; u.w = 0; }
            *(ushort4*)(&As[r][kb]) = u;
        }
#pragma unroll
        for (int i = 0; i < 2; ++i) {
            int q = tid + i * 256;
            int n = q >> 3, kb = (q & 7) * 4;
            *(ushort4*)(&Bs[n][kb]) = *(const ushort4*)(W + (size_t)(bcol + n) * 256 + k0 + kb);
        }
        __syncthreads();
        bf16x8 af[4], bfr[2];
#pragma unroll
        for (int fr = 0; fr < 4; ++fr)
            af[fr] = *(const bf16x8*)(&As[wr * 64 + fr * 16 + (l & 15)][(l >> 4) * 8]);
#pragma unroll
        for (int fc = 0; fc < 2; ++fc)
            bfr[fc] = *(const bf16x8*)(&Bs[wc * 32 + fc * 16 + (l & 15)][(l >> 4) * 8]);
#pragma unroll
        for (int fr = 0; fr < 4; ++fr)
#pragma unroll
            for (int fc = 0; fc < 2; ++fc)
                acc[fr][fc] = __builtin_amdgcn_mfma_f32_16x16x32_bf16(af[fr], bfr[fc], acc[fr][fc], 0, 0, 0);
        __syncthreads();
    }
#pragma unroll
    for (int fr = 0; fr < 4; ++fr) {
#pragma unroll
        for (int fc = 0; fc < 2; ++fc) {
            int col = bcol + wc * 32 + fc * 16 + (l & 15);
#pragma unroll
            for (int i = 0; i < 4; ++i) {
                int row = brow + wr * 64 + fr * 16 + (l >> 4) * 4 + i;
                if (row >= M) continue;
                C[(size_t)row * 256 + col] = bf16rne(acc[fr][fc][i]);
            }
        }
    }
}

// ---------------- fp32 GEMM (Wcomb build only) ----------------
__global__ __launch_bounds__(256)
void gemm_f32(const float* __restrict__ A, const float* __restrict__ B,
              float* __restrict__ C, int M, int N, int K) {
    const int BM = 64, BN = 64, BK = 16;
    __shared__ float As[BK][BM + 1];
    __shared__ float Bs[BK][BN + 1];
    int tid = threadIdx.x;
    int tr = tid >> 4, tc = tid & 15;
    int brow = blockIdx.y * BM, bcol = blockIdx.x * BN;
    float acc[4][4] = {{0.f}};
    for (int k0 = 0; k0 < K; k0 += BK) {
#pragma unroll
        for (int i = 0; i < 4; ++i) {
            int e = tid + i * 256;
            int r = e >> 4, c = e & 15;
            int gr = brow + r, gc = k0 + c;
            As[c][r] = (gr < M && gc < K) ? A[(long)gr * K + gc] : 0.f;
        }
#pragma unroll
        for (int i = 0; i < 4; ++i) {
            int e = tid + i * 256;
            int r = e >> 6, c = e & 63;
            int gr = k0 + r, gc = bcol + c;
            Bs[r][c] = (gr < K && gc < N) ? B[(long)gr * N + gc] : 0.f;
        }
        __syncthreads();
#pragma unroll
        for (int k = 0; k < BK; ++k) {
            float ra[4], rb[4];
#pragma unroll
            for (int i = 0; i < 4; ++i) ra[i] = As[k][tr * 4 + i];
#pragma unroll
            for (int j = 0; j < 4; ++j) rb[j] = Bs[k][tc * 4 + j];
#pragma unroll
            for (int i = 0; i < 4; ++i)
#pragma unroll
                for (int j = 0; j < 4; ++j) acc[i][j] += ra[i] * rb[j];
        }
        __syncthreads();
    }
#pragma unroll
    for (int i = 0; i < 4; ++i) {
        int gr = brow + tr * 4 + i;
        if (gr >= M) continue;
#pragma unroll
        for (int j = 0; j < 4; ++j) {
            int gc = bcol + tc * 4 + j;
            if (gc < N) C[(long)gr * N + gc] = acc[i][j];
        }
    }
}

// ---------------- final linear + log_softmax fused ----------------
__global__ __launch_bounds__(256)
void gemm_out_lsm(const float* __restrict__ A, const float* __restrict__ B,
                  float* __restrict__ out, int M) {
    const int BK = 16;
    __shared__ float As[BK][65];
    __shared__ float Bs[BK][65];
    __shared__ float tile[64][41];
    __shared__ float lsb[64];
    int tid = threadIdx.x;
    int tr = tid >> 4, tc = tid & 15;
    int brow = blockIdx.y * 64;
    float acc[4][4] = {{0.f}};
    for (int k0 = 0; k0 < 256; k0 += BK) {
#pragma unroll
        for (int i = 0; i < 4; ++i) {
            int e = tid + i * 256;
            int r = e >> 4, c = e & 15;
            int gr = brow + r;
            As[c][r] = (gr < M) ? A[(long)gr * 256 + k0 + c] : 0.f;
        }
#pragma unroll
        for (int i = 0; i < 4; ++i) {
            int e = tid + i * 256;
            int r = e >> 6, c = e & 63;
            Bs[r][c] = (c < FOUT) ? B[(long)(k0 + r) * FOUT + c] : 0.f;
        }
        __syncthreads();
#pragma unroll
        for (int k = 0; k < BK; ++k) {
            float ra[4], rb[4];
#pragma unroll
            for (int i = 0; i < 4; ++i) ra[i] = As[k][tr * 4 + i];
#pragma unroll
            for (int j = 0; j < 4; ++j) rb[j] = Bs[k][tc * 4 + j];
#pragma unroll
            for (int i = 0; i < 4; ++i)
#pragma unroll
                for (int j = 0; j < 4; ++j) acc[i][j] += ra[i] * rb[j];
        }
        __syncthreads();
    }
#pragma unroll
    for (int i = 0; i < 4; ++i)
#pragma unroll
        for (int j = 0; j < 4; ++j) {
            int gc = tc * 4 + j;
            if (gc < FOUT) tile[tr * 4 + i][gc] = acc[i][j];
        }
    __syncthreads();
    if (tid < 64) {
        int gr = brow + tid;
        float mx = -INFINITY;
        if (gr < M) {
            for (int c = 0; c < FOUT; ++c) mx = fmaxf(mx, tile[tid][c]);
            float s = 0.f;
            for (int c = 0; c < FOUT; ++c) s += __expf(tile[tid][c] - mx);
            lsb[tid] = mx + logf(s);
        }
    }
    __syncthreads();
#pragma unroll
    for (int i = 0; i < 4; ++i) {
        int r = tr * 4 + i;
        int gr = brow + r;
        if (gr >= M) continue;
#pragma unroll
        for (int j = 0; j < 4; ++j) {
            int gc = tc * 4 + j;
            if (gc < FOUT) out[(long)gr * FOUT + gc] = tile[r][gc] - lsb[r];
        }
    }
}

// ---------------- GAT pre-computation (wg_av + bias_proj fused) ----------------
__global__ void gat_prep(const float* __restrict__ W, const float* __restrict__ as_,
                         const float* __restrict__ ad_, const float* __restrict__ b_gat,
                         const float* __restrict__ W_etn,
                         float* __restrict__ asv, float* __restrict__ adv, float* __restrict__ b2) {
    int t = threadIdx.x;
    if (blockIdx.x == FE) {
        float s = 0.f;
        for (int i = 0; i < HD; ++i) s += b_gat[i] * W_etn[i * HD + t];
        b2[t] = s;
        return;
    }
    __shared__ float sm[256];
    int i = blockIdx.x;
    float w = W[i * HD + t];
    sm[t] = w * as_[t];
    __syncthreads();
    for (int o = 128; o > 0; o >>= 1) { if (t < o) sm[t] += sm[t + o]; __syncthreads(); }
    if (t == 0) asv[i] = sm[0];
    __syncthreads();
    sm[t] = w * ad_[t];
    __syncthreads();
    for (int o = 128; o > 0; o >>= 1) { if (t < o) sm[t] += sm[t + o]; __syncthreads(); }
    if (t == 0) adv[i] = sm[0];
}

__global__ void edge_scores_conv(const float* __restrict__ et, const float* __restrict__ asv,
                                 const float* __restrict__ adv, float* __restrict__ es,
                                 float* __restrict__ ed, unsigned short* __restrict__ et_bf) {
    int e = blockIdx.x * 4 + (threadIdx.x >> 6);
    int l = threadIdx.x & 63;
    float x = et[(long)e * FE + l];
    et_bf[(long)e * FE + l] = bf16rne(x);
    float vs = x * asv[l];
    float vd = x * adv[l];
    for (int o = 32; o > 0; o >>= 1) { vs += __shfl_down(vs, o); vd += __shfl_down(vd, o); }
    if (l == 0) { es[e] = vs; ed[e] = vd; }
}

// ---------------- GAT: fused alpha + gather (8-lane group, online softmax, one pass) ----------------
// Scores are per-entry SCALARS (leaky(es[src]+ed[d])), so all 8 lanes compute them
// redundantly (es/ed are L1/L2-hot) and the softmax runs online over the segment while
// the 8-wide uint4 feature slices accumulate — no alpha buffers, no second pass.
__global__ void gat_fused2(const int* __restrict__ rowptr, const int* __restrict__ adj,
                           const float* __restrict__ es, const float* __restrict__ ed,
                           const unsigned short* __restrict__ et_bf,
                           unsigned short* __restrict__ agg_et) {
    int d = blockIdx.x * 32 + (threadIdx.x >> 3);
    int hl = threadIdx.x & 7;                  // row = 8 x uint4 (64 bf16)
    if (d >= EE) return;
    int b = rowptr[d], e_ = rowptr[d + 1];
    const uint4* etu = (const uint4*)et_bf;
    float edd = ed[d];
    // self entry first: m = selfsc, s = 1, acc = et[d]
    float m = leaky02(es[d] + edd);
    float srun = 1.f;
    uint4 u = etu[(size_t)d * 8 + hl];
    float a0 = bflo(u.x), a1 = bfhi(u.x), a2 = bflo(u.y), a3 = bfhi(u.y);
    float a4 = bflo(u.z), a5 = bfhi(u.z), a6 = bflo(u.w), a7 = bfhi(u.w);
    // prefetch first neighbor
    int i = b;
    float esn = 0.f; uint4 un;
    if (i < e_) { int s0 = adj[i]; esn = es[s0]; un = etu[(size_t)s0 * 8 + hl]; }
    while (i < e_) {
        float esc = esn; uint4 uc = un;
        int in = i + 1;
        if (in < e_) { int s1 = adj[in]; esn = es[s1]; un = etu[(size_t)s1 * 8 + hl]; }
        float p = leaky02(esc + edd);
        float mn = fmaxf(m, p);
        float scale = exp2f((m - mn) * LOG2E);
        float w = exp2f((p - mn) * LOG2E);
        m = mn;
        srun = srun * scale + w;
        a0 = a0 * scale + w * bflo(uc.x); a1 = a1 * scale + w * bfhi(uc.x);
        a2 = a2 * scale + w * bflo(uc.y); a3 = a3 * scale + w * bfhi(uc.y);
        a4 = a4 * scale + w * bflo(uc.z); a5 = a5 * scale + w * bfhi(uc.z);
        a6 = a6 * scale + w * bflo(uc.w); a7 = a7 * scale + w * bfhi(uc.w);
        i = in;
    }
    float inv = 1.f / (srun + 1e-16f);
    uint4 o;
    o.x = bfpack(a0 * inv, a1 * inv); o.y = bfpack(a2 * inv, a3 * inv);
    o.z = bfpack(a4 * inv, a5 * inv); o.w = bfpack(a6 * inv, a7 * inv);
    ((uint4*)agg_et)[(size_t)d * 8 + hl] = o;
}

// ---------------- incidence mean (8-lane group, uint4, prefetched) ----------------
__global__ void etn_gather3(const int* __restrict__ rowptr, const int* __restrict__ adj,
                            const unsigned short* __restrict__ agg_et,
                            unsigned short* __restrict__ agg2, float* __restrict__ degE) {
    int n = blockIdx.x * 32 + (threadIdx.x >> 3);
    int hl = threadIdx.x & 7;
    if (n >= NN) return;
    int b = rowptr[n], e_ = rowptr[n + 1];
    const uint4* au = (const uint4*)agg_et;
    int i = b;
    uint4 un;
    if (i < e_) un = au[(size_t)adj[i] * 8 + hl];
    float a0 = 0.f, a1 = 0.f, a2 = 0.f, a3 = 0.f, a4 = 0.f, a5 = 0.f, a6 = 0.f, a7 = 0.f;
    while (i < e_) {
        uint4 uc = un;
        int in = i + 1;
        if (in < e_) un = au[(size_t)adj[in] * 8 + hl];
        a0 += bflo(uc.x); a1 += bfhi(uc.x); a2 += bflo(uc.y); a3 += bfhi(uc.y);
        a4 += bflo(uc.z); a5 += bfhi(uc.z); a6 += bflo(uc.w); a7 += bfhi(uc.w);
        i = in;
    }
    float deg = (float)(e_ - b);
    float inv = 1.f / fmaxf(deg, 1.f);
    uint4 o;
    o.x = bfpack(a0 * inv, a1 * inv); o.y = bfpack(a2 * inv, a3 * inv);
    o.z = bfpack(a4 * inv, a5 * inv); o.w = bfpack(a6 * inv, a7 * inv);
    ((uint4*)agg2)[(size_t)n * 8 + hl] = o;
    if (hl == 0) degE[n] = deg;
}

// ---------------- SAGE mean (2 nodes/wave, 32-lane halves, prefetched) ----------------
__global__ void sage_gather2(const unsigned short* __restrict__ X, const int* __restrict__ rowptr,
                             const int* __restrict__ adjS, unsigned short* __restrict__ mean) {
    int base = (blockIdx.x * 4 + (threadIdx.x >> 6)) * 2;
    int lane = threadIdx.x & 63;
    int half = lane >> 5, hl = lane & 31;
    int n = base + half;
    if (n >= NN) return;
    int b = rowptr[n], e_ = rowptr[n + 1];
    const uint4* Xu = (const uint4*)X;
    int i = b;
    uint4 un;
    if (i < e_) un = Xu[(size_t)adjS[i] * 32 + hl];
    float a0 = 0.f, a1 = 0.f, a2 = 0.f, a3 = 0.f, a4 = 0.f, a5 = 0.f, a6 = 0.f, a7 = 0.f;
    while (i < e_) {
        uint4 uc = un;
        int in = i + 1;
        if (in < e_) un = Xu[(size_t)adjS[in] * 32 + hl];
        a0 += bflo(uc.x); a1 += bfhi(uc.x); a2 += bflo(uc.y); a3 += bfhi(uc.y);
        a4 += bflo(uc.z); a5 += bfhi(uc.z); a6 += bflo(uc.w); a7 += bfhi(uc.w);
        i = in;
    }
    float inv = 1.f / fmaxf((float)(e_ - b), 1.f);
    uint4 o;
    o.x = bfpack(a0 * inv, a1 * inv); o.y = bfpack(a2 * inv, a3 * inv);
    o.z = bfpack(a4 * inv, a5 * inv); o.w = bfpack(a6 * inv, a7 * inv);
    ((uint4*)mean)[(size_t)n * 32 + hl] = o;
}

// ---------------- MixAttention: online softmax, k/v prefetched 2 ahead ----------------
__global__ void attn_online(const unsigned short* __restrict__ q, const unsigned short* __restrict__ k,
                            const unsigned short* __restrict__ v, const unsigned short* __restrict__ nrep,
                            const int* __restrict__ rowptr, const int* __restrict__ adjS,
                            float* __restrict__ mixed) {
    int n = blockIdx.x * 4 + (threadIdx.x >> 6);
    int lane = threadIdx.x & 63;
    if (n >= NN) return;
    int half = lane >> 5, hl = lane & 31;
    int b = rowptr[n], e_ = rowptr[n + 1];
    const uint4* qu4 = (const uint4*)q;
    const uint4* ku4 = (const uint4*)k;
    const uint4* vu4 = (const uint4*)v;
    const uint4* nu4 = (const uint4*)nrep;
    uint4 nu = nu4[(size_t)n * 32 + hl];
    float nr0 = bflo(nu.x), nr1 = bfhi(nu.x), nr2 = bflo(nu.y), nr3 = bfhi(nu.y);
    float nr4 = bflo(nu.z), nr5 = bfhi(nu.z), nr6 = bflo(nu.w), nr7 = bfhi(nu.w);
    float* mrow = mixed + (size_t)n * HD;
    if (b == e_) {
        if (half == 0) {
            ((float4*)mrow)[2 * hl]     = make_float4(nr0, nr1, nr2, nr3);
            ((float4*)mrow)[2 * hl + 1] = make_float4(nr4, nr5, nr6, nr7);
        }
        return;
    }
    uint4 qv = qu4[(size_t)n * 32 + hl];
    float q0 = bflo(qv.x), q1 = bfhi(qv.x), q2 = bflo(qv.y), q3 = bfhi(qv.y);
    float q4 = bflo(qv.z), q5 = bfhi(qv.z), q6 = bflo(qv.w), q7 = bfhi(qv.w);
    float m = -INFINITY, srun = 0.f;
    float a0 = 0.f, a1 = 0.f, a2 = 0.f, a3 = 0.f, a4 = 0.f, a5 = 0.f, a6 = 0.f, a7 = 0.f;
    int i = b + half;
    uint4 ku, vu;
    if (i < e_) {
        int s0 = adjS[i];
        ku = ku4[(size_t)s0 * 32 + hl];
        vu = vu4[(size_t)s0 * 32 + hl];
    }
    while (i < e_) {
        int in = i + 2;
        uint4 kn, vn;
        if (in < e_) {
            int s1 = adjS[in];
            kn = ku4[(size_t)s1 * 32 + hl];
            vn = vu4[(size_t)s1 * 32 + hl];
        }
        float p = q0 * bflo(ku.x) + q1 * bfhi(ku.x) + q2 * bflo(ku.y) + q3 * bfhi(ku.y)
                + q4 * bflo(ku.z) + q5 * bfhi(ku.z) + q6 * bflo(ku.w) + q7 * bfhi(ku.w);
        p += __shfl_xor(p, 1); p += __shfl_xor(p, 2); p += __shfl_xor(p, 4);
        p += __shfl_xor(p, 8); p += __shfl_xor(p, 16);
        p *= 0.0625f;
        float mn = fmaxf(m, p);
        float scale = exp2f((m - mn) * LOG2E);
        float w = exp2f((p - mn) * LOG2E);
        m = mn;
        srun = srun * scale + w;
        a0 = a0 * scale + w * bflo(vu.x); a1 = a1 * scale + w * bfhi(vu.x);
        a2 = a2 * scale + w * bflo(vu.y); a3 = a3 * scale + w * bfhi(vu.y);
        a4 = a4 * scale + w * bflo(vu.z); a5 = a5 * scale + w * bfhi(vu.z);
        a6 = a6 * scale + w * bflo(vu.w); a7 = a7 * scale + w * bfhi(vu.w);
        i = in; ku = kn; vu = vn;
    }
    float mo = __shfl_xor(m, 32);
    float so = __shfl_xor(srun, 32);
    float mn = fmaxf(m, mo);
    float cs = exp2f((m - mn) * LOG2E);
    float co = exp2f((mo - mn) * LOG2E);
    float st = srun * cs + so * co;
    float inv = 1.f / (st + 1e-16f);
    float o0 = (a0 * cs + __shfl_xor(a0, 32) * co) * inv + nr0;
    float o1 = (a1 * cs + __shfl_xor(a1, 32) * co) * inv + nr1;
    float o2 = (a2 * cs + __shfl_xor(a2, 32) * co) * inv + nr2;
    float o3 = (a3 * cs + __shfl_xor(a3, 32) * co) * inv + nr3;
    float o4 = (a4 * cs + __shfl_xor(a4, 32) * co) * inv + nr4;
    float o5 = (a5 * cs + __shfl_xor(a5, 32) * co) * inv + nr5;
    float o6 = (a6 * cs + __shfl_xor(a6, 32) * co) * inv + nr6;
    float o7 = (a7 * cs + __shfl_xor(a7, 32) * co) * inv + nr7;
    if (half == 0) {
        ((float4*)mrow)[2 * hl]     = make_float4(o0, o1, o2, o3);
        ((float4*)mrow)[2 * hl + 1] = make_float4(o4, o5, o6, o7);
    }
}

extern "C" void kernel_launch(void* const* d_in, const int* in_sizes, int n_in,
                              void* d_out, int out_size, void* d_ws, size_t ws_size,
                              hipStream_t stream) {
    (void)in_sizes; (void)n_in; (void)out_size; (void)ws_size;
    const float* x     = (const float*)d_in[0];
    const float* et    = (const float*)d_in[1];
    const int*   Hm    = (const int*)d_in[2];
    const int*   raw   = (const int*)d_in[3];
    const int*   lg    = (const int*)d_in[4];
    const float* W_gat = (const float*)d_in[5];
    const float* a_src = (const float*)d_in[6];
    const float* a_dst = (const float*)d_in[7];
    const float* b_gat = (const float*)d_in[8];
    const float* W_etn = (const float*)d_in[9];
    const float* W_eg  = (const float*)d_in[10];
    const float* Wr_e1 = (const float*)d_in[11];
    const float* Wn_e1 = (const float*)d_in[12];
    const float* b_e1  = (const float*)d_in[13];
    const float* Wr_e2 = (const float*)d_in[14];
    const float* Wn_e2 = (const float*)d_in[15];
    const float* b_e2  = (const float*)d_in[16];
    const float* Wr_n1 = (const float*)d_in[17];
    const float* Wn_n1 = (const float*)d_in[18];
    const float* b_n1  = (const float*)d_in[19];
    const float* Wr_n2 = (const float*)d_in[20];
    const float* Wn_n2 = (const float*)d_in[21];
    const float* b_n2  = (const float*)d_in[22];
    const float* Wr_n3 = (const float*)d_in[23];
    const float* Wn_n3 = (const float*)d_in[24];
    const float* b_n3  = (const float*)d_in[25];
    const float* Wq    = (const float*)d_in[26];
    const float* Wk    = (const float*)d_in[27];
    const float* Wv    = (const float*)d_in[28];
    const float* W_out = (const float*)d_in[29];

    const int* srcN = raw;
    const int* dstN = raw + EE;
    const int* lgs  = lg;
    const int* lgd  = lg + ELG;

    float* ws = (float*)d_ws;
    size_t off = 0;
    auto alloc = [&](size_t n) { float* p = ws + off; off += (n + 63) & ~(size_t)63; return p; };
    auto allocU = [&](size_t nus) { return (unsigned short*)alloc(nus / 2 + 64); };

    unsigned short* et_bf   = allocU((size_t)EE * FE);
    unsigned short* agg_et  = allocU((size_t)EE * FE);   // reused later as q/k/v
    float* es     = alloc(EE);
    float* ed     = alloc(EE);
    float* Wcomb  = alloc((size_t)FE * HD);
    float* b2     = alloc(HD);
    float* asv    = alloc(FE);
    float* adv    = alloc(FE);
    unsigned short* agg2_bf = allocU((size_t)NN * FE);
    float* degE   = alloc(NN);
    unsigned short* etnL  = allocU((size_t)NN * HD);
    unsigned short* erep  = allocU((size_t)NN * HD);
    unsigned short* meanb = allocU((size_t)NN * HD);
    unsigned short* t1    = allocU((size_t)NN * HD);
    unsigned short* aggr  = allocU((size_t)NN * HD);
    unsigned short* nrep  = allocU((size_t)NN * HD);
    unsigned short* x_bf  = allocU((size_t)NN * HD);
    float* mixed  = alloc((size_t)NN * HD);
    unsigned short* wtb    = allocU((size_t)14 * 65536);
    unsigned short* wcombt = allocU((size_t)HD * FE);
    int* rowptrD  = (int*)alloc(NN + 64);
    int* cursD    = (int*)alloc(NN);
    int* adjS     = (int*)alloc(EE);
    int* rowptrLG = (int*)alloc(EE + 64);
    int* cursLG   = (int*)alloc(EE);
    int* adjLG    = (int*)alloc(ELG);
    int* rowptrH  = (int*)alloc(NN + 64);
    int* cursH    = (int*)alloc(NN);
    int* adjH     = (int*)alloc(2 * EE);
    int* cntAll   = (int*)alloc(NTOTC + 64);
    int* scanAll  = (int*)alloc(NTOTC + 64);
    int* bsum     = (int*)alloc(1024);
    // aliases (lifetime-checked)
    unsigned short* ta = etnL;                 // etnL dead after erep GEMM
    unsigned short* tb = erep;                 // erep dead after edge layer 1
    unsigned short* qb = agg_et;               // agg_et dead after etn_gather
    unsigned short* kb = agg_et + (size_t)NN * HD;
    unsigned short* vb = agg_et + (size_t)2 * NN * HD;
    float* outp = (float*)d_out;

    unsigned short* W_eg_t  = wtb + 0 * 65536;
    unsigned short* Wr_e1_t = wtb + 1 * 65536;
    unsigned short* Wn_e1_t = wtb + 2 * 65536;
    unsigned short* Wr_e2_t = wtb + 3 * 65536;
    unsigned short* Wn_e2_t = wtb + 4 * 65536;
    unsigned short* Wr_n1_t = wtb + 5 * 65536;
    unsigned short* Wn_n1_t = wtb + 6 * 65536;
    unsigned short* Wr_n2_t = wtb + 7 * 65536;
    unsigned short* Wn_n2_t = wtb + 8 * 65536;
    unsigned short* Wr_n3_t = wtb + 9 * 65536;
    unsigned short* Wn_n3_t = wtb + 10 * 65536;
    unsigned short* Wq_t    = wtb + 11 * 65536;
    unsigned short* Wk_t    = wtb + 12 * 65536;
    unsigned short* Wv_t    = wtb + 13 * 65536;

    dim3 gB(4, (NN + 127) / 128);

    // ======== weight conversion + x conversion ========
    Ptr14 p14;
    p14.p[0] = W_eg;  p14.p[1] = Wr_e1; p14.p[2] = Wn_e1; p14.p[3] = Wr_e2;
    p14.p[4] = Wn_e2; p14.p[5] = Wr_n1; p14.p[6] = Wn_n1; p14.p[7] = Wr_n2;
    p14.p[8] = Wn_n2; p14.p[9] = Wr_n3; p14.p[10] = Wn_n3; p14.p[11] = Wq;
    p14.p[12] = Wk;   p14.p[13] = Wv;
    wtrans14<<<14 * 64, 256, 0, stream>>>(p14, wtb);
    conv_bf16<<<(NN * HD / 2 + 255) / 256, 256, 0, stream>>>(x, (unsigned int*)x_bf, NN * HD / 2);

    // ======== consolidated CSR build (persistent XCD-class kernels, round-9 proven) ========
    zero_i32<<<(NTOTC + 255) / 256, 256, 0, stream>>>(cntAll, NTOTC);
    count_ranged<<<8 * PBLK, 256, 0, stream>>>(dstN, lgd, Hm, cntAll);
    {
        int nb = (NTOTC + 1023) / 1024;
        scan_pass1<<<nb, 256, 0, stream>>>(cntAll, bsum, NTOTC);
        scan_pass2<<<1, 256, 0, stream>>>(bsum, nb);
        scan_pass3<<<nb, 256, 0, stream>>>(cntAll, bsum, scanAll, NTOTC);
    }
    rebase_all<<<(NTOTC + 255) / 256, 256, 0, stream>>>(scanAll, rowptrD, cursD,
                                                        rowptrLG, cursLG, rowptrH, cursH);
    place_ranged<<<8 * PBLK, 256, 0, stream>>>(srcN, dstN, lgs, lgd, Hm,
                                               cursD, cursLG, cursH, adjS, adjLG, adjH);

    // ======== GAT (folded Wcomb = W_gat@W_etn; alpha fused into gather) ========
    gemm_f32<<<dim3(4, 1), 256, 0, stream>>>(W_gat, W_etn, Wcomb, FE, HD, HD);
    wtrans_one<<<(FE / 32) * (HD / 32), 256, 0, stream>>>(Wcomb, wcombt, FE, HD);
    gat_prep<<<FE + 1, 256, 0, stream>>>(W_gat, a_src, a_dst, b_gat, W_etn, asv, adv, b2);
    edge_scores_conv<<<EE / 4, 256, 0, stream>>>(et, asv, adv, es, ed, et_bf);
    gat_fused2<<<EE / 32, 256, 0, stream>>>(rowptrLG, adjLG, es, ed, et_bf, agg_et);

    // ======== EdgeToNode incidence mean + GEMMs ========
    etn_gather3<<<(NN + 31) / 32, 256, 0, stream>>>(rowptrH, adjH, agg_et, agg2_bf, degE);
    gemm_bf16<<<gB, 256, 0, stream>>>(agg2_bf, nullptr, wcombt, nullptr, b2, degE, etnL, NN, FE, 4);
    gemm_bf16<<<gB, 256, 0, stream>>>(etnL, nullptr, W_eg_t, nullptr, nullptr, nullptr, erep, NN, HD, 0);

    // ======== edge_aggr SAGE (2 layers, dual-K fused) ========
    sage_gather2<<<(NN + 7) / 8, 256, 0, stream>>>(erep, rowptrD, adjS, meanb);
    gemm_bf16<<<gB, 256, 0, stream>>>(erep, meanb, Wr_e1_t, Wn_e1_t, b_e1, nullptr, t1, NN, HD, 1);
    sage_gather2<<<(NN + 7) / 8, 256, 0, stream>>>(t1, rowptrD, adjS, meanb);
    gemm_bf16<<<gB, 256, 0, stream>>>(t1, meanb, Wr_e2_t, Wn_e2_t, b_e2, nullptr, aggr, NN, HD, 0);

    // ======== attr_node SAGE (3 layers, dual-K fused) ========
    sage_gather2<<<(NN + 7) / 8, 256, 0, stream>>>(x_bf, rowptrD, adjS, meanb);
    gemm_bf16<<<gB, 256, 0, stream>>>(x_bf, meanb, Wr_n1_t, Wn_n1_t, b_n1, nullptr, ta, NN, HD, 1);
    sage_gather2<<<(NN + 7) / 8, 256, 0, stream>>>(ta, rowptrD, adjS, meanb);
    gemm_bf16<<<gB, 256, 0, stream>>>(ta, meanb, Wr_n2_t, Wn_n2_t, b_n2, nullptr, tb, NN, HD, 1);
    sage_gather2<<<(NN + 7) / 8, 256, 0, stream>>>(tb, rowptrD, adjS, meanb);
    gemm_bf16<<<gB, 256, 0, stream>>>(tb, meanb, Wr_n3_t, Wn_n3_t, b_n3, nullptr, nrep, NN, HD, 0);

    // ======== MixAttention (q,k,v in ONE launch) ========
    gemm_bf16_tri<<<dim3(12, (NN + 127) / 128), 256, 0, stream>>>(
        nrep, Wq_t, qb, aggr, Wk_t, kb, aggr, Wv_t, vb, NN);
    attn_online<<<(NN + 3) / 4, 256, 0, stream>>>(qb, kb, vb, nrep, rowptrD, adjS, mixed);

    // ======== final linear + log_softmax (fused) ========
    gemm_out_lsm<<<dim3(1, (NN + 63) / 64), 256, 0, stream>>>(mixed, W_out, outp, NN);
}

// Round 12
// 795.363 us; speedup vs baseline: 3.4708x; 1.0650x over previous
//
#include <hip/hip_runtime.h>
#include <math.h>

#define NN   20000
#define EE   320000
#define ELG  600000
#define FE   64
#define HD   256
#define FOUT 40
#define LOG2E 1.44269504f
#define NTOTC (NN + EE + NN)            // concatenated count-buffer size
#define NIDX  (EE + ELG + 2 * EE)       // concatenated index-stream size
#define RD_RANGE  ((NN + 7) / 8)        // keys per XCD range (D and H sections)
#define RLG_RANGE ((EE + 7) / 8)        // keys per XCD range (LG section)
#define PBLK 256                        // persistent blocks per XCD class

typedef __attribute__((ext_vector_type(8))) short bf16x8;
typedef __attribute__((ext_vector_type(4))) float f32x4;

__device__ __forceinline__ float leaky02(float x) { return x > 0.f ? x : 0.2f * x; }

__device__ __forceinline__ unsigned short bf16rne(float f) {
    unsigned int u = __float_as_uint(f);
    u = (u + 0x7FFFu + ((u >> 16) & 1u)) >> 16;
    return (unsigned short)u;
}
__device__ __forceinline__ float bflo(unsigned int u) { return __uint_as_float(u << 16); }
__device__ __forceinline__ float bfhi(unsigned int u) { return __uint_as_float(u & 0xffff0000u); }
__device__ __forceinline__ unsigned int bfpack(float a, float b) {
    return (unsigned int)bf16rne(a) | ((unsigned int)bf16rne(b) << 16);
}

// ---------------- small utility kernels ----------------
__global__ void zero_i32(int* __restrict__ p, int n) {
    int i = blockIdx.x * 256 + threadIdx.x;
    if (i < n) p[i] = 0;
}
__global__ void conv_bf16(const float* __restrict__ in, unsigned int* __restrict__ out, int n2) {
    int i = blockIdx.x * 256 + threadIdx.x;
    if (i < n2) { float2 v = ((const float2*)in)[i]; out[i] = bfpack(v.x, v.y); }
}

// ---------------- CSR build: count + in-bucket position in ONE atomic pass ----------------
// cntAll sections: [0,NN) = raw-by-dst, [NN,NN+EE) = lg-by-lgd, [NN+EE,NN+EE+NN) = incidence H
// Atomics are memory-side on MI355X (XCD locality irrelevant), so this kernel is a plain
// dense grid: coalesced stream reads + coalesced posAll writes.
__global__ void count_pos(const int* __restrict__ dstN, const int* __restrict__ lgd,
                          const int* __restrict__ Hm, int* __restrict__ cntAll,
                          int* __restrict__ posAll) {
    int i = blockIdx.x * 256 + threadIdx.x;
    if (i >= NIDX) return;
    int key;
    if (i < EE) key = dstN[i];
    else if (i < EE + ELG) key = NN + lgd[i - EE];
    else key = NN + EE + Hm[i - EE - ELG];
    posAll[i] = atomicAdd(&cntAll[key], 1);
}

__global__ void scan_pass1(const int* __restrict__ in, int* __restrict__ bsum, int n) {
    __shared__ int sm[256];
    int base = blockIdx.x * 1024, t = threadIdx.x;
    int s = 0;
#pragma unroll
    for (int j = 0; j < 4; ++j) { int i = base + t * 4 + j; s += (i < n) ? in[i] : 0; }
    sm[t] = s; __syncthreads();
    for (int o = 128; o > 0; o >>= 1) { if (t < o) sm[t] += sm[t + o]; __syncthreads(); }
    if (t == 0) bsum[blockIdx.x] = sm[0];
}
__global__ void scan_pass2(int* __restrict__ bsum, int nb) {
    __shared__ int sm[1024];
    int t = threadIdx.x;
    for (int i = t; i < nb; i += 256) sm[i] = bsum[i];
    __syncthreads();
    if (t == 0) { int run = 0; for (int i = 0; i < nb; ++i) { int v = sm[i]; sm[i] = run; run += v; } }
    __syncthreads();
    for (int i = t; i < nb; i += 256) bsum[i] = sm[i];
}
__global__ void scan_pass3(const int* __restrict__ in, const int* __restrict__ boff,
                           int* __restrict__ out, int n) {
    __shared__ int tsum[256];
    int base = blockIdx.x * 1024, t = threadIdx.x;
    int v[4];
#pragma unroll
    for (int j = 0; j < 4; ++j) { int i = base + t * 4 + j; v[j] = (i < n) ? in[i] : 0; }
    int loc = v[0] + v[1] + v[2] + v[3];
    tsum[t] = loc; __syncthreads();
    for (int o = 1; o < 256; o <<= 1) {
        int x = (t >= o) ? tsum[t - o] : 0;
        __syncthreads();
        tsum[t] += x;
        __syncthreads();
    }
    int off = boff[blockIdx.x] + (tsum[t] - loc);
    int run = 0;
#pragma unroll
    for (int j = 0; j < 4; ++j) { int i = base + t * 4 + j; if (i < n) out[i] = off + run; run += v[j]; }
}

// section-rebased rowptr (one pass; no cursors needed anymore)
__global__ void rebase_all(const int* __restrict__ scanAll,
                           int* __restrict__ rowptrD, int* __restrict__ rowptrLG,
                           int* __restrict__ rowptrH) {
    int i = blockIdx.x * 256 + threadIdx.x;
    if (i == 0) { rowptrD[NN] = EE; rowptrLG[EE] = ELG; rowptrH[NN] = 2 * EE; }
    if (i >= NTOTC) return;
    if (i < NN) rowptrD[i] = scanAll[i];
    else if (i < NN + EE) rowptrLG[i - NN] = scanAll[i] - EE;
    else rowptrH[i - NN - EE] = scanAll[i] - (EE + ELG);
}

// Atomic-free scatter: adj[rowptr[key] + pos[i]] = value. 8-class persistent blocks keep
// each adj region's plain stores on one XCD's L2 (round 7->8 proven for stores; atomics
// never benefited). Correctness independent of the class->XCD mapping.
__global__ __launch_bounds__(256)
void place_scatter(const int* __restrict__ srcN, const int* __restrict__ dstN,
                   const int* __restrict__ lgs, const int* __restrict__ lgd,
                   const int* __restrict__ Hm, const int* __restrict__ posAll,
                   const int* __restrict__ rowptrD, const int* __restrict__ rowptrLG,
                   const int* __restrict__ rowptrH,
                   int* __restrict__ adjS, int* __restrict__ adjLG, int* __restrict__ adjH) {
    int r = blockIdx.x & 7;
    int blk = blockIdx.x >> 3;
    const int stride = PBLK * 256;
    for (int i = blk * 256 + threadIdx.x; i < NIDX; i += stride) {
        if (i < EE) {
            int key = dstN[i];
            if (key / RD_RANGE == r) adjS[rowptrD[key] + posAll[i]] = srcN[i];
        } else if (i < EE + ELG) {
            int j = i - EE;
            int key = lgd[j];
            if (key / RLG_RANGE == r) adjLG[rowptrLG[key] + posAll[i]] = lgs[j];
        } else {
            int j = i - EE - ELG;
            int key = Hm[j];
            if (key / RD_RANGE == r) adjH[rowptrH[key] + posAll[i]] = (j < EE) ? j : j - EE;
        }
    }
}

// ---------------- weight transpose+convert ----------------
struct Ptr14 { const float* p[14]; };
__global__ void wtrans14(Ptr14 srcs, unsigned short* __restrict__ dst) {
    int m = blockIdx.x >> 6;
    int tile = blockIdx.x & 63;
    const float* src = srcs.p[m];
    unsigned short* out = dst + (size_t)m * 65536;
    int kb = (tile >> 3) * 32, nb = (tile & 7) * 32;
    __shared__ float sm[32][33];
    int t = threadIdx.x;
#pragma unroll
    for (int i = 0; i < 4; ++i) {
        int e = t + i * 256; int r = e >> 5, c = e & 31;
        sm[r][c] = src[(kb + r) * 256 + nb + c];
    }
    __syncthreads();
#pragma unroll
    for (int i = 0; i < 4; ++i) {
        int e = t + i * 256; int nr = e >> 5, kc = e & 31;
        out[(size_t)(nb + nr) * 256 + kb + kc] = bf16rne(sm[kc][nr]);
    }
}
__global__ void wtrans_one(const float* __restrict__ src, unsigned short* __restrict__ dst,
                           int K, int N) {
    int tilesN = N >> 5;
    int kb = (blockIdx.x / tilesN) * 32, nb = (blockIdx.x % tilesN) * 32;
    __shared__ float sm[32][33];
    int t = threadIdx.x;
#pragma unroll
    for (int i = 0; i < 4; ++i) {
        int e = t + i * 256; int r = e >> 5, c = e & 31;
        sm[r][c] = src[(kb + r) * N + nb + c];
    }
    __syncthreads();
#pragma unroll
    for (int i = 0; i < 4; ++i) {
        int e = t + i * 256; int nr = e >> 5, kc = e & 31;
        dst[(size_t)(nb + nr) * K + kb + kc] = bf16rne(sm[kc][nr]);
    }
}

// ---------------- bf16 MFMA GEMM ----------------
// flags: 1=relu, 4=degE-mask + leaky
__global__ __launch_bounds__(256)
void gemm_bf16(const unsigned short* __restrict__ A1, const unsigned short* __restrict__ A2,
               const unsigned short* __restrict__ W1, const unsigned short* __restrict__ W2,
               const float* __restrict__ bias, const float* __restrict__ degmask,
               unsigned short* __restrict__ C, int M, int K1, int flags) {
    __shared__ unsigned short As[128][40];
    __shared__ unsigned short Bs[64][40];
    int tid = threadIdx.x;
    int w = tid >> 6, l = tid & 63;
    int wr = w >> 1, wc = w & 1;
    int brow = blockIdx.y * 128, bcol = blockIdx.x * 64;
    int Ktot = K1 + (A2 ? 256 : 0);
    f32x4 acc[4][2] = {};
    for (int k0 = 0; k0 < Ktot; k0 += 32) {
        const unsigned short* Ap; const unsigned short* Wp; int kk, Klen;
        if (k0 < K1) { Ap = A1; Wp = W1; kk = k0; Klen = K1; }
        else         { Ap = A2; Wp = W2; kk = k0 - K1; Klen = 256; }
#pragma unroll
        for (int i = 0; i < 4; ++i) {
            int q = tid + i * 256;
            int r = q >> 3, kb = (q & 7) * 4;
            int gr = brow + r;
            ushort4 u;
            if (gr < M) u = *(const ushort4*)(Ap + (size_t)gr * Klen + kk + kb);
            else { u.x = 0; u.y = 0; u.z = 0; u.w = 0; }
            *(ushort4*)(&As[r][kb]) = u;
        }
#pragma unroll
        for (int i = 0; i < 2; ++i) {
            int q = tid + i * 256;
            int n = q >> 3, kb = (q & 7) * 4;
            *(ushort4*)(&Bs[n][kb]) = *(const ushort4*)(Wp + (size_t)(bcol + n) * Klen + kk + kb);
        }
        __syncthreads();
        bf16x8 af[4], bfr[2];
#pragma unroll
        for (int fr = 0; fr < 4; ++fr)
            af[fr] = *(const bf16x8*)(&As[wr * 64 + fr * 16 + (l & 15)][(l >> 4) * 8]);
#pragma unroll
        for (int fc = 0; fc < 2; ++fc)
            bfr[fc] = *(const bf16x8*)(&Bs[wc * 32 + fc * 16 + (l & 15)][(l >> 4) * 8]);
#pragma unroll
        for (int fr = 0; fr < 4; ++fr)
#pragma unroll
            for (int fc = 0; fc < 2; ++fc)
                acc[fr][fc] = __builtin_amdgcn_mfma_f32_16x16x32_bf16(af[fr], bfr[fc], acc[fr][fc], 0, 0, 0);
        __syncthreads();
    }
#pragma unroll
    for (int fr = 0; fr < 4; ++fr) {
#pragma unroll
        for (int fc = 0; fc < 2; ++fc) {
            int col = bcol + wc * 32 + fc * 16 + (l & 15);
#pragma unroll
            for (int i = 0; i < 4; ++i) {
                int row = brow + wr * 64 + fr * 16 + (l >> 4) * 4 + i;
                if (row >= M) continue;
                float v = acc[fr][fc][i];
                if (bias) v += bias[col];
                if (flags & 1) v = fmaxf(v, 0.f);
                if (flags & 4) { v = (degmask[row] > 0.f) ? v : 0.f; v = leaky02(v); }
                C[(size_t)row * 256 + col] = bf16rne(v);
            }
        }
    }
}

// three single-K GEMMs in one launch
__global__ __launch_bounds__(256)
void gemm_bf16_tri(const unsigned short* __restrict__ A0, const unsigned short* __restrict__ W0,
                   unsigned short* __restrict__ C0,
                   const unsigned short* __restrict__ A1, const unsigned short* __restrict__ W1,
                   unsigned short* __restrict__ C1,
                   const unsigned short* __restrict__ A2, const unsigned short* __restrict__ W2,
                   unsigned short* __restrict__ C2, int M) {
    __shared__ unsigned short As[128][40];
    __shared__ unsigned short Bs[64][40];
    int sel = blockIdx.x >> 2;
    const unsigned short* A = (sel == 0) ? A0 : (sel == 1) ? A1 : A2;
    const unsigned short* W = (sel == 0) ? W0 : (sel == 1) ? W1 : W2;
    unsigned short* C = (sel == 0) ? C0 : (sel == 1) ? C1 : C2;
    int tid = threadIdx.x;
    int w = tid >> 6, l = tid & 63;
    int wr = w >> 1, wc = w & 1;
    int brow = blockIdx.y * 128, bcol = (blockIdx.x & 3) * 64;
    f32x4 acc[4][2] = {};
    for (int k0 = 0; k0 < 256; k0 += 32) {
#pragma unroll
        for (int i = 0; i < 4; ++i) {
            int q = tid + i * 256;
            int r = q >> 3, kb = (q & 7) * 4;
            int gr = brow + r;
            ushort4 u;
            if (gr < M) u = *(const ushort4*)(A + (size_t)gr * 256 + k0 + kb);
            else { u.x = 0; u.y = 0; u.z = 0; u.w = 0; }
            *(ushort4*)(&As[r][kb]) = u;
        }
#pragma unroll
        for (int i = 0; i < 2; ++i) {
            int q = tid + i * 256;
            int n = q >> 3, kb = (q & 7) * 4;
            *(ushort4*)(&Bs[n][kb]) = *(const ushort4*)(W + (size_t)(bcol + n) * 256 + k0 + kb);
        }
        __syncthreads();
        bf16x8 af[4], bfr[2];
#pragma unroll
        for (int fr = 0; fr < 4; ++fr)
            af[fr] = *(const bf16x8*)(&As[wr * 64 + fr * 16 + (l & 15)][(l >> 4) * 8]);
#pragma unroll
        for (int fc = 0; fc < 2; ++fc)
            bfr[fc] = *(const bf16x8*)(&Bs[wc * 32 + fc * 16 + (l & 15)][(l >> 4) * 8]);
#pragma unroll
        for (int fr = 0; fr < 4; ++fr)
#pragma unroll
            for (int fc = 0; fc < 2; ++fc)
                acc[fr][fc] = __builtin_amdgcn_mfma_f32_16x16x32_bf16(af[fr], bfr[fc], acc[fr][fc], 0, 0, 0);
        __syncthreads();
    }
#pragma unroll
    for (int fr = 0; fr < 4; ++fr) {
#pragma unroll
        for (int fc = 0; fc < 2; ++fc) {
            int col = bcol + wc * 32 + fc * 16 + (l & 15);
#pragma unroll
            for (int i = 0; i < 4; ++i) {
                int row = brow + wr * 64 + fr * 16 + (l >> 4) * 4 + i;
                if (row >= M) continue;
                C[(size_t)row * 256 + col] = bf16rne(acc[fr][fc][i]);
            }
        }
    }
}

// ---------------- fp32 GEMM (Wcomb build only) ----------------
__global__ __launch_bounds__(256)
void gemm_f32(const float* __restrict__ A, const float* __restrict__ B,
              float* __restrict__ C, int M, int N, int K) {
    const int BM = 64, BN = 64, BK = 16;
    __shared__ float As[BK][BM + 1];
    __shared__ float Bs[BK][BN + 1];
    int tid = threadIdx.x;
    int tr = tid >> 4, tc = tid & 15;
    int brow = blockIdx.y * BM, bcol = blockIdx.x * BN;
    float acc[4][4] = {{0.f}};
    for (int k0 = 0; k0 < K; k0 += BK) {
#pragma unroll
        for (int i = 0; i < 4; ++i) {
            int e = tid + i * 256;
            int r = e >> 4, c = e & 15;
            int gr = brow + r, gc = k0 + c;
            As[c][r] = (gr < M && gc < K) ? A[(long)gr * K + gc] : 0.f;
        }
#pragma unroll
        for (int i = 0; i < 4; ++i) {
            int e = tid + i * 256;
            int r = e >> 6, c = e & 63;
            int gr = k0 + r, gc = bcol + c;
            Bs[r][c] = (gr < K && gc < N) ? B[(long)gr * N + gc] : 0.f;
        }
        __syncthreads();
#pragma unroll
        for (int k = 0; k < BK; ++k) {
            float ra[4], rb[4];
#pragma unroll
            for (int i = 0; i < 4; ++i) ra[i] = As[k][tr * 4 + i];
#pragma unroll
            for (int j = 0; j < 4; ++j) rb[j] = Bs[k][tc * 4 + j];
#pragma unroll
            for (int i = 0; i < 4; ++i)
#pragma unroll
                for (int j = 0; j < 4; ++j) acc[i][j] += ra[i] * rb[j];
        }
        __syncthreads();
    }
#pragma unroll
    for (int i = 0; i < 4; ++i) {
        int gr = brow + tr * 4 + i;
        if (gr >= M) continue;
#pragma unroll
        for (int j = 0; j < 4; ++j) {
            int gc = bcol + tc * 4 + j;
            if (gc < N) C[(long)gr * N + gc] = acc[i][j];
        }
    }
}

// ---------------- final linear + log_softmax fused ----------------
__global__ __launch_bounds__(256)
void gemm_out_lsm(const float* __restrict__ A, const float* __restrict__ B,
                  float* __restrict__ out, int M) {
    const int BK = 16;
    __shared__ float As[BK][65];
    __shared__ float Bs[BK][65];
    __shared__ float tile[64][41];
    __shared__ float lsb[64];
    int tid = threadIdx.x;
    int tr = tid >> 4, tc = tid & 15;
    int brow = blockIdx.y * 64;
    float acc[4][4] = {{0.f}};
    for (int k0 = 0; k0 < 256; k0 += BK) {
#pragma unroll
        for (int i = 0; i < 4; ++i) {
            int e = tid + i * 256;
            int r = e >> 4, c = e & 15;
            int gr = brow + r;
            As[c][r] = (gr < M) ? A[(long)gr * 256 + k0 + c] : 0.f;
        }
#pragma unroll
        for (int i = 0; i < 4; ++i) {
            int e = tid + i * 256;
            int r = e >> 6, c = e & 63;
            Bs[r][c] = (c < FOUT) ? B[(long)(k0 + r) * FOUT + c] : 0.f;
        }
        __syncthreads();
#pragma unroll
        for (int k = 0; k < BK; ++k) {
            float ra[4], rb[4];
#pragma unroll
            for (int i = 0; i < 4; ++i) ra[i] = As[k][tr * 4 + i];
#pragma unroll
            for (int j = 0; j < 4; ++j) rb[j] = Bs[k][tc * 4 + j];
#pragma unroll
            for (int i = 0; i < 4; ++i)
#pragma unroll
                for (int j = 0; j < 4; ++j) acc[i][j] += ra[i] * rb[j];
        }
        __syncthreads();
    }
#pragma unroll
    for (int i = 0; i < 4; ++i)
#pragma unroll
        for (int j = 0; j < 4; ++j) {
            int gc = tc * 4 + j;
            if (gc < FOUT) tile[tr * 4 + i][gc] = acc[i][j];
        }
    __syncthreads();
    if (tid < 64) {
        int gr = brow + tid;
        float mx = -INFINITY;
        if (gr < M) {
            for (int c = 0; c < FOUT; ++c) mx = fmaxf(mx, tile[tid][c]);
            float s = 0.f;
            for (int c = 0; c < FOUT; ++c) s += __expf(tile[tid][c] - mx);
            lsb[tid] = mx + logf(s);
        }
    }
    __syncthreads();
#pragma unroll
    for (int i = 0; i < 4; ++i) {
        int r = tr * 4 + i;
        int gr = brow + r;
        if (gr >= M) continue;
#pragma unroll
        for (int j = 0; j < 4; ++j) {
            int gc = tc * 4 + j;
            if (gc < FOUT) out[(long)gr * FOUT + gc] = tile[r][gc] - lsb[r];
        }
    }
}

// ---------------- GAT pre-computation (wg_av + bias_proj fused) ----------------
__global__ void gat_prep(const float* __restrict__ W, const float* __restrict__ as_,
                         const float* __restrict__ ad_, const float* __restrict__ b_gat,
                         const float* __restrict__ W_etn,
                         float* __restrict__ asv, float* __restrict__ adv, float* __restrict__ b2) {
    int t = threadIdx.x;
    if (blockIdx.x == FE) {
        float s = 0.f;
        for (int i = 0; i < HD; ++i) s += b_gat[i] * W_etn[i * HD + t];
        b2[t] = s;
        return;
    }
    __shared__ float sm[256];
    int i = blockIdx.x;
    float w = W[i * HD + t];
    sm[t] = w * as_[t];
    __syncthreads();
    for (int o = 128; o > 0; o >>= 1) { if (t < o) sm[t] += sm[t + o]; __syncthreads(); }
    if (t == 0) asv[i] = sm[0];
    __syncthreads();
    sm[t] = w * ad_[t];
    __syncthreads();
    for (int o = 128; o > 0; o >>= 1) { if (t < o) sm[t] += sm[t + o]; __syncthreads(); }
    if (t == 0) adv[i] = sm[0];
}

__global__ void edge_scores_conv(const float* __restrict__ et, const float* __restrict__ asv,
                                 const float* __restrict__ adv, float* __restrict__ es,
                                 float* __restrict__ ed, unsigned short* __restrict__ et_bf) {
    int e = blockIdx.x * 4 + (threadIdx.x >> 6);
    int l = threadIdx.x & 63;
    float x = et[(long)e * FE + l];
    et_bf[(long)e * FE + l] = bf16rne(x);
    float vs = x * asv[l];
    float vd = x * adv[l];
    for (int o = 32; o > 0; o >>= 1) { vs += __shfl_down(vs, o); vd += __shfl_down(vd, o); }
    if (l == 0) { es[e] = vs; ed[e] = vd; }
}

// ---------------- GAT: fused alpha + gather (8-lane group, online softmax, one pass) ----------------
__global__ void gat_fused2(const int* __restrict__ rowptr, const int* __restrict__ adj,
                           const float* __restrict__ es, const float* __restrict__ ed,
                           const unsigned short* __restrict__ et_bf,
                           unsigned short* __restrict__ agg_et) {
    int d = blockIdx.x * 32 + (threadIdx.x >> 3);
    int hl = threadIdx.x & 7;                  // row = 8 x uint4 (64 bf16)
    if (d >= EE) return;
    int b = rowptr[d], e_ = rowptr[d + 1];
    const uint4* etu = (const uint4*)et_bf;
    float edd = ed[d];
    float m = leaky02(es[d] + edd);
    float srun = 1.f;
    uint4 u = etu[(size_t)d * 8 + hl];
    float a0 = bflo(u.x), a1 = bfhi(u.x), a2 = bflo(u.y), a3 = bfhi(u.y);
    float a4 = bflo(u.z), a5 = bfhi(u.z), a6 = bflo(u.w), a7 = bfhi(u.w);
    int i = b;
    float esn = 0.f; uint4 un;
    if (i < e_) { int s0 = adj[i]; esn = es[s0]; un = etu[(size_t)s0 * 8 + hl]; }
    while (i < e_) {
        float esc = esn; uint4 uc = un;
        int in = i + 1;
        if (in < e_) { int s1 = adj[in]; esn = es[s1]; un = etu[(size_t)s1 * 8 + hl]; }
        float p = leaky02(esc + edd);
        float mn = fmaxf(m, p);
        float scale = exp2f((m - mn) * LOG2E);
        float w = exp2f((p - mn) * LOG2E);
        m = mn;
        srun = srun * scale + w;
        a0 = a0 * scale + w * bflo(uc.x); a1 = a1 * scale + w * bfhi(uc.x);
        a2 = a2 * scale + w * bflo(uc.y); a3 = a3 * scale + w * bfhi(uc.y);
        a4 = a4 * scale + w * bflo(uc.z); a5 = a5 * scale + w * bfhi(uc.z);
        a6 = a6 * scale + w * bflo(uc.w); a7 = a7 * scale + w * bfhi(uc.w);
        i = in;
    }
    float inv = 1.f / (srun + 1e-16f);
    uint4 o;
    o.x = bfpack(a0 * inv, a1 * inv); o.y = bfpack(a2 * inv, a3 * inv);
    o.z = bfpack(a4 * inv, a5 * inv); o.w = bfpack(a6 * inv, a7 * inv);
    ((uint4*)agg_et)[(size_t)d * 8 + hl] = o;
}

// ---------------- incidence mean (8-lane group, uint4, prefetched) ----------------
__global__ void etn_gather3(const int* __restrict__ rowptr, const int* __restrict__ adj,
                            const unsigned short* __restrict__ agg_et,
                            unsigned short* __restrict__ agg2, float* __restrict__ degE) {
    int n = blockIdx.x * 32 + (threadIdx.x >> 3);
    int hl = threadIdx.x & 7;
    if (n >= NN) return;
    int b = rowptr[n], e_ = rowptr[n + 1];
    const uint4* au = (const uint4*)agg_et;
    int i = b;
    uint4 un;
    if (i < e_) un = au[(size_t)adj[i] * 8 + hl];
    float a0 = 0.f, a1 = 0.f, a2 = 0.f, a3 = 0.f, a4 = 0.f, a5 = 0.f, a6 = 0.f, a7 = 0.f;
    while (i < e_) {
        uint4 uc = un;
        int in = i + 1;
        if (in < e_) un = au[(size_t)adj[in] * 8 + hl];
        a0 += bflo(uc.x); a1 += bfhi(uc.x); a2 += bflo(uc.y); a3 += bfhi(uc.y);
        a4 += bflo(uc.z); a5 += bfhi(uc.z); a6 += bflo(uc.w); a7 += bfhi(uc.w);
        i = in;
    }
    float deg = (float)(e_ - b);
    float inv = 1.f / fmaxf(deg, 1.f);
    uint4 o;
    o.x = bfpack(a0 * inv, a1 * inv); o.y = bfpack(a2 * inv, a3 * inv);
    o.z = bfpack(a4 * inv, a5 * inv); o.w = bfpack(a6 * inv, a7 * inv);
    ((uint4*)agg2)[(size_t)n * 8 + hl] = o;
    if (hl == 0) degE[n] = deg;
}

// ---------------- SAGE mean (2 nodes/wave, 32-lane halves, prefetched) ----------------
__global__ void sage_gather2(const unsigned short* __restrict__ X, const int* __restrict__ rowptr,
                             const int* __restrict__ adjS, unsigned short* __restrict__ mean) {
    int base = (blockIdx.x * 4 + (threadIdx.x >> 6)) * 2;
    int lane = threadIdx.x & 63;
    int half = lane >> 5, hl = lane & 31;
    int n = base + half;
    if (n >= NN) return;
    int b = rowptr[n], e_ = rowptr[n + 1];
    const uint4* Xu = (const uint4*)X;
    int i = b;
    uint4 un;
    if (i < e_) un = Xu[(size_t)adjS[i] * 32 + hl];
    float a0 = 0.f, a1 = 0.f, a2 = 0.f, a3 = 0.f, a4 = 0.f, a5 = 0.f, a6 = 0.f, a7 = 0.f;
    while (i < e_) {
        uint4 uc = un;
        int in = i + 1;
        if (in < e_) un = Xu[(size_t)adjS[in] * 32 + hl];
        a0 += bflo(uc.x); a1 += bfhi(uc.x); a2 += bflo(uc.y); a3 += bfhi(uc.y);
        a4 += bflo(uc.z); a5 += bfhi(uc.z); a6 += bflo(uc.w); a7 += bfhi(uc.w);
        i = in;
    }
    float inv = 1.f / fmaxf((float)(e_ - b), 1.f);
    uint4 o;
    o.x = bfpack(a0 * inv, a1 * inv); o.y = bfpack(a2 * inv, a3 * inv);
    o.z = bfpack(a4 * inv, a5 * inv); o.w = bfpack(a6 * inv, a7 * inv);
    ((uint4*)mean)[(size_t)n * 32 + hl] = o;
}

// ---------------- MixAttention: online softmax, k/v prefetched 2 ahead ----------------
__global__ void attn_online(const unsigned short* __restrict__ q, const unsigned short* __restrict__ k,
                            const unsigned short* __restrict__ v, const unsigned short* __restrict__ nrep,
                            const int* __restrict__ rowptr, const int* __restrict__ adjS,
                            float* __restrict__ mixed) {
    int n = blockIdx.x * 4 + (threadIdx.x >> 6);
    int lane = threadIdx.x & 63;
    if (n >= NN) return;
    int half = lane >> 5, hl = lane & 31;
    int b = rowptr[n], e_ = rowptr[n + 1];
    const uint4* qu4 = (const uint4*)q;
    const uint4* ku4 = (const uint4*)k;
    const uint4* vu4 = (const uint4*)v;
    const uint4* nu4 = (const uint4*)nrep;
    uint4 nu = nu4[(size_t)n * 32 + hl];
    float nr0 = bflo(nu.x), nr1 = bfhi(nu.x), nr2 = bflo(nu.y), nr3 = bfhi(nu.y);
    float nr4 = bflo(nu.z), nr5 = bfhi(nu.z), nr6 = bflo(nu.w), nr7 = bfhi(nu.w);
    float* mrow = mixed + (size_t)n * HD;
    if (b == e_) {
        if (half == 0) {
            ((float4*)mrow)[2 * hl]     = make_float4(nr0, nr1, nr2, nr3);
            ((float4*)mrow)[2 * hl + 1] = make_float4(nr4, nr5, nr6, nr7);
        }
        return;
    }
    uint4 qv = qu4[(size_t)n * 32 + hl];
    float q0 = bflo(qv.x), q1 = bfhi(qv.x), q2 = bflo(qv.y), q3 = bfhi(qv.y);
    float q4 = bflo(qv.z), q5 = bfhi(qv.z), q6 = bflo(qv.w), q7 = bfhi(qv.w);
    float m = -INFINITY, srun = 0.f;
    float a0 = 0.f, a1 = 0.f, a2 = 0.f, a3 = 0.f, a4 = 0.f, a5 = 0.f, a6 = 0.f, a7 = 0.f;
    int i = b + half;
    uint4 ku, vu;
    if (i < e_) {
        int s0 = adjS[i];
        ku = ku4[(size_t)s0 * 32 + hl];
        vu = vu4[(size_t)s0 * 32 + hl];
    }
    while (i < e_) {
        int in = i + 2;
        uint4 kn, vn;
        if (in < e_) {
            int s1 = adjS[in];
            kn = ku4[(size_t)s1 * 32 + hl];
            vn = vu4[(size_t)s1 * 32 + hl];
        }
        float p = q0 * bflo(ku.x) + q1 * bfhi(ku.x) + q2 * bflo(ku.y) + q3 * bfhi(ku.y)
                + q4 * bflo(ku.z) + q5 * bfhi(ku.z) + q6 * bflo(ku.w) + q7 * bfhi(ku.w);
        p += __shfl_xor(p, 1); p += __shfl_xor(p, 2); p += __shfl_xor(p, 4);
        p += __shfl_xor(p, 8); p += __shfl_xor(p, 16);
        p *= 0.0625f;
        float mn = fmaxf(m, p);
        float scale = exp2f((m - mn) * LOG2E);
        float w = exp2f((p - mn) * LOG2E);
        m = mn;
        srun = srun * scale + w;
        a0 = a0 * scale + w * bflo(vu.x); a1 = a1 * scale + w * bfhi(vu.x);
        a2 = a2 * scale + w * bflo(vu.y); a3 = a3 * scale + w * bfhi(vu.y);
        a4 = a4 * scale + w * bflo(vu.z); a5 = a5 * scale + w * bfhi(vu.z);
        a6 = a6 * scale + w * bflo(vu.w); a7 = a7 * scale + w * bfhi(vu.w);
        i = in; ku = kn; vu = vn;
    }
    float mo = __shfl_xor(m, 32);
    float so = __shfl_xor(srun, 32);
    float mn = fmaxf(m, mo);
    float cs = exp2f((m - mn) * LOG2E);
    float co = exp2f((mo - mn) * LOG2E);
    float st = srun * cs + so * co;
    float inv = 1.f / (st + 1e-16f);
    float o0 = (a0 * cs + __shfl_xor(a0, 32) * co) * inv + nr0;
    float o1 = (a1 * cs + __shfl_xor(a1, 32) * co) * inv + nr1;
    float o2 = (a2 * cs + __shfl_xor(a2, 32) * co) * inv + nr2;
    float o3 = (a3 * cs + __shfl_xor(a3, 32) * co) * inv + nr3;
    float o4 = (a4 * cs + __shfl_xor(a4, 32) * co) * inv + nr4;
    float o5 = (a5 * cs + __shfl_xor(a5, 32) * co) * inv + nr5;
    float o6 = (a6 * cs + __shfl_xor(a6, 32) * co) * inv + nr6;
    float o7 = (a7 * cs + __shfl_xor(a7, 32) * co) * inv + nr7;
    if (half == 0) {
        ((float4*)mrow)[2 * hl]     = make_float4(o0, o1, o2, o3);
        ((float4*)mrow)[2 * hl + 1] = make_float4(o4, o5, o6, o7);
    }
}

extern "C" void kernel_launch(void* const* d_in, const int* in_sizes, int n_in,
                              void* d_out, int out_size, void* d_ws, size_t ws_size,
                              hipStream_t stream) {
    (void)in_sizes; (void)n_in; (void)out_size; (void)ws_size;
    const float* x     = (const float*)d_in[0];
    const float* et    = (const float*)d_in[1];
    const int*   Hm    = (const int*)d_in[2];
    const int*   raw   = (const int*)d_in[3];
    const int*   lg    = (const int*)d_in[4];
    const float* W_gat = (const float*)d_in[5];
    const float* a_src = (const float*)d_in[6];
    const float* a_dst = (const float*)d_in[7];
    const float* b_gat = (const float*)d_in[8];
    const float* W_etn = (const float*)d_in[9];
    const float* W_eg  = (const float*)d_in[10];
    const float* Wr_e1 = (const float*)d_in[11];
    const float* Wn_e1 = (const float*)d_in[12];
    const float* b_e1  = (const float*)d_in[13];
    const float* Wr_e2 = (const float*)d_in[14];
    const float* Wn_e2 = (const float*)d_in[15];
    const float* b_e2  = (const float*)d_in[16];
    const float* Wr_n1 = (const float*)d_in[17];
    const float* Wn_n1 = (const float*)d_in[18];
    const float* b_n1  = (const float*)d_in[19];
    const float* Wr_n2 = (const float*)d_in[20];
    const float* Wn_n2 = (const float*)d_in[21];
    const float* b_n2  = (const float*)d_in[22];
    const float* Wr_n3 = (const float*)d_in[23];
    const float* Wn_n3 = (const float*)d_in[24];
    const float* b_n3  = (const float*)d_in[25];
    const float* Wq    = (const float*)d_in[26];
    const float* Wk    = (const float*)d_in[27];
    const float* Wv    = (const float*)d_in[28];
    const float* W_out = (const float*)d_in[29];

    const int* srcN = raw;
    const int* dstN = raw + EE;
    const int* lgs  = lg;
    const int* lgd  = lg + ELG;

    float* ws = (float*)d_ws;
    size_t off = 0;
    auto alloc = [&](size_t n) { float* p = ws + off; off += (n + 63) & ~(size_t)63; return p; };
    auto allocU = [&](size_t nus) { return (unsigned short*)alloc(nus / 2 + 64); };

    unsigned short* et_bf   = allocU((size_t)EE * FE);
    unsigned short* agg_et  = allocU((size_t)EE * FE);   // reused later as q/k/v
    float* es     = alloc(EE);
    float* ed     = alloc(EE);
    float* Wcomb  = alloc((size_t)FE * HD);
    float* b2     = alloc(HD);
    float* asv    = alloc(FE);
    float* adv    = alloc(FE);
    unsigned short* agg2_bf = allocU((size_t)NN * FE);
    float* degE   = alloc(NN);
    unsigned short* etnL  = allocU((size_t)NN * HD);
    unsigned short* erep  = allocU((size_t)NN * HD);
    unsigned short* meanb = allocU((size_t)NN * HD);
    unsigned short* t1    = allocU((size_t)NN * HD);
    unsigned short* aggr  = allocU((size_t)NN * HD);
    unsigned short* nrep  = allocU((size_t)NN * HD);
    unsigned short* x_bf  = allocU((size_t)NN * HD);
    float* mixed  = alloc((size_t)NN * HD);
    unsigned short* wtb    = allocU((size_t)14 * 65536);
    unsigned short* wcombt = allocU((size_t)HD * FE);
    int* rowptrD  = (int*)alloc(NN + 64);
    int* adjS     = (int*)alloc(EE);
    int* rowptrLG = (int*)alloc(EE + 64);
    int* adjLG    = (int*)alloc(ELG);
    int* rowptrH  = (int*)alloc(NN + 64);
    int* adjH     = (int*)alloc(2 * EE);
    int* cntAll   = (int*)alloc(NTOTC + 64);
    int* scanAll  = (int*)alloc(NTOTC + 64);
    int* posAll   = (int*)alloc(NIDX + 64);
    int* bsum     = (int*)alloc(1024);
    // aliases (lifetime-checked)
    unsigned short* ta = etnL;                 // etnL dead after erep GEMM
    unsigned short* tb = erep;                 // erep dead after edge layer 1
    unsigned short* qb = agg_et;               // agg_et dead after etn_gather
    unsigned short* kb = agg_et + (size_t)NN * HD;
    unsigned short* vb = agg_et + (size_t)2 * NN * HD;
    float* outp = (float*)d_out;

    unsigned short* W_eg_t  = wtb + 0 * 65536;
    unsigned short* Wr_e1_t = wtb + 1 * 65536;
    unsigned short* Wn_e1_t = wtb + 2 * 65536;
    unsigned short* Wr_e2_t = wtb + 3 * 65536;
    unsigned short* Wn_e2_t = wtb + 4 * 65536;
    unsigned short* Wr_n1_t = wtb + 5 * 65536;
    unsigned short* Wn_n1_t = wtb + 6 * 65536;
    unsigned short* Wr_n2_t = wtb + 7 * 65536;
    unsigned short* Wn_n2_t = wtb + 8 * 65536;
    unsigned short* Wr_n3_t = wtb + 9 * 65536;
    unsigned short* Wn_n3_t = wtb + 10 * 65536;
    unsigned short* Wq_t    = wtb + 11 * 65536;
    unsigned short* Wk_t    = wtb + 12 * 65536;
    unsigned short* Wv_t    = wtb + 13 * 65536;

    dim3 gB(4, (NN + 127) / 128);

    // ======== weight conversion + x conversion ========
    Ptr14 p14;
    p14.p[0] = W_eg;  p14.p[1] = Wr_e1; p14.p[2] = Wn_e1; p14.p[3] = Wr_e2;
    p14.p[4] = Wn_e2; p14.p[5] = Wr_n1; p14.p[6] = Wn_n1; p14.p[7] = Wr_n2;
    p14.p[8] = Wn_n2; p14.p[9] = Wr_n3; p14.p[10] = Wn_n3; p14.p[11] = Wq;
    p14.p[12] = Wk;   p14.p[13] = Wv;
    wtrans14<<<14 * 64, 256, 0, stream>>>(p14, wtb);
    conv_bf16<<<(NN * HD / 2 + 255) / 256, 256, 0, stream>>>(x, (unsigned int*)x_bf, NN * HD / 2);

    // ======== CSR build: count+pos (atomic) -> scan -> atomic-free scatter ========
    zero_i32<<<(NTOTC + 255) / 256, 256, 0, stream>>>(cntAll, NTOTC);
    count_pos<<<(NIDX + 255) / 256, 256, 0, stream>>>(dstN, lgd, Hm, cntAll, posAll);
    {
        int nb = (NTOTC + 1023) / 1024;
        scan_pass1<<<nb, 256, 0, stream>>>(cntAll, bsum, NTOTC);
        scan_pass2<<<1, 256, 0, stream>>>(bsum, nb);
        scan_pass3<<<nb, 256, 0, stream>>>(cntAll, bsum, scanAll, NTOTC);
    }
    rebase_all<<<(NTOTC + 255) / 256, 256, 0, stream>>>(scanAll, rowptrD, rowptrLG, rowptrH);
    place_scatter<<<8 * PBLK, 256, 0, stream>>>(srcN, dstN, lgs, lgd, Hm, posAll,
                                                rowptrD, rowptrLG, rowptrH,
                                                adjS, adjLG, adjH);

    // ======== GAT (folded Wcomb = W_gat@W_etn; alpha fused into gather) ========
    gemm_f32<<<dim3(4, 1), 256, 0, stream>>>(W_gat, W_etn, Wcomb, FE, HD, HD);
    wtrans_one<<<(FE / 32) * (HD / 32), 256, 0, stream>>>(Wcomb, wcombt, FE, HD);
    gat_prep<<<FE + 1, 256, 0, stream>>>(W_gat, a_src, a_dst, b_gat, W_etn, asv, adv, b2);
    edge_scores_conv<<<EE / 4, 256, 0, stream>>>(et, asv, adv, es, ed, et_bf);
    gat_fused2<<<EE / 32, 256, 0, stream>>>(rowptrLG, adjLG, es, ed, et_bf, agg_et);

    // ======== EdgeToNode incidence mean + GEMMs ========
    etn_gather3<<<(NN + 31) / 32, 256, 0, stream>>>(rowptrH, adjH, agg_et, agg2_bf, degE);
    gemm_bf16<<<gB, 256, 0, stream>>>(agg2_bf, nullptr, wcombt, nullptr, b2, degE, etnL, NN, FE, 4);
    gemm_bf16<<<gB, 256, 0, stream>>>(etnL, nullptr, W_eg_t, nullptr, nullptr, nullptr, erep, NN, HD, 0);

    // ======== edge_aggr SAGE (2 layers, dual-K fused) ========
    sage_gather2<<<(NN + 7) / 8, 256, 0, stream>>>(erep, rowptrD, adjS, meanb);
    gemm_bf16<<<gB, 256, 0, stream>>>(erep, meanb, Wr_e1_t, Wn_e1_t, b_e1, nullptr, t1, NN, HD, 1);
    sage_gather2<<<(NN + 7) / 8, 256, 0, stream>>>(t1, rowptrD, adjS, meanb);
    gemm_bf16<<<gB, 256, 0, stream>>>(t1, meanb, Wr_e2_t, Wn_e2_t, b_e2, nullptr, aggr, NN, HD, 0);

    // ======== attr_node SAGE (3 layers, dual-K fused) ========
    sage_gather2<<<(NN + 7) / 8, 256, 0, stream>>>(x_bf, rowptrD, adjS, meanb);
    gemm_bf16<<<gB, 256, 0, stream>>>(x_bf, meanb, Wr_n1_t, Wn_n1_t, b_n1, nullptr, ta, NN, HD, 1);
    sage_gather2<<<(NN + 7) / 8, 256, 0, stream>>>(ta, rowptrD, adjS, meanb);
    gemm_bf16<<<gB, 256, 0, stream>>>(ta, meanb, Wr_n2_t, Wn_n2_t, b_n2, nullptr, tb, NN, HD, 1);
    sage_gather2<<<(NN + 7) / 8, 256, 0, stream>>>(tb, rowptrD, adjS, meanb);
    gemm_bf16<<<gB, 256, 0, stream>>>(tb, meanb, Wr_n3_t, Wn_n3_t, b_n3, nullptr, nrep, NN, HD, 0);

    // ======== MixAttention (q,k,v in ONE launch) ========
    gemm_bf16_tri<<<dim3(12, (NN + 127) / 128), 256, 0, stream>>>(
        nrep, Wq_t, qb, aggr, Wk_t, kb, aggr, Wv_t, vb, NN);
    attn_online<<<(NN + 3) / 4, 256, 0, stream>>>(qb, kb, vb, nrep, rowptrD, adjS, mixed);

    // ======== final linear + log_softmax (fused) ========
    gemm_out_lsm<<<dim3(1, (NN + 63) / 64), 256, 0, stream>>>(mixed, W_out, outp, NN);
}

// Round 14
// 756.843 us; speedup vs baseline: 3.6475x; 1.0509x over previous
//
#include <hip/hip_runtime.h>
#include <math.h>

#define NN   20000
#define EE   320000
#define ELG  600000
#define FE   64
#define HD   256
#define FOUT 40
#define LOG2E 1.44269504f
#define NTOTC (NN + EE + NN)            // concatenated count-buffer size
#define NIDX  (EE + ELG + 2 * EE)       // concatenated index-stream size
#define RD_RANGE  ((NN + 7) / 8)        // keys per XCD range (D and H sections)
#define RLG_RANGE ((EE + 7) / 8)        // keys per XCD range (LG section)
#define PBLK 256                        // persistent blocks per XCD class

typedef __attribute__((ext_vector_type(8))) short bf16x8;
typedef __attribute__((ext_vector_type(4))) float f32x4;

__device__ __forceinline__ float leaky02(float x) { return x > 0.f ? x : 0.2f * x; }

__device__ __forceinline__ unsigned short bf16rne(float f) {
    unsigned int u = __float_as_uint(f);
    u = (u + 0x7FFFu + ((u >> 16) & 1u)) >> 16;
    return (unsigned short)u;
}
__device__ __forceinline__ float bflo(unsigned int u) { return __uint_as_float(u << 16); }
__device__ __forceinline__ float bfhi(unsigned int u) { return __uint_as_float(u & 0xffff0000u); }
__device__ __forceinline__ unsigned int bfpack(float a, float b) {
    return (unsigned int)bf16rne(a) | ((unsigned int)bf16rne(b) << 16);
}

// ---------------- small utility kernels ----------------
__global__ void zero_i32(int* __restrict__ p, int n) {
    int i = blockIdx.x * 256 + threadIdx.x;
    if (i < n) p[i] = 0;
}
__global__ void conv_bf16(const float* __restrict__ in, unsigned int* __restrict__ out, int n2) {
    int i = blockIdx.x * 256 + threadIdx.x;
    if (i < n2) { float2 v = ((const float2*)in)[i]; out[i] = bfpack(v.x, v.y); }
}

// ---------------- CSR build: count + in-bucket position in ONE atomic pass ----------------
// cntAll sections: [0,NN) = raw-by-dst, [NN,NN+EE) = lg-by-lgd, [NN+EE,NN+EE+NN) = incidence H
__global__ void count_pos(const int* __restrict__ dstN, const int* __restrict__ lgd,
                          const int* __restrict__ Hm, int* __restrict__ cntAll,
                          int* __restrict__ posAll) {
    int i = blockIdx.x * 256 + threadIdx.x;
    if (i >= NIDX) return;
    int key;
    if (i < EE) key = dstN[i];
    else if (i < EE + ELG) key = NN + lgd[i - EE];
    else key = NN + EE + Hm[i - EE - ELG];
    posAll[i] = atomicAdd(&cntAll[key], 1);
}

__global__ void scan_pass1(const int* __restrict__ in, int* __restrict__ bsum, int n) {
    __shared__ int sm[256];
    int base = blockIdx.x * 1024, t = threadIdx.x;
    int s = 0;
#pragma unroll
    for (int j = 0; j < 4; ++j) { int i = base + t * 4 + j; s += (i < n) ? in[i] : 0; }
    sm[t] = s; __syncthreads();
    for (int o = 128; o > 0; o >>= 1) { if (t < o) sm[t] += sm[t + o]; __syncthreads(); }
    if (t == 0) bsum[blockIdx.x] = sm[0];
}
__global__ void scan_pass2(int* __restrict__ bsum, int nb) {
    __shared__ int sm[1024];
    int t = threadIdx.x;
    for (int i = t; i < nb; i += 256) sm[i] = bsum[i];
    __syncthreads();
    if (t == 0) { int run = 0; for (int i = 0; i < nb; ++i) { int v = sm[i]; sm[i] = run; run += v; } }
    __syncthreads();
    for (int i = t; i < nb; i += 256) bsum[i] = sm[i];
}
// scan pass 3 fused with section rebasing: writes rowptrD/LG/H directly (no scanAll buffer)
__global__ void scan_pass3_rebase(const int* __restrict__ in, const int* __restrict__ boff,
                                  int* __restrict__ rowptrD, int* __restrict__ rowptrLG,
                                  int* __restrict__ rowptrH) {
    __shared__ int tsum[256];
    int base = blockIdx.x * 1024, t = threadIdx.x;
    if (blockIdx.x == 0 && t == 0) { rowptrD[NN] = EE; rowptrLG[EE] = ELG; rowptrH[NN] = 2 * EE; }
    int v[4];
#pragma unroll
    for (int j = 0; j < 4; ++j) { int i = base + t * 4 + j; v[j] = (i < NTOTC) ? in[i] : 0; }
    int loc = v[0] + v[1] + v[2] + v[3];
    tsum[t] = loc; __syncthreads();
    for (int o = 1; o < 256; o <<= 1) {
        int x = (t >= o) ? tsum[t - o] : 0;
        __syncthreads();
        tsum[t] += x;
        __syncthreads();
    }
    int off = boff[blockIdx.x] + (tsum[t] - loc);
    int run = 0;
#pragma unroll
    for (int j = 0; j < 4; ++j) {
        int i = base + t * 4 + j;
        if (i < NTOTC) {
            int val = off + run;
            if (i < NN) rowptrD[i] = val;
            else if (i < NN + EE) rowptrLG[i - NN] = val - EE;
            else rowptrH[i - NN - EE] = val - (EE + ELG);
        }
        run += v[j];
    }
}

// Atomic-free scatter: adj[rowptr[key] + pos[i]] = value. 8-class persistent blocks keep
// each adj region's plain stores on one XCD's L2.
__global__ __launch_bounds__(256)
void place_scatter(const int* __restrict__ srcN, const int* __restrict__ dstN,
                   const int* __restrict__ lgs, const int* __restrict__ lgd,
                   const int* __restrict__ Hm, const int* __restrict__ posAll,
                   const int* __restrict__ rowptrD, const int* __restrict__ rowptrLG,
                   const int* __restrict__ rowptrH,
                   int* __restrict__ adjS, int* __restrict__ adjLG, int* __restrict__ adjH) {
    int r = blockIdx.x & 7;
    int blk = blockIdx.x >> 3;
    const int stride = PBLK * 256;
    for (int i = blk * 256 + threadIdx.x; i < NIDX; i += stride) {
        if (i < EE) {
            int key = dstN[i];
            if (key / RD_RANGE == r) adjS[rowptrD[key] + posAll[i]] = srcN[i];
        } else if (i < EE + ELG) {
            int j = i - EE;
            int key = lgd[j];
            if (key / RLG_RANGE == r) adjLG[rowptrLG[key] + posAll[i]] = lgs[j];
        } else {
            int j = i - EE - ELG;
            int key = Hm[j];
            if (key / RD_RANGE == r) adjH[rowptrH[key] + posAll[i]] = (j < EE) ? j : j - EE;
        }
    }
}

// ---------------- weight transpose+convert ----------------
struct Ptr14 { const float* p[14]; };
__global__ void wtrans14(Ptr14 srcs, unsigned short* __restrict__ dst) {
    int m = blockIdx.x >> 6;
    int tile = blockIdx.x & 63;
    const float* src = srcs.p[m];
    unsigned short* out = dst + (size_t)m * 65536;
    int kb = (tile >> 3) * 32, nb = (tile & 7) * 32;
    __shared__ float sm[32][33];
    int t = threadIdx.x;
#pragma unroll
    for (int i = 0; i < 4; ++i) {
        int e = t + i * 256; int r = e >> 5, c = e & 31;
        sm[r][c] = src[(kb + r) * 256 + nb + c];
    }
    __syncthreads();
#pragma unroll
    for (int i = 0; i < 4; ++i) {
        int e = t + i * 256; int nr = e >> 5, kc = e & 31;
        out[(size_t)(nb + nr) * 256 + kb + kc] = bf16rne(sm[kc][nr]);
    }
}
__global__ void wtrans_one(const float* __restrict__ src, unsigned short* __restrict__ dst,
                           int K, int N) {
    int tilesN = N >> 5;
    int kb = (blockIdx.x / tilesN) * 32, nb = (blockIdx.x % tilesN) * 32;
    __shared__ float sm[32][33];
    int t = threadIdx.x;
#pragma unroll
    for (int i = 0; i < 4; ++i) {
        int e = t + i * 256; int r = e >> 5, c = e & 31;
        sm[r][c] = src[(kb + r) * N + nb + c];
    }
    __syncthreads();
#pragma unroll
    for (int i = 0; i < 4; ++i) {
        int e = t + i * 256; int nr = e >> 5, kc = e & 31;
        dst[(size_t)(nb + nr) * K + kb + kc] = bf16rne(sm[kc][nr]);
    }
}

// ---------------- bf16 MFMA GEMM ----------------
// flags: 1=relu, 4=degE-mask + leaky
__global__ __launch_bounds__(256)
void gemm_bf16(const unsigned short* __restrict__ A1, const unsigned short* __restrict__ A2,
               const unsigned short* __restrict__ W1, const unsigned short* __restrict__ W2,
               const float* __restrict__ bias, const float* __restrict__ degmask,
               unsigned short* __restrict__ C, int M, int K1, int flags) {
    __shared__ unsigned short As[128][40];
    __shared__ unsigned short Bs[64][40];
    int tid = threadIdx.x;
    int w = tid >> 6, l = tid & 63;
    int wr = w >> 1, wc = w & 1;
    int brow = blockIdx.y * 128, bcol = blockIdx.x * 64;
    int Ktot = K1 + (A2 ? 256 : 0);
    f32x4 acc[4][2] = {};
    for (int k0 = 0; k0 < Ktot; k0 += 32) {
        const unsigned short* Ap; const unsigned short* Wp; int kk, Klen;
        if (k0 < K1) { Ap = A1; Wp = W1; kk = k0; Klen = K1; }
        else         { Ap = A2; Wp = W2; kk = k0 - K1; Klen = 256; }
#pragma unroll
        for (int i = 0; i < 4; ++i) {
            int q = tid + i * 256;
            int r = q >> 3, kb = (q & 7) * 4;
            int gr = brow + r;
            ushort4 u;
            if (gr < M) u = *(const ushort4*)(Ap + (size_t)gr * Klen + kk + kb);
            else { u.x = 0; u.y = 0; u.z = 0; u.w = 0; }
            *(ushort4*)(&As[r][kb]) = u;
        }
#pragma unroll
        for (int i = 0; i < 2; ++i) {
            int q = tid + i * 256;
            int n = q >> 3, kb = (q & 7) * 4;
            *(ushort4*)(&Bs[n][kb]) = *(const ushort4*)(Wp + (size_t)(bcol + n) * Klen + kk + kb);
        }
        __syncthreads();
        bf16x8 af[4], bfr[2];
#pragma unroll
        for (int fr = 0; fr < 4; ++fr)
            af[fr] = *(const bf16x8*)(&As[wr * 64 + fr * 16 + (l & 15)][(l >> 4) * 8]);
#pragma unroll
        for (int fc = 0; fc < 2; ++fc)
            bfr[fc] = *(const bf16x8*)(&Bs[wc * 32 + fc * 16 + (l & 15)][(l >> 4) * 8]);
#pragma unroll
        for (int fr = 0; fr < 4; ++fr)
#pragma unroll
            for (int fc = 0; fc < 2; ++fc)
                acc[fr][fc] = __builtin_amdgcn_mfma_f32_16x16x32_bf16(af[fr], bfr[fc], acc[fr][fc], 0, 0, 0);
        __syncthreads();
    }
#pragma unroll
    for (int fr = 0; fr < 4; ++fr) {
#pragma unroll
        for (int fc = 0; fc < 2; ++fc) {
            int col = bcol + wc * 32 + fc * 16 + (l & 15);
#pragma unroll
            for (int i = 0; i < 4; ++i) {
                int row = brow + wr * 64 + fr * 16 + (l >> 4) * 4 + i;
                if (row >= M) continue;
                float v = acc[fr][fc][i];
                if (bias) v += bias[col];
                if (flags & 1) v = fmaxf(v, 0.f);
                if (flags & 4) { v = (degmask[row] > 0.f) ? v : 0.f; v = leaky02(v); }
                C[(size_t)row * 256 + col] = bf16rne(v);
            }
        }
    }
}

// three single-K GEMMs in one launch
__global__ __launch_bounds__(256)
void gemm_bf16_tri(const unsigned short* __restrict__ A0, const unsigned short* __restrict__ W0,
                   unsigned short* __restrict__ C0,
                   const unsigned short* __restrict__ A1, const unsigned short* __restrict__ W1,
                   unsigned short* __restrict__ C1,
                   const unsigned short* __restrict__ A2, const unsigned short* __restrict__ W2,
                   unsigned short* __restrict__ C2, int M) {
    __shared__ unsigned short As[128][40];
    __shared__ unsigned short Bs[64][40];
    int sel = blockIdx.x >> 2;
    const unsigned short* A = (sel == 0) ? A0 : (sel == 1) ? A1 : A2;
    const unsigned short* W = (sel == 0) ? W0 : (sel == 1) ? W1 : W2;
    unsigned short* C = (sel == 0) ? C0 : (sel == 1) ? C1 : C2;
    int tid = threadIdx.x;
    int w = tid >> 6, l = tid & 63;
    int wr = w >> 1, wc = w & 1;
    int brow = blockIdx.y * 128, bcol = (blockIdx.x & 3) * 64;
    f32x4 acc[4][2] = {};
    for (int k0 = 0; k0 < 256; k0 += 32) {
#pragma unroll
        for (int i = 0; i < 4; ++i) {
            int q = tid + i * 256;
            int r = q >> 3, kb = (q & 7) * 4;
            int gr = brow + r;
            ushort4 u;
            if (gr < M) u = *(const ushort4*)(A + (size_t)gr * 256 + k0 + kb);
            else { u.x = 0; u.y = 0; u.z = 0; u.w = 0; }
            *(ushort4*)(&As[r][kb]) = u;
        }
#pragma unroll
        for (int i = 0; i < 2; ++i) {
            int q = tid + i * 256;
            int n = q >> 3, kb = (q & 7) * 4;
            *(ushort4*)(&Bs[n][kb]) = *(const ushort4*)(W + (size_t)(bcol + n) * 256 + k0 + kb);
        }
        __syncthreads();
        bf16x8 af[4], bfr[2];
#pragma unroll
        for (int fr = 0; fr < 4; ++fr)
            af[fr] = *(const bf16x8*)(&As[wr * 64 + fr * 16 + (l & 15)][(l >> 4) * 8]);
#pragma unroll
        for (int fc = 0; fc < 2; ++fc)
            bfr[fc] = *(const bf16x8*)(&Bs[wc * 32 + fc * 16 + (l & 15)][(l >> 4) * 8]);
#pragma unroll
        for (int fr = 0; fr < 4; ++fr)
#pragma unroll
            for (int fc = 0; fc < 2; ++fc)
                acc[fr][fc] = __builtin_amdgcn_mfma_f32_16x16x32_bf16(af[fr], bfr[fc], acc[fr][fc], 0, 0, 0);
        __syncthreads();
    }
#pragma unroll
    for (int fr = 0; fr < 4; ++fr) {
#pragma unroll
        for (int fc = 0; fc < 2; ++fc) {
            int col = bcol + wc * 32 + fc * 16 + (l & 15);
#pragma unroll
            for (int i = 0; i < 4; ++i) {
                int row = brow + wr * 64 + fr * 16 + (l >> 4) * 4 + i;
                if (row >= M) continue;
                C[(size_t)row * 256 + col] = bf16rne(acc[fr][fc][i]);
            }
        }
    }
}

// ---------------- fp32 GEMM (Wcomb build only) ----------------
__global__ __launch_bounds__(256)
void gemm_f32(const float* __restrict__ A, const float* __restrict__ B,
              float* __restrict__ C, int M, int N, int K) {
    const int BM = 64, BN = 64, BK = 16;
    __shared__ float As[BK][BM + 1];
    __shared__ float Bs[BK][BN + 1];
    int tid = threadIdx.x;
    int tr = tid >> 4, tc = tid & 15;
    int brow = blockIdx.y * BM, bcol = blockIdx.x * BN;
    float acc[4][4] = {{0.f}};
    for (int k0 = 0; k0 < K; k0 += BK) {
#pragma unroll
        for (int i = 0; i < 4; ++i) {
            int e = tid + i * 256;
            int r = e >> 4, c = e & 15;
            int gr = brow + r, gc = k0 + c;
            As[c][r] = (gr < M && gc < K) ? A[(long)gr * K + gc] : 0.f;
        }
#pragma unroll
        for (int i = 0; i < 4; ++i) {
            int e = tid + i * 256;
            int r = e >> 6, c = e & 63;
            int gr = k0 + r, gc = bcol + c;
            Bs[r][c] = (gr < K && gc < N) ? B[(long)gr * N + gc] : 0.f;
        }
        __syncthreads();
#pragma unroll
        for (int k = 0; k < BK; ++k) {
            float ra[4], rb[4];
#pragma unroll
            for (int i = 0; i < 4; ++i) ra[i] = As[k][tr * 4 + i];
#pragma unroll
            for (int j = 0; j < 4; ++j) rb[j] = Bs[k][tc * 4 + j];
#pragma unroll
            for (int i = 0; i < 4; ++i)
#pragma unroll
                for (int j = 0; j < 4; ++j) acc[i][j] += ra[i] * rb[j];
        }
        __syncthreads();
    }
#pragma unroll
    for (int i = 0; i < 4; ++i) {
        int gr = brow + tr * 4 + i;
        if (gr >= M) continue;
#pragma unroll
        for (int j = 0; j < 4; ++j) {
            int gc = bcol + tc * 4 + j;
            if (gc < N) C[(long)gr * N + gc] = acc[i][j];
        }
    }
}

// ---------------- final linear + log_softmax fused ----------------
__global__ __launch_bounds__(256)
void gemm_out_lsm(const float* __restrict__ A, const float* __restrict__ B,
                  float* __restrict__ out, int M) {
    const int BK = 16;
    __shared__ float As[BK][65];
    __shared__ float Bs[BK][65];
    __shared__ float tile[64][41];
    __shared__ float lsb[64];
    int tid = threadIdx.x;
    int tr = tid >> 4, tc = tid & 15;
    int brow = blockIdx.y * 64;
    float acc[4][4] = {{0.f}};
    for (int k0 = 0; k0 < 256; k0 += BK) {
#pragma unroll
        for (int i = 0; i < 4; ++i) {
            int e = tid + i * 256;
            int r = e >> 4, c = e & 15;
            int gr = brow + r;
            As[c][r] = (gr < M) ? A[(long)gr * 256 + k0 + c] : 0.f;
        }
#pragma unroll
        for (int i = 0; i < 4; ++i) {
            int e = tid + i * 256;
            int r = e >> 6, c = e & 63;
            Bs[r][c] = (c < FOUT) ? B[(long)(k0 + r) * FOUT + c] : 0.f;
        }
        __syncthreads();
#pragma unroll
        for (int k = 0; k < BK; ++k) {
            float ra[4], rb[4];
#pragma unroll
            for (int i = 0; i < 4; ++i) ra[i] = As[k][tr * 4 + i];
#pragma unroll
            for (int j = 0; j < 4; ++j) rb[j] = Bs[k][tc * 4 + j];
#pragma unroll
            for (int i = 0; i < 4; ++i)
#pragma unroll
                for (int j = 0; j < 4; ++j) acc[i][j] += ra[i] * rb[j];
        }
        __syncthreads();
    }
#pragma unroll
    for (int i = 0; i < 4; ++i)
#pragma unroll
        for (int j = 0; j < 4; ++j) {
            int gc = tc * 4 + j;
            if (gc < FOUT) tile[tr * 4 + i][gc] = acc[i][j];
        }
    __syncthreads();
    if (tid < 64) {
        int gr = brow + tid;
        float mx = -INFINITY;
        if (gr < M) {
            for (int c = 0; c < FOUT; ++c) mx = fmaxf(mx, tile[tid][c]);
            float s = 0.f;
            for (int c = 0; c < FOUT; ++c) s += __expf(tile[tid][c] - mx);
            lsb[tid] = mx + logf(s);
        }
    }
    __syncthreads();
#pragma unroll
    for (int i = 0; i < 4; ++i) {
        int r = tr * 4 + i;
        int gr = brow + r;
        if (gr >= M) continue;
#pragma unroll
        for (int j = 0; j < 4; ++j) {
            int gc = tc * 4 + j;
            if (gc < FOUT) out[(long)gr * FOUT + gc] = tile[r][gc] - lsb[r];
        }
    }
}

// ---------------- GAT pre-computation (wg_av + bias_proj fused) ----------------
__global__ void gat_prep(const float* __restrict__ W, const float* __restrict__ as_,
                         const float* __restrict__ ad_, const float* __restrict__ b_gat,
                         const float* __restrict__ W_etn,
                         float* __restrict__ asv, float* __restrict__ adv, float* __restrict__ b2) {
    int t = threadIdx.x;
    if (blockIdx.x == FE) {
        float s = 0.f;
        for (int i = 0; i < HD; ++i) s += b_gat[i] * W_etn[i * HD + t];
        b2[t] = s;
        return;
    }
    __shared__ float sm[256];
    int i = blockIdx.x;
    float w = W[i * HD + t];
    sm[t] = w * as_[t];
    __syncthreads();
    for (int o = 128; o > 0; o >>= 1) { if (t < o) sm[t] += sm[t + o]; __syncthreads(); }
    if (t == 0) asv[i] = sm[0];
    __syncthreads();
    sm[t] = w * ad_[t];
    __syncthreads();
    for (int o = 128; o > 0; o >>= 1) { if (t < o) sm[t] += sm[t + o]; __syncthreads(); }
    if (t == 0) adv[i] = sm[0];
}

// es/ed scores + bf16 conversion: 16-lane group per edge, float4 per lane (16 B/lane)
__global__ void edge_scores_conv16(const float* __restrict__ et, const float* __restrict__ asv,
                                   const float* __restrict__ adv, float* __restrict__ es,
                                   float* __restrict__ ed, unsigned short* __restrict__ et_bf) {
    int e = blockIdx.x * 16 + (threadIdx.x >> 4);
    int l = threadIdx.x & 15;
    float4 xv = *(const float4*)(et + (size_t)e * FE + l * 4);
    float4 av = *(const float4*)(asv + l * 4);
    float4 dv = *(const float4*)(adv + l * 4);
    uint2 o; o.x = bfpack(xv.x, xv.y); o.y = bfpack(xv.z, xv.w);
    ((uint2*)et_bf)[(size_t)e * 16 + l] = o;   // row = 64 bf16 = 16 uint2 (stride fix)
    float vs = xv.x * av.x + xv.y * av.y + xv.z * av.z + xv.w * av.w;
    float vd = xv.x * dv.x + xv.y * dv.y + xv.z * dv.z + xv.w * dv.w;
    vs += __shfl_xor(vs, 1); vd += __shfl_xor(vd, 1);
    vs += __shfl_xor(vs, 2); vd += __shfl_xor(vd, 2);
    vs += __shfl_xor(vs, 4); vd += __shfl_xor(vd, 4);
    vs += __shfl_xor(vs, 8); vd += __shfl_xor(vd, 8);
    if (l == 0) { es[e] = vs; ed[e] = vd; }
}

// ---------------- GAT: fused alpha + gather (8-lane group, online softmax, one pass) ----------------
__global__ void gat_fused2(const int* __restrict__ rowptr, const int* __restrict__ adj,
                           const float* __restrict__ es, const float* __restrict__ ed,
                           const unsigned short* __restrict__ et_bf,
                           unsigned short* __restrict__ agg_et) {
    int d = blockIdx.x * 32 + (threadIdx.x >> 3);
    int hl = threadIdx.x & 7;                  // row = 8 x uint4 (64 bf16)
    if (d >= EE) return;
    int b = rowptr[d], e_ = rowptr[d + 1];
    const uint4* etu = (const uint4*)et_bf;
    float edd = ed[d];
    float m = leaky02(es[d] + edd);
    float srun = 1.f;
    uint4 u = etu[(size_t)d * 8 + hl];
    float a0 = bflo(u.x), a1 = bfhi(u.x), a2 = bflo(u.y), a3 = bfhi(u.y);
    float a4 = bflo(u.z), a5 = bfhi(u.z), a6 = bflo(u.w), a7 = bfhi(u.w);
    int i = b;
    float esn = 0.f; uint4 un;
    if (i < e_) { int s0 = adj[i]; esn = es[s0]; un = etu[(size_t)s0 * 8 + hl]; }
    while (i < e_) {
        float esc = esn; uint4 uc = un;
        int in = i + 1;
        if (in < e_) { int s1 = adj[in]; esn = es[s1]; un = etu[(size_t)s1 * 8 + hl]; }
        float p = leaky02(esc + edd);
        float mn = fmaxf(m, p);
        float scale = exp2f((m - mn) * LOG2E);
        float w = exp2f((p - mn) * LOG2E);
        m = mn;
        srun = srun * scale + w;
        a0 = a0 * scale + w * bflo(uc.x); a1 = a1 * scale + w * bfhi(uc.x);
        a2 = a2 * scale + w * bflo(uc.y); a3 = a3 * scale + w * bfhi(uc.y);
        a4 = a4 * scale + w * bflo(uc.z); a5 = a5 * scale + w * bfhi(uc.z);
        a6 = a6 * scale + w * bflo(uc.w); a7 = a7 * scale + w * bfhi(uc.w);
        i = in;
    }
    float inv = 1.f / (srun + 1e-16f);
    uint4 o;
    o.x = bfpack(a0 * inv, a1 * inv); o.y = bfpack(a2 * inv, a3 * inv);
    o.z = bfpack(a4 * inv, a5 * inv); o.w = bfpack(a6 * inv, a7 * inv);
    ((uint4*)agg_et)[(size_t)d * 8 + hl] = o;
}

// ---------------- incidence mean (8-lane group, uint4, prefetched) ----------------
__global__ void etn_gather3(const int* __restrict__ rowptr, const int* __restrict__ adj,
                            const unsigned short* __restrict__ agg_et,
                            unsigned short* __restrict__ agg2, float* __restrict__ degE) {
    int n = blockIdx.x * 32 + (threadIdx.x >> 3);
    int hl = threadIdx.x & 7;
    if (n >= NN) return;
    int b = rowptr[n], e_ = rowptr[n + 1];
    const uint4* au = (const uint4*)agg_et;
    int i = b;
    uint4 un;
    if (i < e_) un = au[(size_t)adj[i] * 8 + hl];
    float a0 = 0.f, a1 = 0.f, a2 = 0.f, a3 = 0.f, a4 = 0.f, a5 = 0.f, a6 = 0.f, a7 = 0.f;
    while (i < e_) {
        uint4 uc = un;
        int in = i + 1;
        if (in < e_) un = au[(size_t)adj[in] * 8 + hl];
        a0 += bflo(uc.x); a1 += bfhi(uc.x); a2 += bflo(uc.y); a3 += bfhi(uc.y);
        a4 += bflo(uc.z); a5 += bfhi(uc.z); a6 += bflo(uc.w); a7 += bfhi(uc.w);
        i = in;
    }
    float deg = (float)(e_ - b);
    float inv = 1.f / fmaxf(deg, 1.f);
    uint4 o;
    o.x = bfpack(a0 * inv, a1 * inv); o.y = bfpack(a2 * inv, a3 * inv);
    o.z = bfpack(a4 * inv, a5 * inv); o.w = bfpack(a6 * inv, a7 * inv);
    ((uint4*)agg2)[(size_t)n * 8 + hl] = o;
    if (hl == 0) degE[n] = deg;
}

// ---------------- SAGE mean (2 nodes/wave, 32-lane halves, prefetched) ----------------
__global__ void sage_gather2(const unsigned short* __restrict__ X, const int* __restrict__ rowptr,
                             const int* __restrict__ adjS, unsigned short* __restrict__ mean) {
    int base = (blockIdx.x * 4 + (threadIdx.x >> 6)) * 2;
    int lane = threadIdx.x & 63;
    int half = lane >> 5, hl = lane & 31;
    int n = base + half;
    if (n >= NN) return;
    int b = rowptr[n], e_ = rowptr[n + 1];
    const uint4* Xu = (const uint4*)X;
    int i = b;
    uint4 un;
    if (i < e_) un = Xu[(size_t)adjS[i] * 32 + hl];
    float a0 = 0.f, a1 = 0.f, a2 = 0.f, a3 = 0.f, a4 = 0.f, a5 = 0.f, a6 = 0.f, a7 = 0.f;
    while (i < e_) {
        uint4 uc = un;
        int in = i + 1;
        if (in < e_) un = Xu[(size_t)adjS[in] * 32 + hl];
        a0 += bflo(uc.x); a1 += bfhi(uc.x); a2 += bflo(uc.y); a3 += bfhi(uc.y);
        a4 += bflo(uc.z); a5 += bfhi(uc.z); a6 += bflo(uc.w); a7 += bfhi(uc.w);
        i = in;
    }
    float inv = 1.f / fmaxf((float)(e_ - b), 1.f);
    uint4 o;
    o.x = bfpack(a0 * inv, a1 * inv); o.y = bfpack(a2 * inv, a3 * inv);
    o.z = bfpack(a4 * inv, a5 * inv); o.w = bfpack(a6 * inv, a7 * inv);
    ((uint4*)mean)[(size_t)n * 32 + hl] = o;
}

// ---------------- MixAttention: online softmax, k/v prefetched 2 ahead ----------------
__global__ void attn_online(const unsigned short* __restrict__ q, const unsigned short* __restrict__ k,
                            const unsigned short* __restrict__ v, const unsigned short* __restrict__ nrep,
                            const int* __restrict__ rowptr, const int* __restrict__ adjS,
                            float* __restrict__ mixed) {
    int n = blockIdx.x * 4 + (threadIdx.x >> 6);
    int lane = threadIdx.x & 63;
    if (n >= NN) return;
    int half = lane >> 5, hl = lane & 31;
    int b = rowptr[n], e_ = rowptr[n + 1];
    const uint4* qu4 = (const uint4*)q;
    const uint4* ku4 = (const uint4*)k;
    const uint4* vu4 = (const uint4*)v;
    const uint4* nu4 = (const uint4*)nrep;
    uint4 nu = nu4[(size_t)n * 32 + hl];
    float nr0 = bflo(nu.x), nr1 = bfhi(nu.x), nr2 = bflo(nu.y), nr3 = bfhi(nu.y);
    float nr4 = bflo(nu.z), nr5 = bfhi(nu.z), nr6 = bflo(nu.w), nr7 = bfhi(nu.w);
    float* mrow = mixed + (size_t)n * HD;
    if (b == e_) {
        if (half == 0) {
            ((float4*)mrow)[2 * hl]     = make_float4(nr0, nr1, nr2, nr3);
            ((float4*)mrow)[2 * hl + 1] = make_float4(nr4, nr5, nr6, nr7);
        }
        return;
    }
    uint4 qv = qu4[(size_t)n * 32 + hl];
    float q0 = bflo(qv.x), q1 = bfhi(qv.x), q2 = bflo(qv.y), q3 = bfhi(qv.y);
    float q4 = bflo(qv.z), q5 = bfhi(qv.z), q6 = bflo(qv.w), q7 = bfhi(qv.w);
    float m = -INFINITY, srun = 0.f;
    float a0 = 0.f, a1 = 0.f, a2 = 0.f, a3 = 0.f, a4 = 0.f, a5 = 0.f, a6 = 0.f, a7 = 0.f;
    int i = b + half;
    uint4 ku, vu;
    if (i < e_) {
        int s0 = adjS[i];
        ku = ku4[(size_t)s0 * 32 + hl];
        vu = vu4[(size_t)s0 * 32 + hl];
    }
    while (i < e_) {
        int in = i + 2;
        uint4 kn, vn;
        if (in < e_) {
            int s1 = adjS[in];
            kn = ku4[(size_t)s1 * 32 + hl];
            vn = vu4[(size_t)s1 * 32 + hl];
        }
        float p = q0 * bflo(ku.x) + q1 * bfhi(ku.x) + q2 * bflo(ku.y) + q3 * bfhi(ku.y)
                + q4 * bflo(ku.z) + q5 * bfhi(ku.z) + q6 * bflo(ku.w) + q7 * bfhi(ku.w);
        p += __shfl_xor(p, 1); p += __shfl_xor(p, 2); p += __shfl_xor(p, 4);
        p += __shfl_xor(p, 8); p += __shfl_xor(p, 16);
        p *= 0.0625f;
        float mn = fmaxf(m, p);
        float scale = exp2f((m - mn) * LOG2E);
        float w = exp2f((p - mn) * LOG2E);
        m = mn;
        srun = srun * scale + w;
        a0 = a0 * scale + w * bflo(vu.x); a1 = a1 * scale + w * bfhi(vu.x);
        a2 = a2 * scale + w * bflo(vu.y); a3 = a3 * scale + w * bfhi(vu.y);
        a4 = a4 * scale + w * bflo(vu.z); a5 = a5 * scale + w * bfhi(vu.z);
        a6 = a6 * scale + w * bflo(vu.w); a7 = a7 * scale + w * bfhi(vu.w);
        i = in; ku = kn; vu = vn;
    }
    float mo = __shfl_xor(m, 32);
    float so = __shfl_xor(srun, 32);
    float mn = fmaxf(m, mo);
    float cs = exp2f((m - mn) * LOG2E);
    float co = exp2f((mo - mn) * LOG2E);
    float st = srun * cs + so * co;
    float inv = 1.f / (st + 1e-16f);
    float o0 = (a0 * cs + __shfl_xor(a0, 32) * co) * inv + nr0;
    float o1 = (a1 * cs + __shfl_xor(a1, 32) * co) * inv + nr1;
    float o2 = (a2 * cs + __shfl_xor(a2, 32) * co) * inv + nr2;
    float o3 = (a3 * cs + __shfl_xor(a3, 32) * co) * inv + nr3;
    float o4 = (a4 * cs + __shfl_xor(a4, 32) * co) * inv + nr4;
    float o5 = (a5 * cs + __shfl_xor(a5, 32) * co) * inv + nr5;
    float o6 = (a6 * cs + __shfl_xor(a6, 32) * co) * inv + nr6;
    float o7 = (a7 * cs + __shfl_xor(a7, 32) * co) * inv + nr7;
    if (half == 0) {
        ((float4*)mrow)[2 * hl]     = make_float4(o0, o1, o2, o3);
        ((float4*)mrow)[2 * hl + 1] = make_float4(o4, o5, o6, o7);
    }
}

extern "C" void kernel_launch(void* const* d_in, const int* in_sizes, int n_in,
                              void* d_out, int out_size, void* d_ws, size_t ws_size,
                              hipStream_t stream) {
    (void)in_sizes; (void)n_in; (void)out_size; (void)ws_size;
    const float* x     = (const float*)d_in[0];
    const float* et    = (const float*)d_in[1];
    const int*   Hm    = (const int*)d_in[2];
    const int*   raw   = (const int*)d_in[3];
    const int*   lg    = (const int*)d_in[4];
    const float* W_gat = (const float*)d_in[5];
    const float* a_src = (const float*)d_in[6];
    const float* a_dst = (const float*)d_in[7];
    const float* b_gat = (const float*)d_in[8];
    const float* W_etn = (const float*)d_in[9];
    const float* W_eg  = (const float*)d_in[10];
    const float* Wr_e1 = (const float*)d_in[11];
    const float* Wn_e1 = (const float*)d_in[12];
    const float* b_e1  = (const float*)d_in[13];
    const float* Wr_e2 = (const float*)d_in[14];
    const float* Wn_e2 = (const float*)d_in[15];
    const float* b_e2  = (const float*)d_in[16];
    const float* Wr_n1 = (const float*)d_in[17];
    const float* Wn_n1 = (const float*)d_in[18];
    const float* b_n1  = (const float*)d_in[19];
    const float* Wr_n2 = (const float*)d_in[20];
    const float* Wn_n2 = (const float*)d_in[21];
    const float* b_n2  = (const float*)d_in[22];
    const float* Wr_n3 = (const float*)d_in[23];
    const float* Wn_n3 = (const float*)d_in[24];
    const float* b_n3  = (const float*)d_in[25];
    const float* Wq    = (const float*)d_in[26];
    const float* Wk    = (const float*)d_in[27];
    const float* Wv    = (const float*)d_in[28];
    const float* W_out = (const float*)d_in[29];

    const int* srcN = raw;
    const int* dstN = raw + EE;
    const int* lgs  = lg;
    const int* lgd  = lg + ELG;

    float* ws = (float*)d_ws;
    size_t off = 0;
    auto alloc = [&](size_t n) { float* p = ws + off; off += (n + 63) & ~(size_t)63; return p; };
    auto allocU = [&](size_t nus) { return (unsigned short*)alloc(nus / 2 + 64); };

    unsigned short* et_bf   = allocU((size_t)EE * FE);
    unsigned short* agg_et  = allocU((size_t)EE * FE);   // reused later as q/k/v
    float* es     = alloc(EE);
    float* ed     = alloc(EE);
    float* Wcomb  = alloc((size_t)FE * HD);
    float* b2     = alloc(HD);
    float* asv    = alloc(FE);
    float* adv    = alloc(FE);
    unsigned short* agg2_bf = allocU((size_t)NN * FE);
    float* degE   = alloc(NN);
    unsigned short* etnL  = allocU((size_t)NN * HD);
    unsigned short* erep  = allocU((size_t)NN * HD);
    unsigned short* meanb = allocU((size_t)NN * HD);
    unsigned short* t1    = allocU((size_t)NN * HD);
    unsigned short* aggr  = allocU((size_t)NN * HD);
    unsigned short* nrep  = allocU((size_t)NN * HD);
    unsigned short* x_bf  = allocU((size_t)NN * HD);
    float* mixed  = alloc((size_t)NN * HD);
    unsigned short* wtb    = allocU((size_t)14 * 65536);
    unsigned short* wcombt = allocU((size_t)HD * FE);
    int* rowptrD  = (int*)alloc(NN + 64);
    int* adjS     = (int*)alloc(EE);
    int* rowptrLG = (int*)alloc(EE + 64);
    int* adjLG    = (int*)alloc(ELG);
    int* rowptrH  = (int*)alloc(NN + 64);
    int* adjH     = (int*)alloc(2 * EE);
    int* cntAll   = (int*)alloc(NTOTC + 64);
    int* posAll   = (int*)alloc(NIDX + 64);
    int* bsum     = (int*)alloc(1024);
    // aliases (lifetime-checked)
    unsigned short* ta = etnL;                 // etnL dead after erep GEMM
    unsigned short* tb = erep;                 // erep dead after edge layer 1
    unsigned short* qb = agg_et;               // agg_et dead after etn_gather
    unsigned short* kb = agg_et + (size_t)NN * HD;
    unsigned short* vb = agg_et + (size_t)2 * NN * HD;
    float* outp = (float*)d_out;

    unsigned short* W_eg_t  = wtb + 0 * 65536;
    unsigned short* Wr_e1_t = wtb + 1 * 65536;
    unsigned short* Wn_e1_t = wtb + 2 * 65536;
    unsigned short* Wr_e2_t = wtb + 3 * 65536;
    unsigned short* Wn_e2_t = wtb + 4 * 65536;
    unsigned short* Wr_n1_t = wtb + 5 * 65536;
    unsigned short* Wn_n1_t = wtb + 6 * 65536;
    unsigned short* Wr_n2_t = wtb + 7 * 65536;
    unsigned short* Wn_n2_t = wtb + 8 * 65536;
    unsigned short* Wr_n3_t = wtb + 9 * 65536;
    unsigned short* Wn_n3_t = wtb + 10 * 65536;
    unsigned short* Wq_t    = wtb + 11 * 65536;
    unsigned short* Wk_t    = wtb + 12 * 65536;
    unsigned short* Wv_t    = wtb + 13 * 65536;

    dim3 gB(4, (NN + 127) / 128);

    // ======== weight conversion + x conversion ========
    Ptr14 p14;
    p14.p[0] = W_eg;  p14.p[1] = Wr_e1; p14.p[2] = Wn_e1; p14.p[3] = Wr_e2;
    p14.p[4] = Wn_e2; p14.p[5] = Wr_n1; p14.p[6] = Wn_n1; p14.p[7] = Wr_n2;
    p14.p[8] = Wn_n2; p14.p[9] = Wr_n3; p14.p[10] = Wn_n3; p14.p[11] = Wq;
    p14.p[12] = Wk;   p14.p[13] = Wv;
    wtrans14<<<14 * 64, 256, 0, stream>>>(p14, wtb);
    conv_bf16<<<(NN * HD / 2 + 255) / 256, 256, 0, stream>>>(x, (unsigned int*)x_bf, NN * HD / 2);

    // ======== CSR build: count+pos (atomic) -> scan+rebase -> atomic-free scatter ========
    zero_i32<<<(NTOTC + 255) / 256, 256, 0, stream>>>(cntAll, NTOTC);
    count_pos<<<(NIDX + 255) / 256, 256, 0, stream>>>(dstN, lgd, Hm, cntAll, posAll);
    {
        int nb = (NTOTC + 1023) / 1024;
        scan_pass1<<<nb, 256, 0, stream>>>(cntAll, bsum, NTOTC);
        scan_pass2<<<1, 256, 0, stream>>>(bsum, nb);
        scan_pass3_rebase<<<nb, 256, 0, stream>>>(cntAll, bsum, rowptrD, rowptrLG, rowptrH);
    }
    place_scatter<<<8 * PBLK, 256, 0, stream>>>(srcN, dstN, lgs, lgd, Hm, posAll,
                                                rowptrD, rowptrLG, rowptrH,
                                                adjS, adjLG, adjH);

    // ======== GAT (folded Wcomb = W_gat@W_etn; alpha fused into gather) ========
    gemm_f32<<<dim3(4, 1), 256, 0, stream>>>(W_gat, W_etn, Wcomb, FE, HD, HD);
    wtrans_one<<<(FE / 32) * (HD / 32), 256, 0, stream>>>(Wcomb, wcombt, FE, HD);
    gat_prep<<<FE + 1, 256, 0, stream>>>(W_gat, a_src, a_dst, b_gat, W_etn, asv, adv, b2);
    edge_scores_conv16<<<EE / 16, 256, 0, stream>>>(et, asv, adv, es, ed, et_bf);
    gat_fused2<<<EE / 32, 256, 0, stream>>>(rowptrLG, adjLG, es, ed, et_bf, agg_et);

    // ======== EdgeToNode incidence mean + GEMMs ========
    etn_gather3<<<(NN + 31) / 32, 256, 0, stream>>>(rowptrH, adjH, agg_et, agg2_bf, degE);
    gemm_bf16<<<gB, 256, 0, stream>>>(agg2_bf, nullptr, wcombt, nullptr, b2, degE, etnL, NN, FE, 4);
    gemm_bf16<<<gB, 256, 0, stream>>>(etnL, nullptr, W_eg_t, nullptr, nullptr, nullptr, erep, NN, HD, 0);

    // ======== edge_aggr SAGE (2 layers, dual-K fused) ========
    sage_gather2<<<(NN + 7) / 8, 256, 0, stream>>>(erep, rowptrD, adjS, meanb);
    gemm_bf16<<<gB, 256, 0, stream>>>(erep, meanb, Wr_e1_t, Wn_e1_t, b_e1, nullptr, t1, NN, HD, 1);
    sage_gather2<<<(NN + 7) / 8, 256, 0, stream>>>(t1, rowptrD, adjS, meanb);
    gemm_bf16<<<gB, 256, 0, stream>>>(t1, meanb, Wr_e2_t, Wn_e2_t, b_e2, nullptr, aggr, NN, HD, 0);

    // ======== attr_node SAGE (3 layers, dual-K fused) ========
    sage_gather2<<<(NN + 7) / 8, 256, 0, stream>>>(x_bf, rowptrD, adjS, meanb);
    gemm_bf16<<<gB, 256, 0, stream>>>(x_bf, meanb, Wr_n1_t, Wn_n1_t, b_n1, nullptr, ta, NN, HD, 1);
    sage_gather2<<<(NN + 7) / 8, 256, 0, stream>>>(ta, rowptrD, adjS, meanb);
    gemm_bf16<<<gB, 256, 0, stream>>>(ta, meanb, Wr_n2_t, Wn_n2_t, b_n2, nullptr, tb, NN, HD, 1);
    sage_gather2<<<(NN + 7) / 8, 256, 0, stream>>>(tb, rowptrD, adjS, meanb);
    gemm_bf16<<<gB, 256, 0, stream>>>(tb, meanb, Wr_n3_t, Wn_n3_t, b_n3, nullptr, nrep, NN, HD, 0);

    // ======== MixAttention (q,k,v in ONE launch) ========
    gemm_bf16_tri<<<dim3(12, (NN + 127) / 128), 256, 0, stream>>>(
        nrep, Wq_t, qb, aggr, Wk_t, kb, aggr, Wv_t, vb, NN);
    attn_online<<<(NN + 3) / 4, 256, 0, stream>>>(qb, kb, vb, nrep, rowptrD, adjS, mixed);

    // ======== final linear + log_softmax (fused) ========
    gemm_out_lsm<<<dim3(1, (NN + 63) / 64), 256, 0, stream>>>(mixed, W_out, outp, NN);
}

// Round 15
// 754.242 us; speedup vs baseline: 3.6601x; 1.0034x over previous
//
#include <hip/hip_runtime.h>
#include <math.h>

#define NN   20000
#define EE   320000
#define ELG  600000
#define FE   64
#define HD   256
#define FOUT 40
#define LOG2E 1.44269504f
#define NTOTC (NN + EE + NN)            // concatenated count-buffer size
#define NIDX  (EE + ELG + 2 * EE)       // concatenated index-stream size
#define RD_RANGE  ((NN + 7) / 8)        // keys per XCD range (D and H sections)
#define RLG_RANGE ((EE + 7) / 8)        // keys per XCD range (LG section)
#define PBLK 256                        // persistent blocks per XCD class

typedef __attribute__((ext_vector_type(8))) short bf16x8;
typedef __attribute__((ext_vector_type(4))) float f32x4;

__device__ __forceinline__ float leaky02(float x) { return x > 0.f ? x : 0.2f * x; }

__device__ __forceinline__ unsigned short bf16rne(float f) {
    unsigned int u = __float_as_uint(f);
    u = (u + 0x7FFFu + ((u >> 16) & 1u)) >> 16;
    return (unsigned short)u;
}
__device__ __forceinline__ float bflo(unsigned int u) { return __uint_as_float(u << 16); }
__device__ __forceinline__ float bfhi(unsigned int u) { return __uint_as_float(u & 0xffff0000u); }
__device__ __forceinline__ unsigned int bfpack(float a, float b) {
    return (unsigned int)bf16rne(a) | ((unsigned int)bf16rne(b) << 16);
}

// ---------------- small utility kernels ----------------
__global__ void zero_i32(int* __restrict__ p, int n) {
    int i = blockIdx.x * 256 + threadIdx.x;
    if (i < n) p[i] = 0;
}
__global__ void conv_bf16(const float* __restrict__ in, unsigned int* __restrict__ out, int n2) {
    int i = blockIdx.x * 256 + threadIdx.x;
    if (i < n2) { float2 v = ((const float2*)in)[i]; out[i] = bfpack(v.x, v.y); }
}

// ---------------- CSR build: count + in-bucket position in ONE atomic pass ----------------
__global__ void count_pos(const int* __restrict__ dstN, const int* __restrict__ lgd,
                          const int* __restrict__ Hm, int* __restrict__ cntAll,
                          int* __restrict__ posAll) {
    int i = blockIdx.x * 256 + threadIdx.x;
    if (i >= NIDX) return;
    int key;
    if (i < EE) key = dstN[i];
    else if (i < EE + ELG) key = NN + lgd[i - EE];
    else key = NN + EE + Hm[i - EE - ELG];
    posAll[i] = atomicAdd(&cntAll[key], 1);
}

__global__ void scan_pass1(const int* __restrict__ in, int* __restrict__ bsum, int n) {
    __shared__ int sm[256];
    int base = blockIdx.x * 1024, t = threadIdx.x;
    int s = 0;
#pragma unroll
    for (int j = 0; j < 4; ++j) { int i = base + t * 4 + j; s += (i < n) ? in[i] : 0; }
    sm[t] = s; __syncthreads();
    for (int o = 128; o > 0; o >>= 1) { if (t < o) sm[t] += sm[t + o]; __syncthreads(); }
    if (t == 0) bsum[blockIdx.x] = sm[0];
}
__global__ void scan_pass2(int* __restrict__ bsum, int nb) {
    __shared__ int sm[1024];
    int t = threadIdx.x;
    for (int i = t; i < nb; i += 256) sm[i] = bsum[i];
    __syncthreads();
    if (t == 0) { int run = 0; for (int i = 0; i < nb; ++i) { int v = sm[i]; sm[i] = run; run += v; } }
    __syncthreads();
    for (int i = t; i < nb; i += 256) bsum[i] = sm[i];
}
// scan pass 3 fused with section rebasing
__global__ void scan_pass3_rebase(const int* __restrict__ in, const int* __restrict__ boff,
                                  int* __restrict__ rowptrD, int* __restrict__ rowptrLG,
                                  int* __restrict__ rowptrH) {
    __shared__ int tsum[256];
    int base = blockIdx.x * 1024, t = threadIdx.x;
    if (blockIdx.x == 0 && t == 0) { rowptrD[NN] = EE; rowptrLG[EE] = ELG; rowptrH[NN] = 2 * EE; }
    int v[4];
#pragma unroll
    for (int j = 0; j < 4; ++j) { int i = base + t * 4 + j; v[j] = (i < NTOTC) ? in[i] : 0; }
    int loc = v[0] + v[1] + v[2] + v[3];
    tsum[t] = loc; __syncthreads();
    for (int o = 1; o < 256; o <<= 1) {
        int x = (t >= o) ? tsum[t - o] : 0;
        __syncthreads();
        tsum[t] += x;
        __syncthreads();
    }
    int off = boff[blockIdx.x] + (tsum[t] - loc);
    int run = 0;
#pragma unroll
    for (int j = 0; j < 4; ++j) {
        int i = base + t * 4 + j;
        if (i < NTOTC) {
            int val = off + run;
            if (i < NN) rowptrD[i] = val;
            else if (i < NN + EE) rowptrLG[i - NN] = val - EE;
            else rowptrH[i - NN - EE] = val - (EE + ELG);
        }
        run += v[j];
    }
}

// Atomic-free scatter; 8-class persistent blocks keep each adj region's stores on one XCD L2.
__global__ __launch_bounds__(256)
void place_scatter(const int* __restrict__ srcN, const int* __restrict__ dstN,
                   const int* __restrict__ lgs, const int* __restrict__ lgd,
                   const int* __restrict__ Hm, const int* __restrict__ posAll,
                   const int* __restrict__ rowptrD, const int* __restrict__ rowptrLG,
                   const int* __restrict__ rowptrH,
                   int* __restrict__ adjS, int* __restrict__ adjLG, int* __restrict__ adjH) {
    int r = blockIdx.x & 7;
    int blk = blockIdx.x >> 3;
    const int stride = PBLK * 256;
    for (int i = blk * 256 + threadIdx.x; i < NIDX; i += stride) {
        if (i < EE) {
            int key = dstN[i];
            if (key / RD_RANGE == r) adjS[rowptrD[key] + posAll[i]] = srcN[i];
        } else if (i < EE + ELG) {
            int j = i - EE;
            int key = lgd[j];
            if (key / RLG_RANGE == r) adjLG[rowptrLG[key] + posAll[i]] = lgs[j];
        } else {
            int j = i - EE - ELG;
            int key = Hm[j];
            if (key / RD_RANGE == r) adjH[rowptrH[key] + posAll[i]] = (j < EE) ? j : j - EE;
        }
    }
}

// ---------------- weight transpose+convert ----------------
struct Ptr14 { const float* p[14]; };
__global__ void wtrans14(Ptr14 srcs, unsigned short* __restrict__ dst) {
    int m = blockIdx.x >> 6;
    int tile = blockIdx.x & 63;
    const float* src = srcs.p[m];
    unsigned short* out = dst + (size_t)m * 65536;
    int kb = (tile >> 3) * 32, nb = (tile & 7) * 32;
    __shared__ float sm[32][33];
    int t = threadIdx.x;
#pragma unroll
    for (int i = 0; i < 4; ++i) {
        int e = t + i * 256; int r = e >> 5, c = e & 31;
        sm[r][c] = src[(kb + r) * 256 + nb + c];
    }
    __syncthreads();
#pragma unroll
    for (int i = 0; i < 4; ++i) {
        int e = t + i * 256; int nr = e >> 5, kc = e & 31;
        out[(size_t)(nb + nr) * 256 + kb + kc] = bf16rne(sm[kc][nr]);
    }
}
__global__ void wtrans_one(const float* __restrict__ src, unsigned short* __restrict__ dst,
                           int K, int N) {
    int tilesN = N >> 5;
    int kb = (blockIdx.x / tilesN) * 32, nb = (blockIdx.x % tilesN) * 32;
    __shared__ float sm[32][33];
    int t = threadIdx.x;
#pragma unroll
    for (int i = 0; i < 4; ++i) {
        int e = t + i * 256; int r = e >> 5, c = e & 31;
        sm[r][c] = src[(kb + r) * N + nb + c];
    }
    __syncthreads();
#pragma unroll
    for (int i = 0; i < 4; ++i) {
        int e = t + i * 256; int nr = e >> 5, kc = e & 31;
        dst[(size_t)(nb + nr) * K + kb + kc] = bf16rne(sm[kc][nr]);
    }
}

// ---------------- bf16 MFMA GEMM ----------------
// flags: 1=relu, 4=degE-mask + leaky
__global__ __launch_bounds__(256)
void gemm_bf16(const unsigned short* __restrict__ A1, const unsigned short* __restrict__ A2,
               const unsigned short* __restrict__ W1, const unsigned short* __restrict__ W2,
               const float* __restrict__ bias, const float* __restrict__ degmask,
               unsigned short* __restrict__ C, int M, int K1, int flags) {
    __shared__ unsigned short As[128][40];
    __shared__ unsigned short Bs[64][40];
    int tid = threadIdx.x;
    int w = tid >> 6, l = tid & 63;
    int wr = w >> 1, wc = w & 1;
    int brow = blockIdx.y * 128, bcol = blockIdx.x * 64;
    int Ktot = K1 + (A2 ? 256 : 0);
    f32x4 acc[4][2] = {};
    for (int k0 = 0; k0 < Ktot; k0 += 32) {
        const unsigned short* Ap; const unsigned short* Wp; int kk, Klen;
        if (k0 < K1) { Ap = A1; Wp = W1; kk = k0; Klen = K1; }
        else         { Ap = A2; Wp = W2; kk = k0 - K1; Klen = 256; }
#pragma unroll
        for (int i = 0; i < 4; ++i) {
            int q = tid + i * 256;
            int r = q >> 3, kb = (q & 7) * 4;
            int gr = brow + r;
            ushort4 u;
            if (gr < M) u = *(const ushort4*)(Ap + (size_t)gr * Klen + kk + kb);
            else { u.x = 0; u.y = 0; u.z = 0; u.w = 0; }
            *(ushort4*)(&As[r][kb]) = u;
        }
#pragma unroll
        for (int i = 0; i < 2; ++i) {
            int q = tid + i * 256;
            int n = q >> 3, kb = (q & 7) * 4;
            *(ushort4*)(&Bs[n][kb]) = *(const ushort4*)(Wp + (size_t)(bcol + n) * Klen + kk + kb);
        }
        __syncthreads();
        bf16x8 af[4], bfr[2];
#pragma unroll
        for (int fr = 0; fr < 4; ++fr)
            af[fr] = *(const bf16x8*)(&As[wr * 64 + fr * 16 + (l & 15)][(l >> 4) * 8]);
#pragma unroll
        for (int fc = 0; fc < 2; ++fc)
            bfr[fc] = *(const bf16x8*)(&Bs[wc * 32 + fc * 16 + (l & 15)][(l >> 4) * 8]);
#pragma unroll
        for (int fr = 0; fr < 4; ++fr)
#pragma unroll
            for (int fc = 0; fc < 2; ++fc)
                acc[fr][fc] = __builtin_amdgcn_mfma_f32_16x16x32_bf16(af[fr], bfr[fc], acc[fr][fc], 0, 0, 0);
        __syncthreads();
    }
#pragma unroll
    for (int fr = 0; fr < 4; ++fr) {
#pragma unroll
        for (int fc = 0; fc < 2; ++fc) {
            int col = bcol + wc * 32 + fc * 16 + (l & 15);
#pragma unroll
            for (int i = 0; i < 4; ++i) {
                int row = brow + wr * 64 + fr * 16 + (l >> 4) * 4 + i;
                if (row >= M) continue;
                float v = acc[fr][fc][i];
                if (bias) v += bias[col];
                if (flags & 1) v = fmaxf(v, 0.f);
                if (flags & 4) { v = (degmask[row] > 0.f) ? v : 0.f; v = leaky02(v); }
                C[(size_t)row * 256 + col] = bf16rne(v);
            }
        }
    }
}

// three single-K GEMMs in one launch
__global__ __launch_bounds__(256)
void gemm_bf16_tri(const unsigned short* __restrict__ A0, const unsigned short* __restrict__ W0,
                   unsigned short* __restrict__ C0,
                   const unsigned short* __restrict__ A1, const unsigned short* __restrict__ W1,
                   unsigned short* __restrict__ C1,
                   const unsigned short* __restrict__ A2, const unsigned short* __restrict__ W2,
                   unsigned short* __restrict__ C2, int M) {
    __shared__ unsigned short As[128][40];
    __shared__ unsigned short Bs[64][40];
    int sel = blockIdx.x >> 2;
    const unsigned short* A = (sel == 0) ? A0 : (sel == 1) ? A1 : A2;
    const unsigned short* W = (sel == 0) ? W0 : (sel == 1) ? W1 : W2;
    unsigned short* C = (sel == 0) ? C0 : (sel == 1) ? C1 : C2;
    int tid = threadIdx.x;
    int w = tid >> 6, l = tid & 63;
    int wr = w >> 1, wc = w & 1;
    int brow = blockIdx.y * 128, bcol = (blockIdx.x & 3) * 64;
    f32x4 acc[4][2] = {};
    for (int k0 = 0; k0 < 256; k0 += 32) {
#pragma unroll
        for (int i = 0; i < 4; ++i) {
            int q = tid + i * 256;
            int r = q >> 3, kb = (q & 7) * 4;
            int gr = brow + r;
            ushort4 u;
            if (gr < M) u = *(const ushort4*)(A + (size_t)gr * 256 + k0 + kb);
            else { u.x = 0; u.y = 0; u.z = 0; u.w = 0; }
            *(ushort4*)(&As[r][kb]) = u;
        }
#pragma unroll
        for (int i = 0; i < 2; ++i) {
            int q = tid + i * 256;
            int n = q >> 3, kb = (q & 7) * 4;
            *(ushort4*)(&Bs[n][kb]) = *(const ushort4*)(W + (size_t)(bcol + n) * 256 + k0 + kb);
        }
        __syncthreads();
        bf16x8 af[4], bfr[2];
#pragma unroll
        for (int fr = 0; fr < 4; ++fr)
            af[fr] = *(const bf16x8*)(&As[wr * 64 + fr * 16 + (l & 15)][(l >> 4) * 8]);
#pragma unroll
        for (int fc = 0; fc < 2; ++fc)
            bfr[fc] = *(const bf16x8*)(&Bs[wc * 32 + fc * 16 + (l & 15)][(l >> 4) * 8]);
#pragma unroll
        for (int fr = 0; fr < 4; ++fr)
#pragma unroll
            for (int fc = 0; fc < 2; ++fc)
                acc[fr][fc] = __builtin_amdgcn_mfma_f32_16x16x32_bf16(af[fr], bfr[fc], acc[fr][fc], 0, 0, 0);
        __syncthreads();
    }
#pragma unroll
    for (int fr = 0; fr < 4; ++fr) {
#pragma unroll
        for (int fc = 0; fc < 2; ++fc) {
            int col = bcol + wc * 32 + fc * 16 + (l & 15);
#pragma unroll
            for (int i = 0; i < 4; ++i) {
                int row = brow + wr * 64 + fr * 16 + (l >> 4) * 4 + i;
                if (row >= M) continue;
                C[(size_t)row * 256 + col] = bf16rne(acc[fr][fc][i]);
            }
        }
    }
}

// ---------------- fp32 GEMM (Wcomb build only) ----------------
__global__ __launch_bounds__(256)
void gemm_f32(const float* __restrict__ A, const float* __restrict__ B,
              float* __restrict__ C, int M, int N, int K) {
    const int BM = 64, BN = 64, BK = 16;
    __shared__ float As[BK][BM + 1];
    __shared__ float Bs[BK][BN + 1];
    int tid = threadIdx.x;
    int tr = tid >> 4, tc = tid & 15;
    int brow = blockIdx.y * BM, bcol = blockIdx.x * BN;
    float acc[4][4] = {{0.f}};
    for (int k0 = 0; k0 < K; k0 += BK) {
#pragma unroll
        for (int i = 0; i < 4; ++i) {
            int e = tid + i * 256;
            int r = e >> 4, c = e & 15;
            int gr = brow + r, gc = k0 + c;
            As[c][r] = (gr < M && gc < K) ? A[(long)gr * K + gc] : 0.f;
        }
#pragma unroll
        for (int i = 0; i < 4; ++i) {
            int e = tid + i * 256;
            int r = e >> 6, c = e & 63;
            int gr = k0 + r, gc = bcol + c;
            Bs[r][c] = (gr < K && gc < N) ? B[(long)gr * N + gc] : 0.f;
        }
        __syncthreads();
#pragma unroll
        for (int k = 0; k < BK; ++k) {
            float ra[4], rb[4];
#pragma unroll
            for (int i = 0; i < 4; ++i) ra[i] = As[k][tr * 4 + i];
#pragma unroll
            for (int j = 0; j < 4; ++j) rb[j] = Bs[k][tc * 4 + j];
#pragma unroll
            for (int i = 0; i < 4; ++i)
#pragma unroll
                for (int j = 0; j < 4; ++j) acc[i][j] += ra[i] * rb[j];
        }
        __syncthreads();
    }
#pragma unroll
    for (int i = 0; i < 4; ++i) {
        int gr = brow + tr * 4 + i;
        if (gr >= M) continue;
#pragma unroll
        for (int j = 0; j < 4; ++j) {
            int gc = bcol + tc * 4 + j;
            if (gc < N) C[(long)gr * N + gc] = acc[i][j];
        }
    }
}

// ---------------- final linear + log_softmax fused ----------------
__global__ __launch_bounds__(256)
void gemm_out_lsm(const float* __restrict__ A, const float* __restrict__ B,
                  float* __restrict__ out, int M) {
    const int BK = 16;
    __shared__ float As[BK][65];
    __shared__ float Bs[BK][65];
    __shared__ float tile[64][41];
    __shared__ float lsb[64];
    int tid = threadIdx.x;
    int tr = tid >> 4, tc = tid & 15;
    int brow = blockIdx.y * 64;
    float acc[4][4] = {{0.f}};
    for (int k0 = 0; k0 < 256; k0 += BK) {
#pragma unroll
        for (int i = 0; i < 4; ++i) {
            int e = tid + i * 256;
            int r = e >> 4, c = e & 15;
            int gr = brow + r;
            As[c][r] = (gr < M) ? A[(long)gr * 256 + k0 + c] : 0.f;
        }
#pragma unroll
        for (int i = 0; i < 4; ++i) {
            int e = tid + i * 256;
            int r = e >> 6, c = e & 63;
            Bs[r][c] = (c < FOUT) ? B[(long)(k0 + r) * FOUT + c] : 0.f;
        }
        __syncthreads();
#pragma unroll
        for (int k = 0; k < BK; ++k) {
            float ra[4], rb[4];
#pragma unroll
            for (int i = 0; i < 4; ++i) ra[i] = As[k][tr * 4 + i];
#pragma unroll
            for (int j = 0; j < 4; ++j) rb[j] = Bs[k][tc * 4 + j];
#pragma unroll
            for (int i = 0; i < 4; ++i)
#pragma unroll
                for (int j = 0; j < 4; ++j) acc[i][j] += ra[i] * rb[j];
        }
        __syncthreads();
    }
#pragma unroll
    for (int i = 0; i < 4; ++i)
#pragma unroll
        for (int j = 0; j < 4; ++j) {
            int gc = tc * 4 + j;
            if (gc < FOUT) tile[tr * 4 + i][gc] = acc[i][j];
        }
    __syncthreads();
    if (tid < 64) {
        int gr = brow + tid;
        float mx = -INFINITY;
        if (gr < M) {
            for (int c = 0; c < FOUT; ++c) mx = fmaxf(mx, tile[tid][c]);
            float s = 0.f;
            for (int c = 0; c < FOUT; ++c) s += __expf(tile[tid][c] - mx);
            lsb[tid] = mx + logf(s);
        }
    }
    __syncthreads();
#pragma unroll
    for (int i = 0; i < 4; ++i) {
        int r = tr * 4 + i;
        int gr = brow + r;
        if (gr >= M) continue;
#pragma unroll
        for (int j = 0; j < 4; ++j) {
            int gc = tc * 4 + j;
            if (gc < FOUT) out[(long)gr * FOUT + gc] = tile[r][gc] - lsb[r];
        }
    }
}

// ---------------- GAT pre-computation (wg_av + bias_proj fused) ----------------
__global__ void gat_prep(const float* __restrict__ W, const float* __restrict__ as_,
                         const float* __restrict__ ad_, const float* __restrict__ b_gat,
                         const float* __restrict__ W_etn,
                         float* __restrict__ asv, float* __restrict__ adv, float* __restrict__ b2) {
    int t = threadIdx.x;
    if (blockIdx.x == FE) {
        float s = 0.f;
        for (int i = 0; i < HD; ++i) s += b_gat[i] * W_etn[i * HD + t];
        b2[t] = s;
        return;
    }
    __shared__ float sm[256];
    int i = blockIdx.x;
    float w = W[i * HD + t];
    sm[t] = w * as_[t];
    __syncthreads();
    for (int o = 128; o > 0; o >>= 1) { if (t < o) sm[t] += sm[t + o]; __syncthreads(); }
    if (t == 0) asv[i] = sm[0];
    __syncthreads();
    sm[t] = w * ad_[t];
    __syncthreads();
    for (int o = 128; o > 0; o >>= 1) { if (t < o) sm[t] += sm[t + o]; __syncthreads(); }
    if (t == 0) adv[i] = sm[0];
}

// es/ed scores + bf16 conversion: 16-lane group per edge, float4 per lane (16 B/lane)
__global__ void edge_scores_conv16(const float* __restrict__ et, const float* __restrict__ asv,
                                   const float* __restrict__ adv, float* __restrict__ es,
                                   float* __restrict__ ed, unsigned short* __restrict__ et_bf) {
    int e = blockIdx.x * 16 + (threadIdx.x >> 4);
    int l = threadIdx.x & 15;
    float4 xv = *(const float4*)(et + (size_t)e * FE + l * 4);
    float4 av = *(const float4*)(asv + l * 4);
    float4 dv = *(const float4*)(adv + l * 4);
    uint2 o; o.x = bfpack(xv.x, xv.y); o.y = bfpack(xv.z, xv.w);
    ((uint2*)et_bf)[(size_t)e * 16 + l] = o;   // row = 64 bf16 = 16 uint2
    float vs = xv.x * av.x + xv.y * av.y + xv.z * av.z + xv.w * av.w;
    float vd = xv.x * dv.x + xv.y * dv.y + xv.z * dv.z + xv.w * dv.w;
    vs += __shfl_xor(vs, 1); vd += __shfl_xor(vd, 1);
    vs += __shfl_xor(vs, 2); vd += __shfl_xor(vd, 2);
    vs += __shfl_xor(vs, 4); vd += __shfl_xor(vd, 4);
    vs += __shfl_xor(vs, 8); vd += __shfl_xor(vd, 8);
    if (l == 0) { es[e] = vs; ed[e] = vd; }
}

// ---------------- GAT: fused alpha + gather (8-lane group, online softmax, one pass) ----------------
__global__ void gat_fused2(const int* __restrict__ rowptr, const int* __restrict__ adj,
                           const float* __restrict__ es, const float* __restrict__ ed,
                           const unsigned short* __restrict__ et_bf,
                           unsigned short* __restrict__ agg_et) {
    int d = blockIdx.x * 32 + (threadIdx.x >> 3);
    int hl = threadIdx.x & 7;                  // row = 8 x uint4 (64 bf16)
    if (d >= EE) return;
    int b = rowptr[d], e_ = rowptr[d + 1];
    const uint4* etu = (const uint4*)et_bf;
    float edd = ed[d];
    float m = leaky02(es[d] + edd);
    float srun = 1.f;
    uint4 u = etu[(size_t)d * 8 + hl];
    float a0 = bflo(u.x), a1 = bfhi(u.x), a2 = bflo(u.y), a3 = bfhi(u.y);
    float a4 = bflo(u.z), a5 = bfhi(u.z), a6 = bflo(u.w), a7 = bfhi(u.w);
    int i = b;
    float esn = 0.f; uint4 un;
    if (i < e_) { int s0 = adj[i]; esn = es[s0]; un = etu[(size_t)s0 * 8 + hl]; }
    while (i < e_) {
        float esc = esn; uint4 uc = un;
        int in = i + 1;
        if (in < e_) { int s1 = adj[in]; esn = es[s1]; un = etu[(size_t)s1 * 8 + hl]; }
        float p = leaky02(esc + edd);
        float mn = fmaxf(m, p);
        float scale = exp2f((m - mn) * LOG2E);
        float w = exp2f((p - mn) * LOG2E);
        m = mn;
        srun = srun * scale + w;
        a0 = a0 * scale + w * bflo(uc.x); a1 = a1 * scale + w * bfhi(uc.x);
        a2 = a2 * scale + w * bflo(uc.y); a3 = a3 * scale + w * bfhi(uc.y);
        a4 = a4 * scale + w * bflo(uc.z); a5 = a5 * scale + w * bfhi(uc.z);
        a6 = a6 * scale + w * bflo(uc.w); a7 = a7 * scale + w * bfhi(uc.w);
        i = in;
    }
    float inv = 1.f / (srun + 1e-16f);
    uint4 o;
    o.x = bfpack(a0 * inv, a1 * inv); o.y = bfpack(a2 * inv, a3 * inv);
    o.z = bfpack(a4 * inv, a5 * inv); o.w = bfpack(a6 * inv, a7 * inv);
    ((uint4*)agg_et)[(size_t)d * 8 + hl] = o;
}

// ---------------- incidence mean (8-lane group, uint4, 2-deep prefetch) ----------------
__global__ void etn_gather3(const int* __restrict__ rowptr, const int* __restrict__ adj,
                            const unsigned short* __restrict__ agg_et,
                            unsigned short* __restrict__ agg2, float* __restrict__ degE) {
    int n = blockIdx.x * 32 + (threadIdx.x >> 3);
    int hl = threadIdx.x & 7;
    if (n >= NN) return;
    int b = rowptr[n], e_ = rowptr[n + 1];
    const uint4* au = (const uint4*)agg_et;
    uint4 u0, u1;
    if (b < e_)     u0 = au[(size_t)adj[b] * 8 + hl];
    if (b + 1 < e_) u1 = au[(size_t)adj[b + 1] * 8 + hl];
    float a0 = 0.f, a1 = 0.f, a2 = 0.f, a3 = 0.f, a4 = 0.f, a5 = 0.f, a6 = 0.f, a7 = 0.f;
    for (int i = b; i < e_; ++i) {
        uint4 uc = u0;
        u0 = u1;
        if (i + 2 < e_) u1 = au[(size_t)adj[i + 2] * 8 + hl];
        a0 += bflo(uc.x); a1 += bfhi(uc.x); a2 += bflo(uc.y); a3 += bfhi(uc.y);
        a4 += bflo(uc.z); a5 += bfhi(uc.z); a6 += bflo(uc.w); a7 += bfhi(uc.w);
    }
    float deg = (float)(e_ - b);
    float inv = 1.f / fmaxf(deg, 1.f);
    uint4 o;
    o.x = bfpack(a0 * inv, a1 * inv); o.y = bfpack(a2 * inv, a3 * inv);
    o.z = bfpack(a4 * inv, a5 * inv); o.w = bfpack(a6 * inv, a7 * inv);
    ((uint4*)agg2)[(size_t)n * 8 + hl] = o;
    if (hl == 0) degE[n] = deg;
}

// ---------------- SAGE mean (2 nodes/wave, 32-lane halves, 2-deep prefetch) ----------------
__global__ void sage_gather2(const unsigned short* __restrict__ X, const int* __restrict__ rowptr,
                             const int* __restrict__ adjS, unsigned short* __restrict__ mean) {
    int base = (blockIdx.x * 4 + (threadIdx.x >> 6)) * 2;
    int lane = threadIdx.x & 63;
    int half = lane >> 5, hl = lane & 31;
    int n = base + half;
    if (n >= NN) return;
    int b = rowptr[n], e_ = rowptr[n + 1];
    const uint4* Xu = (const uint4*)X;
    uint4 u0, u1;
    if (b < e_)     u0 = Xu[(size_t)adjS[b] * 32 + hl];
    if (b + 1 < e_) u1 = Xu[(size_t)adjS[b + 1] * 32 + hl];
    float a0 = 0.f, a1 = 0.f, a2 = 0.f, a3 = 0.f, a4 = 0.f, a5 = 0.f, a6 = 0.f, a7 = 0.f;
    for (int i = b; i < e_; ++i) {
        uint4 uc = u0;
        u0 = u1;
        if (i + 2 < e_) u1 = Xu[(size_t)adjS[i + 2] * 32 + hl];
        a0 += bflo(uc.x); a1 += bfhi(uc.x); a2 += bflo(uc.y); a3 += bfhi(uc.y);
        a4 += bflo(uc.z); a5 += bfhi(uc.z); a6 += bflo(uc.w); a7 += bfhi(uc.w);
    }
    float inv = 1.f / fmaxf((float)(e_ - b), 1.f);
    uint4 o;
    o.x = bfpack(a0 * inv, a1 * inv); o.y = bfpack(a2 * inv, a3 * inv);
    o.z = bfpack(a4 * inv, a5 * inv); o.w = bfpack(a6 * inv, a7 * inv);
    ((uint4*)mean)[(size_t)n * 32 + hl] = o;
}

// ---------------- MixAttention: online softmax, k/v prefetched 2 ahead ----------------
__global__ void attn_online(const unsigned short* __restrict__ q, const unsigned short* __restrict__ k,
                            const unsigned short* __restrict__ v, const unsigned short* __restrict__ nrep,
                            const int* __restrict__ rowptr, const int* __restrict__ adjS,
                            float* __restrict__ mixed) {
    int n = blockIdx.x * 4 + (threadIdx.x >> 6);
    int lane = threadIdx.x & 63;
    if (n >= NN) return;
    int half = lane >> 5, hl = lane & 31;
    int b = rowptr[n], e_ = rowptr[n + 1];
    const uint4* qu4 = (const uint4*)q;
    const uint4* ku4 = (const uint4*)k;
    const uint4* vu4 = (const uint4*)v;
    const uint4* nu4 = (const uint4*)nrep;
    uint4 nu = nu4[(size_t)n * 32 + hl];
    float nr0 = bflo(nu.x), nr1 = bfhi(nu.x), nr2 = bflo(nu.y), nr3 = bfhi(nu.y);
    float nr4 = bflo(nu.z), nr5 = bfhi(nu.z), nr6 = bflo(nu.w), nr7 = bfhi(nu.w);
    float* mrow = mixed + (size_t)n * HD;
    if (b == e_) {
        if (half == 0) {
            ((float4*)mrow)[2 * hl]     = make_float4(nr0, nr1, nr2, nr3);
            ((float4*)mrow)[2 * hl + 1] = make_float4(nr4, nr5, nr6, nr7);
        }
        return;
    }
    uint4 qv = qu4[(size_t)n * 32 + hl];
    float q0 = bflo(qv.x), q1 = bfhi(qv.x), q2 = bflo(qv.y), q3 = bfhi(qv.y);
    float q4 = bflo(qv.z), q5 = bfhi(qv.z), q6 = bflo(qv.w), q7 = bfhi(qv.w);
    float m = -INFINITY, srun = 0.f;
    float a0 = 0.f, a1 = 0.f, a2 = 0.f, a3 = 0.f, a4 = 0.f, a5 = 0.f, a6 = 0.f, a7 = 0.f;
    int i = b + half;
    uint4 ku, vu;
    if (i < e_) {
        int s0 = adjS[i];
        ku = ku4[(size_t)s0 * 32 + hl];
        vu = vu4[(size_t)s0 * 32 + hl];
    }
    while (i < e_) {
        int in = i + 2;
        uint4 kn, vn;
        if (in < e_) {
            int s1 = adjS[in];
            kn = ku4[(size_t)s1 * 32 + hl];
            vn = vu4[(size_t)s1 * 32 + hl];
        }
        float p = q0 * bflo(ku.x) + q1 * bfhi(ku.x) + q2 * bflo(ku.y) + q3 * bfhi(ku.y)
                + q4 * bflo(ku.z) + q5 * bfhi(ku.z) + q6 * bflo(ku.w) + q7 * bfhi(ku.w);
        p += __shfl_xor(p, 1); p += __shfl_xor(p, 2); p += __shfl_xor(p, 4);
        p += __shfl_xor(p, 8); p += __shfl_xor(p, 16);
        p *= 0.0625f;
        float mn = fmaxf(m, p);
        float scale = exp2f((m - mn) * LOG2E);
        float w = exp2f((p - mn) * LOG2E);
        m = mn;
        srun = srun * scale + w;
        a0 = a0 * scale + w * bflo(vu.x); a1 = a1 * scale + w * bfhi(vu.x);
        a2 = a2 * scale + w * bflo(vu.y); a3 = a3 * scale + w * bfhi(vu.y);
        a4 = a4 * scale + w * bflo(vu.z); a5 = a5 * scale + w * bfhi(vu.z);
        a6 = a6 * scale + w * bflo(vu.w); a7 = a7 * scale + w * bfhi(vu.w);
        i = in; ku = kn; vu = vn;
    }
    float mo = __shfl_xor(m, 32);
    float so = __shfl_xor(srun, 32);
    float mn = fmaxf(m, mo);
    float cs = exp2f((m - mn) * LOG2E);
    float co = exp2f((mo - mn) * LOG2E);
    float st = srun * cs + so * co;
    float inv = 1.f / (st + 1e-16f);
    float o0 = (a0 * cs + __shfl_xor(a0, 32) * co) * inv + nr0;
    float o1 = (a1 * cs + __shfl_xor(a1, 32) * co) * inv + nr1;
    float o2 = (a2 * cs + __shfl_xor(a2, 32) * co) * inv + nr2;
    float o3 = (a3 * cs + __shfl_xor(a3, 32) * co) * inv + nr3;
    float o4 = (a4 * cs + __shfl_xor(a4, 32) * co) * inv + nr4;
    float o5 = (a5 * cs + __shfl_xor(a5, 32) * co) * inv + nr5;
    float o6 = (a6 * cs + __shfl_xor(a6, 32) * co) * inv + nr6;
    float o7 = (a7 * cs + __shfl_xor(a7, 32) * co) * inv + nr7;
    if (half == 0) {
        ((float4*)mrow)[2 * hl]     = make_float4(o0, o1, o2, o3);
        ((float4*)mrow)[2 * hl + 1] = make_float4(o4, o5, o6, o7);
    }
}

extern "C" void kernel_launch(void* const* d_in, const int* in_sizes, int n_in,
                              void* d_out, int out_size, void* d_ws, size_t ws_size,
                              hipStream_t stream) {
    (void)in_sizes; (void)n_in; (void)out_size; (void)ws_size;
    const float* x     = (const float*)d_in[0];
    const float* et    = (const float*)d_in[1];
    const int*   Hm    = (const int*)d_in[2];
    const int*   raw   = (const int*)d_in[3];
    const int*   lg    = (const int*)d_in[4];
    const float* W_gat = (const float*)d_in[5];
    const float* a_src = (const float*)d_in[6];
    const float* a_dst = (const float*)d_in[7];
    const float* b_gat = (const float*)d_in[8];
    const float* W_etn = (const float*)d_in[9];
    const float* W_eg  = (const float*)d_in[10];
    const float* Wr_e1 = (const float*)d_in[11];
    const float* Wn_e1 = (const float*)d_in[12];
    const float* b_e1  = (const float*)d_in[13];
    const float* Wr_e2 = (const float*)d_in[14];
    const float* Wn_e2 = (const float*)d_in[15];
    const float* b_e2  = (const float*)d_in[16];
    const float* Wr_n1 = (const float*)d_in[17];
    const float* Wn_n1 = (const float*)d_in[18];
    const float* b_n1  = (const float*)d_in[19];
    const float* Wr_n2 = (const float*)d_in[20];
    const float* Wn_n2 = (const float*)d_in[21];
    const float* b_n2  = (const float*)d_in[22];
    const float* Wr_n3 = (const float*)d_in[23];
    const float* Wn_n3 = (const float*)d_in[24];
    const float* b_n3  = (const float*)d_in[25];
    const float* Wq    = (const float*)d_in[26];
    const float* Wk    = (const float*)d_in[27];
    const float* Wv    = (const float*)d_in[28];
    const float* W_out = (const float*)d_in[29];

    const int* srcN = raw;
    const int* dstN = raw + EE;
    const int* lgs  = lg;
    const int* lgd  = lg + ELG;

    float* ws = (float*)d_ws;
    size_t off = 0;
    auto alloc = [&](size_t n) { float* p = ws + off; off += (n + 63) & ~(size_t)63; return p; };
    auto allocU = [&](size_t nus) { return (unsigned short*)alloc(nus / 2 + 64); };

    unsigned short* et_bf   = allocU((size_t)EE * FE);
    unsigned short* agg_et  = allocU((size_t)EE * FE);   // reused later as q/k/v
    float* es     = alloc(EE);
    float* ed     = alloc(EE);
    float* Wcomb  = alloc((size_t)FE * HD);
    float* b2     = alloc(HD);
    float* asv    = alloc(FE);
    float* adv    = alloc(FE);
    unsigned short* agg2_bf = allocU((size_t)NN * FE);
    float* degE   = alloc(NN);
    unsigned short* etnL  = allocU((size_t)NN * HD);
    unsigned short* erep  = allocU((size_t)NN * HD);
    unsigned short* meanb = allocU((size_t)NN * HD);
    unsigned short* t1    = allocU((size_t)NN * HD);
    unsigned short* aggr  = allocU((size_t)NN * HD);
    unsigned short* nrep  = allocU((size_t)NN * HD);
    unsigned short* x_bf  = allocU((size_t)NN * HD);
    float* mixed  = alloc((size_t)NN * HD);
    unsigned short* wtb    = allocU((size_t)14 * 65536);
    unsigned short* wcombt = allocU((size_t)HD * FE);
    int* rowptrD  = (int*)alloc(NN + 64);
    int* adjS     = (int*)alloc(EE);
    int* rowptrLG = (int*)alloc(EE + 64);
    int* adjLG    = (int*)alloc(ELG);
    int* rowptrH  = (int*)alloc(NN + 64);
    int* adjH     = (int*)alloc(2 * EE);
    int* cntAll   = (int*)alloc(NTOTC + 64);
    int* posAll   = (int*)alloc(NIDX + 64);
    int* bsum     = (int*)alloc(1024);
    // aliases (lifetime-checked)
    unsigned short* ta = etnL;                 // etnL dead after erep GEMM
    unsigned short* tb = erep;                 // erep dead after edge layer 1
    unsigned short* qb = agg_et;               // agg_et dead after etn_gather
    unsigned short* kb = agg_et + (size_t)NN * HD;
    unsigned short* vb = agg_et + (size_t)2 * NN * HD;
    float* outp = (float*)d_out;

    unsigned short* W_eg_t  = wtb + 0 * 65536;
    unsigned short* Wr_e1_t = wtb + 1 * 65536;
    unsigned short* Wn_e1_t = wtb + 2 * 65536;
    unsigned short* Wr_e2_t = wtb + 3 * 65536;
    unsigned short* Wn_e2_t = wtb + 4 * 65536;
    unsigned short* Wr_n1_t = wtb + 5 * 65536;
    unsigned short* Wn_n1_t = wtb + 6 * 65536;
    unsigned short* Wr_n2_t = wtb + 7 * 65536;
    unsigned short* Wn_n2_t = wtb + 8 * 65536;
    unsigned short* Wr_n3_t = wtb + 9 * 65536;
    unsigned short* Wn_n3_t = wtb + 10 * 65536;
    unsigned short* Wq_t    = wtb + 11 * 65536;
    unsigned short* Wk_t    = wtb + 12 * 65536;
    unsigned short* Wv_t    = wtb + 13 * 65536;

    dim3 gB(4, (NN + 127) / 128);

    // ======== weight conversion + x conversion ========
    Ptr14 p14;
    p14.p[0] = W_eg;  p14.p[1] = Wr_e1; p14.p[2] = Wn_e1; p14.p[3] = Wr_e2;
    p14.p[4] = Wn_e2; p14.p[5] = Wr_n1; p14.p[6] = Wn_n1; p14.p[7] = Wr_n2;
    p14.p[8] = Wn_n2; p14.p[9] = Wr_n3; p14.p[10] = Wn_n3; p14.p[11] = Wq;
    p14.p[12] = Wk;   p14.p[13] = Wv;
    wtrans14<<<14 * 64, 256, 0, stream>>>(p14, wtb);
    conv_bf16<<<(NN * HD / 2 + 255) / 256, 256, 0, stream>>>(x, (unsigned int*)x_bf, NN * HD / 2);

    // ======== CSR build: count+pos (atomic) -> scan+rebase -> atomic-free scatter ========
    zero_i32<<<(NTOTC + 255) / 256, 256, 0, stream>>>(cntAll, NTOTC);
    count_pos<<<(NIDX + 255) / 256, 256, 0, stream>>>(dstN, lgd, Hm, cntAll, posAll);
    {
        int nb = (NTOTC + 1023) / 1024;
        scan_pass1<<<nb, 256, 0, stream>>>(cntAll, bsum, NTOTC);
        scan_pass2<<<1, 256, 0, stream>>>(bsum, nb);
        scan_pass3_rebase<<<nb, 256, 0, stream>>>(cntAll, bsum, rowptrD, rowptrLG, rowptrH);
    }
    place_scatter<<<8 * PBLK, 256, 0, stream>>>(srcN, dstN, lgs, lgd, Hm, posAll,
                                                rowptrD, rowptrLG, rowptrH,
                                                adjS, adjLG, adjH);

    // ======== GAT (folded Wcomb = W_gat@W_etn; alpha fused into gather) ========
    gemm_f32<<<dim3(4, 1), 256, 0, stream>>>(W_gat, W_etn, Wcomb, FE, HD, HD);
    wtrans_one<<<(FE / 32) * (HD / 32), 256, 0, stream>>>(Wcomb, wcombt, FE, HD);
    gat_prep<<<FE + 1, 256, 0, stream>>>(W_gat, a_src, a_dst, b_gat, W_etn, asv, adv, b2);
    edge_scores_conv16<<<EE / 16, 256, 0, stream>>>(et, asv, adv, es, ed, et_bf);
    gat_fused2<<<EE / 32, 256, 0, stream>>>(rowptrLG, adjLG, es, ed, et_bf, agg_et);

    // ======== EdgeToNode incidence mean + GEMMs ========
    etn_gather3<<<(NN + 31) / 32, 256, 0, stream>>>(rowptrH, adjH, agg_et, agg2_bf, degE);
    gemm_bf16<<<gB, 256, 0, stream>>>(agg2_bf, nullptr, wcombt, nullptr, b2, degE, etnL, NN, FE, 4);
    gemm_bf16<<<gB, 256, 0, stream>>>(etnL, nullptr, W_eg_t, nullptr, nullptr, nullptr, erep, NN, HD, 0);

    // ======== edge_aggr SAGE (2 layers, dual-K fused) ========
    sage_gather2<<<(NN + 7) / 8, 256, 0, stream>>>(erep, rowptrD, adjS, meanb);
    gemm_bf16<<<gB, 256, 0, stream>>>(erep, meanb, Wr_e1_t, Wn_e1_t, b_e1, nullptr, t1, NN, HD, 1);
    sage_gather2<<<(NN + 7) / 8, 256, 0, stream>>>(t1, rowptrD, adjS, meanb);
    gemm_bf16<<<gB, 256, 0, stream>>>(t1, meanb, Wr_e2_t, Wn_e2_t, b_e2, nullptr, aggr, NN, HD, 0);

    // ======== attr_node SAGE (3 layers, dual-K fused) ========
    sage_gather2<<<(NN + 7) / 8, 256, 0, stream>>>(x_bf, rowptrD, adjS, meanb);
    gemm_bf16<<<gB, 256, 0, stream>>>(x_bf, meanb, Wr_n1_t, Wn_n1_t, b_n1, nullptr, ta, NN, HD, 1);
    sage_gather2<<<(NN + 7) / 8, 256, 0, stream>>>(ta, rowptrD, adjS, meanb);
    gemm_bf16<<<gB, 256, 0, stream>>>(ta, meanb, Wr_n2_t, Wn_n2_t, b_n2, nullptr, tb, NN, HD, 1);
    sage_gather2<<<(NN + 7) / 8, 256, 0, stream>>>(tb, rowptrD, adjS, meanb);
    gemm_bf16<<<gB, 256, 0, stream>>>(tb, meanb, Wr_n3_t, Wn_n3_t, b_n3, nullptr, nrep, NN, HD, 0);

    // ======== MixAttention (q,k,v in ONE launch) ========
    gemm_bf16_tri<<<dim3(12, (NN + 127) / 128), 256, 0, stream>>>(
        nrep, Wq_t, qb, aggr, Wk_t, kb, aggr, Wv_t, vb, NN);
    attn_online<<<(NN + 3) / 4, 256, 0, stream>>>(qb, kb, vb, nrep, rowptrD, adjS, mixed);

    // ======== final linear + log_softmax (fused) ========
    gemm_out_lsm<<<dim3(1, (NN + 63) / 64), 256, 0, stream>>>(mixed, W_out, outp, NN);
}